// Round 12
// baseline (324.295 us; speedup 1.0000x reference)
//
#include <hip/hip_runtime.h>
#include <math.h>

#define B_    2
#define C_    128
#define N_    2048
#define HID_  512
#define HEADS_ 8
#define EPS_  1e-6f
#define NS_   0.2f
#define KSPLIT 8

typedef __attribute__((ext_vector_type(8))) short short8v;  // 8 bf16
typedef __attribute__((ext_vector_type(4))) float f32x4;
typedef unsigned short ush;
typedef unsigned int u32;

__device__ inline ush f2bf(float f) {
    unsigned u = __float_as_uint(f);
    u += 0x7FFF + ((u >> 16) & 1);          // round-to-nearest-even
    return (ush)(u >> 16);
}
__device__ inline float bf2f(ush u) { return __uint_as_float((u32)u << 16); }

// pack float -> (hi bf16 << 16) | lo bf16, with hi+lo ~ x to ~2^-17 rel
__device__ inline u32 splitpack(float x) {
    ush hi = f2bf(x);
    float hf = __uint_as_float((u32)hi << 16);
    ush lo = f2bf(x - hf);
    return ((u32)hi << 16) | (u32)lo;
}

__device__ inline void unpack16(const u32* buf, short8v& h0, short8v& h1,
                                short8v& l0, short8v& l1) {
    ush h[16], l[16];
    #pragma unroll
    for (int j = 0; j < 16; ++j) { u32 u = buf[j]; h[j] = (ush)(u >> 16); l[j] = (ush)(u & 0xffff); }
    h0 = *(short8v*)&h[0]; h1 = *(short8v*)&h[8];
    l0 = *(short8v*)&l[0]; l1 = *(short8v*)&l[8];
}

__device__ inline void unpack_hi(const u32* buf, short8v& h0, short8v& h1) {
    ush h[16];
    #pragma unroll
    for (int j = 0; j < 16; ++j) h[j] = (ush)(buf[j] >> 16);
    h0 = *(short8v*)&h[0]; h1 = *(short8v*)&h[8];
}

// ---------------------------------------------------------------------------
// vec_layernorm, z-indexed multi-input: writes bf16 plane ysp and optional
// fp32 y (for transpose/graph consumers)
// ---------------------------------------------------------------------------
struct LNArgs {
    const float* x[2]; const float* g[2]; const float* bt[2];
    float* y[2]; ush* ysp[2];
};
__global__ __launch_bounds__(256) void ln_kernel(LNArgs a)
{
    __shared__ float norms[128][32];
    __shared__ float red1[8][32];
    __shared__ float red2[8][32];
    const int s = blockIdx.z;
    const float* x = a.x[s];
    const float* gma = a.g[s];
    const float* bta = a.bt[s];
    float* y = a.y[s];
    ush* ysp = a.ysp[s];

    const int b  = blockIdx.y;
    const int n0 = blockIdx.x * 32;
    const int nn = threadIdx.x & 31;
    const int cg = threadIdx.x >> 5;

    float s1 = 0.f, s2 = 0.f;
    for (int it = 0; it < 16; ++it) {
        int c = it * 8 + cg;
        size_t base = ((size_t)(b * C_ + c) * 3) * N_ + n0 + nn;
        float x0 = x[base], x1 = x[base + N_], x2 = x[base + 2 * N_];
        float nr = sqrtf(x0 * x0 + x1 * x1 + x2 * x2 + EPS_);
        norms[c][nn] = nr;
        s1 += nr; s2 += nr * nr;
    }
    red1[cg][nn] = s1; red2[cg][nn] = s2;
    __syncthreads();
    float S1 = 0.f, S2 = 0.f;
    #pragma unroll
    for (int g = 0; g < 8; ++g) { S1 += red1[g][nn]; S2 += red2[g][nn]; }
    float mu   = S1 * (1.f / 128.f);
    float var  = S2 * (1.f / 128.f) - mu * mu;
    float rstd = rsqrtf(var + EPS_);

    for (int it = 0; it < 16; ++it) {
        int c = it * 8 + cg;
        float nr = norms[c][nn];
        float ln = (nr - mu) * rstd * gma[c] + bta[c];
        float sc = ln / (nr + EPS_);
        size_t base = ((size_t)(b * C_ + c) * 3) * N_ + n0 + nn;
        float y0 = x[base] * sc, y1 = x[base + N_] * sc, y2 = x[base + 2 * N_] * sc;
        if (y) {
            y[base]          = y0;
            y[base + N_]     = y1;
            y[base + 2 * N_] = y2;
        }
        ysp[base]          = f2bf(y0);
        ysp[base + N_]     = f2bf(y1);
        ysp[base + 2 * N_] = f2bf(y2);
    }
}

// ---------------------------------------------------------------------------
// weight split-conversion: 15 weights, one launch (with optional pre-scale)
// ---------------------------------------------------------------------------
struct WCArgs { const float* src[15]; u32* dst[15]; int n[15]; float scale[15]; };
__global__ __launch_bounds__(256) void wconv_kernel(WCArgs a)
{
    const int w = blockIdx.y;
    const int i = blockIdx.x * 256 + threadIdx.x;
    if (i < a.n[w]) a.dst[w][i] = splitpack(a.src[w][i] * a.scale[w]);
}

// ---------------------------------------------------------------------------
// bf16 MFMA GEMM core. SPLIT: 3-term fp32-quality. XBF: X input is bf16 ush.
// XMODE 0: X[(b*K + c)*M + m]   XMODE 1: X[((b*N+n)*3+t)*K + c], m = t*N+n
// OMODE 0: fp32(+Z)  1: split u32  4: qkv fragment-major  5: fp32 + bf16
// ---------------------------------------------------------------------------
template <int XMODE, int OMODE, bool SPLIT, bool XBF>
__device__ __forceinline__ void gemm_tile(
    const u32* __restrict__ Wsp, int wstride,
    const void* __restrict__ Xv, int K,
    const float* __restrict__ Z, float* __restrict__ Y, u32* __restrict__ Ysp,
    ush* __restrict__ Ybf, ush* __restrict__ Ytr,
    int b, int m0, int o0loc, int oglob, int Ostr,
    ush (*Wh)[64], ush (*Wl)[64], ush (*Xh)[64], ush (*Xl)[64])
{
    const int M = 3 * N_;
    const int tid = threadIdx.x;
    const int lane = tid & 63, wv = tid >> 6;
    const int col = lane & 15, grp = lane >> 4;
    const int wo = wv >> 1, wm = wv & 1;

    f32x4 acc[2][2];
    #pragma unroll
    for (int i = 0; i < 2; ++i)
        #pragma unroll
        for (int j = 0; j < 2; ++j) { f32x4 z = {0.f,0.f,0.f,0.f}; acc[i][j] = z; }

    for (int kk = 0; kk < K; kk += 64) {
        // ---- stage W tile (64 o x 64 k), split u32 source ----
        {
            const int o = tid >> 2, kg = tid & 3;
            const u32* src = Wsp + (size_t)(o0loc + o) * wstride + kk + kg * 16;
            u32 buf[16];
            #pragma unroll
            for (int j = 0; j < 4; ++j) *(uint4*)&buf[j * 4] = *(const uint4*)(src + j * 4);
            const int s0 = ((kg * 2)     ^ (o & 7)) << 3;
            const int s1 = ((kg * 2 + 1) ^ (o & 7)) << 3;
            if (SPLIT) {
                short8v h0, h1, l0, l1; unpack16(buf, h0, h1, l0, l1);
                *(short8v*)&Wh[o][s0] = h0; *(short8v*)&Wh[o][s1] = h1;
                *(short8v*)&Wl[o][s0] = l0; *(short8v*)&Wl[o][s1] = l1;
            } else {
                short8v h0, h1; unpack_hi(buf, h0, h1);
                *(short8v*)&Wh[o][s0] = h0; *(short8v*)&Wh[o][s1] = h1;
            }
        }
        // ---- stage X tile (64 k x 64 m), stored transposed Xs[m][k] ----
        if (XMODE == 0) {
            const int m = lane, kq = wv;
            const int s0 = ((kq * 2)     ^ (m & 7)) << 3;
            const int s1 = ((kq * 2 + 1) ^ (m & 7)) << 3;
            if (XBF) {
                const ush* src = (const ush*)Xv + ((size_t)b * K + kk + kq * 16) * M + m0 + m;
                ush h[16];
                #pragma unroll
                for (int j = 0; j < 16; ++j) h[j] = src[(size_t)j * M];
                *(short8v*)&Xh[m][s0] = *(short8v*)&h[0];
                *(short8v*)&Xh[m][s1] = *(short8v*)&h[8];
            } else {
                const u32* src = (const u32*)Xv + ((size_t)b * K + kk + kq * 16) * M + m0 + m;
                u32 buf[16];
                #pragma unroll
                for (int j = 0; j < 16; ++j) buf[j] = src[(size_t)j * M];
                if (SPLIT) {
                    short8v h0, h1, l0, l1; unpack16(buf, h0, h1, l0, l1);
                    *(short8v*)&Xh[m][s0] = h0; *(short8v*)&Xh[m][s1] = h1;
                    *(short8v*)&Xl[m][s0] = l0; *(short8v*)&Xl[m][s1] = l1;
                } else {
                    short8v h0, h1; unpack_hi(buf, h0, h1);
                    *(short8v*)&Xh[m][s0] = h0; *(short8v*)&Xh[m][s1] = h1;
                }
            }
        } else {
            const int m = tid >> 2, kg = tid & 3;
            const int mg = m0 + m;
            const int n = mg & (N_ - 1), t = mg >> 11;
            const int s0 = ((kg * 2)     ^ (m & 7)) << 3;
            const int s1 = ((kg * 2 + 1) ^ (m & 7)) << 3;
            if (XBF) {
                const ush* src = (const ush*)Xv + ((size_t)(b * N_ + n) * 3 + t) * K + kk + kg * 16;
                ush h[16];
                *(uint4*)&h[0] = *(const uint4*)(src);
                *(uint4*)&h[8] = *(const uint4*)(src + 8);
                *(short8v*)&Xh[m][s0] = *(short8v*)&h[0];
                *(short8v*)&Xh[m][s1] = *(short8v*)&h[8];
            } else {
                const u32* src = (const u32*)Xv + ((size_t)(b * N_ + n) * 3 + t) * K + kk + kg * 16;
                u32 buf[16];
                #pragma unroll
                for (int j = 0; j < 4; ++j) *(uint4*)&buf[j * 4] = *(const uint4*)(src + j * 4);
                if (SPLIT) {
                    short8v h0, h1, l0, l1; unpack16(buf, h0, h1, l0, l1);
                    *(short8v*)&Xh[m][s0] = h0; *(short8v*)&Xh[m][s1] = h1;
                    *(short8v*)&Xl[m][s0] = l0; *(short8v*)&Xl[m][s1] = l1;
                } else {
                    short8v h0, h1; unpack_hi(buf, h0, h1);
                    *(short8v*)&Xh[m][s0] = h0; *(short8v*)&Xh[m][s1] = h1;
                }
            }
        }
        __syncthreads();
        // ---- MFMAs per K-step: 8 (hi-only) or 24 (split) ----
        #pragma unroll
        for (int kc = 0; kc < 2; ++kc) {
            const int sk = ((kc * 4 + grp) ^ (col & 7)) << 3;
            short8v ah0 = *(const short8v*)&Wh[wo * 32 + col][sk];
            short8v ah1 = *(const short8v*)&Wh[wo * 32 + 16 + col][sk];
            short8v xh0 = *(const short8v*)&Xh[wm * 32 + col][sk];
            short8v xh1 = *(const short8v*)&Xh[wm * 32 + 16 + col][sk];
            acc[0][0] = __builtin_amdgcn_mfma_f32_16x16x32_bf16(ah0, xh0, acc[0][0], 0, 0, 0);
            acc[0][1] = __builtin_amdgcn_mfma_f32_16x16x32_bf16(ah0, xh1, acc[0][1], 0, 0, 0);
            acc[1][0] = __builtin_amdgcn_mfma_f32_16x16x32_bf16(ah1, xh0, acc[1][0], 0, 0, 0);
            acc[1][1] = __builtin_amdgcn_mfma_f32_16x16x32_bf16(ah1, xh1, acc[1][1], 0, 0, 0);
            if (SPLIT) {
                short8v al0 = *(const short8v*)&Wl[wo * 32 + col][sk];
                short8v al1 = *(const short8v*)&Wl[wo * 32 + 16 + col][sk];
                short8v xl0 = *(const short8v*)&Xl[wm * 32 + col][sk];
                short8v xl1 = *(const short8v*)&Xl[wm * 32 + 16 + col][sk];
                acc[0][0] = __builtin_amdgcn_mfma_f32_16x16x32_bf16(ah0, xl0, acc[0][0], 0, 0, 0);
                acc[0][1] = __builtin_amdgcn_mfma_f32_16x16x32_bf16(ah0, xl1, acc[0][1], 0, 0, 0);
                acc[1][0] = __builtin_amdgcn_mfma_f32_16x16x32_bf16(ah1, xl0, acc[1][0], 0, 0, 0);
                acc[1][1] = __builtin_amdgcn_mfma_f32_16x16x32_bf16(ah1, xl1, acc[1][1], 0, 0, 0);
                acc[0][0] = __builtin_amdgcn_mfma_f32_16x16x32_bf16(al0, xh0, acc[0][0], 0, 0, 0);
                acc[0][1] = __builtin_amdgcn_mfma_f32_16x16x32_bf16(al0, xh1, acc[0][1], 0, 0, 0);
                acc[1][0] = __builtin_amdgcn_mfma_f32_16x16x32_bf16(al1, xh0, acc[1][0], 0, 0, 0);
                acc[1][1] = __builtin_amdgcn_mfma_f32_16x16x32_bf16(al1, xh1, acc[1][1], 0, 0, 0);
            }
        }
        __syncthreads();
    }
    // ---- epilogue ----
    #pragma unroll
    for (int of = 0; of < 2; ++of) {
        #pragma unroll
        for (int r = 0; r < 4; ++r) {
            const int o = oglob + wo * 32 + of * 16 + grp * 4 + r;
            #pragma unroll
            for (int mf = 0; mf < 2; ++mf) {
                const int mloc = m0 + wm * 32 + mf * 16 + col;
                const size_t idx = ((size_t)b * Ostr + o) * M + mloc;
                float v = acc[of][mf][r];
                if (OMODE == 0 || OMODE == 5) {
                    if (Z) v += Z[idx];
                    Y[idx] = v;
                }
                if (OMODE == 1) Ysp[idx] = splitpack(v);
                if (OMODE == 5) Ybf[idx] = f2bf(v);
                if (OMODE == 4) {
                    ush bv = f2bf(v);
                    const int t = mloc >> 11, n = mloc & (N_ - 1);
                    const int h = (o >> 4) & 7, cl = o & 15;
                    const int d = cl * 3 + t;
                    if (o >= 256) {
                        const int kt = n >> 6, hh = (n >> 5) & 1, db = d >> 4;
                        const size_t idx2 = ((size_t)(b * 8 + h) * 192
                                           + (kt * 2 + hh) * 3 + db) * 512
                                          + (((n >> 3) & 3) * 16 + (d & 15)) * 8 + (n & 7);
                        Ybf[idx2] = bv;
                    } else {
                        const int isK = (o >> 7) & 1;
                        const int qg = n >> 4, half = d >> 5;
                        const size_t idx2 = ((size_t)(isK * 16 + b * 8 + h) * 256
                                           + qg * 2 + half) * 512
                                          + (((d >> 3) & 3) * 16 + (n & 15)) * 8 + (d & 7);
                        Ytr[idx2] = bv;
                    }
                }
            }
        }
    }
}

template <int XMODE, int OMODE, bool SPLIT, bool XBF>
__global__ __launch_bounds__(256) void gemm_kernel2(
    const u32* __restrict__ Wsp, int wstride,
    const void* __restrict__ Xv,
    const float* __restrict__ Z,
    float* __restrict__ Y, u32* __restrict__ Ysp, ush* __restrict__ Ybf,
    int Ostr, int obase, int K)
{
    if (SPLIT) {
        __shared__ __align__(16) ush Wh[64][64];
        __shared__ __align__(16) ush Wl[64][64];
        __shared__ __align__(16) ush Xh[64][64];
        __shared__ __align__(16) ush Xl[64][64];
        gemm_tile<XMODE, OMODE, true, XBF>(Wsp, wstride, Xv, K, Z, Y, Ysp, Ybf, nullptr,
                                blockIdx.z, blockIdx.x * 64,
                                blockIdx.y * 64, obase + blockIdx.y * 64, Ostr,
                                Wh, Wl, Xh, Xl);
    } else {
        __shared__ __align__(16) ush Wh[64][64];
        __shared__ __align__(16) ush Xh[64][64];
        gemm_tile<XMODE, OMODE, false, XBF>(Wsp, wstride, Xv, K, Z, Y, Ysp, Ybf, nullptr,
                                blockIdx.z, blockIdx.x * 64,
                                blockIdx.y * 64, obase + blockIdx.y * 64, Ostr,
                                Wh, nullptr, Xh, nullptr);
    }
}

struct QKVArgs {
    const u32* W0; const u32* W1; const u32* W2;
    const ush* X0; const ush* X1; const ush* X2;
};

// fused: qkv projections (blocks 0..1151, fragment-major outputs) +
// transpose(s) (blocks 1152.., (B,C,3,N) fp32 -> (B,N,3,C))
__global__ __launch_bounds__(256) void qkv_tr_kernel(QKVArgs A,
        ush* __restrict__ vfm, ush* __restrict__ qktb,
        const float* __restrict__ ts0, float* __restrict__ td0,
        const float* __restrict__ ts1, float* __restrict__ td1)
{
    __shared__ __align__(16) ush Wh[64][64];
    __shared__ __align__(16) ush Xh[64][64];
    const int bx = blockIdx.x;
    if (bx < 1152) {
        const int z = bx / 576, rem = bx % 576;
        const int y = rem / 96, x = rem % 96;
        const int wi = y >> 1;
        const u32* W = wi == 0 ? A.W0 : (wi == 1 ? A.W1 : A.W2);
        const ush* X = wi == 0 ? A.X0 : (wi == 1 ? A.X1 : A.X2);
        gemm_tile<0, 4, false, true>(W, 128, X, 128, nullptr, nullptr, nullptr, vfm, qktb,
                        z, x * 64, (y & 1) * 64, y * 64, 384,
                        Wh, nullptr, Xh, nullptr);
    } else {
        int i = bx - 1152;
        const int which = i / 1536; i %= 1536;
        const float* src = which ? ts1 : ts0;
        float* dst = which ? td1 : td0;
        const int x = i & 63, y = (i >> 6) & 3, z = i >> 8;
        const int b = z / 3, t = z % 3;
        const int n0 = x * 32, c0 = y * 32;
        float (*tile)[33] = (float(*)[33])Wh;
        const int tx = threadIdx.x & 31, ty = threadIdx.x >> 5;
        #pragma unroll
        for (int p = 0; p < 4; ++p) {
            int c = c0 + ty + p * 8;
            tile[ty + p * 8][tx] = src[((size_t)(b * C_ + c) * 3 + t) * N_ + n0 + tx];
        }
        __syncthreads();
        #pragma unroll
        for (int p = 0; p < 4; ++p) {
            int n = n0 + ty + p * 8;
            dst[((size_t)(b * N_ + n) * 3 + t) * C_ + c0 + tx] = tile[tx][ty + p * 8];
        }
    }
}

// fused Wo (XMODE0, y=0,1) + We (XMODE1, y=2,3) -> f12 split (Ostr 256)
__global__ __launch_bounds__(256) void wowe_kernel(
    const u32* __restrict__ Wo, const ush* __restrict__ ao,
    const u32* __restrict__ We, const ush* __restrict__ gb,
    u32* __restrict__ f12)
{
    __shared__ __align__(16) ush Wh[64][64];
    __shared__ __align__(16) ush Xh[64][64];
    const int y = blockIdx.y;
    if (y < 2)
        gemm_tile<0, 1, false, true>(Wo, 128, ao, 128, nullptr, nullptr, f12, nullptr, nullptr,
                        blockIdx.z, blockIdx.x * 64, y * 64, y * 64, 256,
                        Wh, nullptr, Xh, nullptr);
    else
        gemm_tile<1, 1, false, true>(We, 256, gb, 256, nullptr, nullptr, f12, nullptr, nullptr,
                        blockIdx.z, blockIdx.x * 64, (y - 2) * 64, 128 + (y - 2) * 64, 256,
                        Wh, nullptr, Xh, nullptr);
}

// ---------------------------------------------------------------------------
// fused: barrier-free split-K flash attention (blocks 0..2047, XCD-chunked,
// fragment-major coalesced loads) + graph attention (blocks 2048..6143)
// ---------------------------------------------------------------------------
__global__ __launch_bounds__(256) void attn_graph_kernel(
    const ush* __restrict__ vfm, const ush* __restrict__ qktb,
    ush* __restrict__ pacc, float* __restrict__ pml,
    const float* __restrict__ tq, const float* __restrict__ tv,
    const int* __restrict__ idx, ush* __restrict__ gbuf)
{
    __shared__ __align__(16) ush Pl[4][2][16][64];   // 16 KB (shared w/ graph)

    const int tid = threadIdx.x;
    if (blockIdx.x < 2048) {
        // ================= attention =================
        const int flat = blockIdx.x;
        const int xcd  = flat & 7;
        const int slot = flat >> 3;
        const int gid  = xcd * 4 + (slot >> 6);
        const int q32  = slot & 63;
        const int bh   = gid & 15;
        const int zz   = gid >> 4;

        const int lane = tid & 63, wv = tid >> 6;
        const int col = lane & 15, grp = lane >> 4;
        const int c7  = col & 7;
        const int kz  = zz * 4 + wv;
        const int ks0 = kz * (N_ / KSPLIT);

        const ush* Qpl = qktb + (size_t)bh * 131072;
        const ush* Kpl = qktb + (size_t)(16 + bh) * 131072;
        const ush* Vpl = vfm  + (size_t)bh * 98304;

        short8v qf[2][2];
        #pragma unroll
        for (int qi = 0; qi < 2; ++qi) {
            const int qg = q32 * 2 + qi;
            qf[qi][0] = *(const short8v*)(Qpl + ((size_t)qg * 2 + 0) * 512 + lane * 8);
            qf[qi][1] = *(const short8v*)(Qpl + ((size_t)qg * 2 + 1) * 512 + lane * 8);
        }

        f32x4 acc[2][3];
        #pragma unroll
        for (int qi = 0; qi < 2; ++qi)
            #pragma unroll
            for (int db = 0; db < 3; ++db) { f32x4 z = {0.f,0.f,0.f,0.f}; acc[qi][db] = z; }
        float m_i[2] = {0.f, 0.f};
        float l_l[2] = {0.f, 0.f};

        const int NT = (N_ / KSPLIT) / 64;
        for (int mt = 0; mt < NT; ++mt) {
            const int m0 = ks0 + mt * 64;

            short8v ka[4][2];
            #pragma unroll
            for (int kb = 0; kb < 4; ++kb) {
                const size_t kg = (m0 >> 4) + kb;
                ka[kb][0] = *(const short8v*)(Kpl + (kg * 2 + 0) * 512 + lane * 8);
                ka[kb][1] = *(const short8v*)(Kpl + (kg * 2 + 1) * 512 + lane * 8);
            }
            const int kt = m0 >> 6;
            short8v vf[2][3];
            #pragma unroll
            for (int hh = 0; hh < 2; ++hh)
                #pragma unroll
                for (int db = 0; db < 3; ++db)
                    vf[hh][db] = *(const short8v*)(Vpl + (size_t)((kt * 2 + hh) * 3 + db) * 512 + lane * 8);

            f32x4 sf[2][4];
            __builtin_amdgcn_s_setprio(1);
            #pragma unroll
            for (int qi = 0; qi < 2; ++qi)
                #pragma unroll
                for (int kb = 0; kb < 4; ++kb) {
                    f32x4 z = {0.f, 0.f, 0.f, 0.f};
                    z = __builtin_amdgcn_mfma_f32_16x16x32_bf16(ka[kb][0], qf[qi][0], z, 0, 0, 0);
                    z = __builtin_amdgcn_mfma_f32_16x16x32_bf16(ka[kb][1], qf[qi][1], z, 0, 0, 0);
                    sf[qi][kb] = z;
                }
            __builtin_amdgcn_s_setprio(0);

            #pragma unroll
            for (int qi = 0; qi < 2; ++qi) {
                float psum = 0.f;
                #pragma unroll
                for (int kb = 0; kb < 4; ++kb) {
                    float e0 = __expf(sf[qi][kb][0] - m_i[qi]);
                    float e1 = __expf(sf[qi][kb][1] - m_i[qi]);
                    float e2 = __expf(sf[qi][kb][2] - m_i[qi]);
                    float e3 = __expf(sf[qi][kb][3] - m_i[qi]);
                    psum += (e0 + e1) + (e2 + e3);
                    u32 r0, r1;
                    asm("v_cvt_pk_bf16_f32 %0, %1, %2" : "=v"(r0) : "v"(e0), "v"(e1));
                    asm("v_cvt_pk_bf16_f32 %0, %1, %2" : "=v"(r1) : "v"(e2), "v"(e3));
                    const int un = (4 * kb + grp) ^ (c7 << 1);
                    uint2 pk2; pk2.x = r0; pk2.y = r1;
                    *(uint2*)&Pl[wv][qi][col][un << 2] = pk2;
                }
                l_l[qi] += psum;
            }

            __builtin_amdgcn_s_setprio(1);
            #pragma unroll
            for (int qi = 0; qi < 2; ++qi)
                #pragma unroll
                for (int hh = 0; hh < 2; ++hh) {
                    const int ur = (8 * hh + 2 * grp) ^ (c7 << 1);
                    short8v pf = *(const short8v*)&Pl[wv][qi][col][ur << 2];
                    #pragma unroll
                    for (int db = 0; db < 3; ++db)
                        acc[qi][db] = __builtin_amdgcn_mfma_f32_16x16x32_bf16(vf[hh][db], pf, acc[qi][db], 0, 0, 0);
                }
            __builtin_amdgcn_s_setprio(0);

            #pragma unroll
            for (int qi = 0; qi < 2; ++qi) {
                float pmax = -1e30f;
                #pragma unroll
                for (int kb = 0; kb < 4; ++kb)
                    #pragma unroll
                    for (int r = 0; r < 4; ++r) pmax = fmaxf(pmax, sf[qi][kb][r]);
                pmax = fmaxf(pmax, __shfl_xor(pmax, 16, 64));
                pmax = fmaxf(pmax, __shfl_xor(pmax, 32, 64));
                if (!__all(pmax - m_i[qi] <= 8.0f)) {
                    float mnew = fmaxf(m_i[qi], pmax);
                    float sc = __expf(m_i[qi] - mnew);
                    l_l[qi] *= sc;
                    #pragma unroll
                    for (int db = 0; db < 3; ++db) {
                        acc[qi][db][0] *= sc; acc[qi][db][1] *= sc;
                        acc[qi][db][2] *= sc; acc[qi][db][3] *= sc;
                    }
                    m_i[qi] = mnew;
                }
            }
        }

        const int ntile = q32 >> 1, qh = q32 & 1;
        const size_t pb = (size_t)(kz * 16 + bh) * 32 + ntile;
        #pragma unroll
        for (int qi = 0; qi < 2; ++qi) {
            float l = l_l[qi];
            l += __shfl_xor(l, 16, 64);
            l += __shfl_xor(l, 32, 64);
            const int q = qh * 32 + qi * 16 + col;
            #pragma unroll
            for (int db = 0; db < 3; ++db)
                #pragma unroll
                for (int r = 0; r < 4; ++r) {
                    int d = db * 16 + grp * 4 + r;
                    pacc[pb * 3072 + d * 64 + q] = f2bf(acc[qi][db][r]);
                }
            if (grp == 0) {
                pml[pb * 128 + q]      = m_i[qi];
                pml[pb * 128 + 64 + q] = l;
            }
        }
    } else {
        // ================= graph attention =================
        const int j = blockIdx.x - 2048;
        const int b = j >> 11, n = j & 2047;
        float* center = (float*)Pl;
        float* sd = center + 384;
        int* nbr_i = (int*)(sd + 16);

        const float* qrow = tq + (size_t)(b * N_ + n) * 384;
        for (int e = tid; e < 384; e += 256) center[e] = qrow[e];
        if (tid < 16) nbr_i[tid] = idx[(size_t)(b * N_ + n) * 16 + tid];
        __syncthreads();

        const int lane = tid & 63, wv = tid >> 6;
        for (int kk = 0; kk < 4; ++kk) {
            int k = wv * 4 + kk;
            const float* vrow = tv + ((size_t)b * N_ + nbr_i[k]) * 384;
            float p = 0.f;
            #pragma unroll
            for (int jj = 0; jj < 6; ++jj) {
                int e = lane + jj * 64;
                p += center[e] * vrow[e];
            }
            #pragma unroll
            for (int off = 32; off; off >>= 1) p += __shfl_down(p, off, 64);
            if (lane == 0) sd[k] = p * 0.05103103630798288f;
        }
        __syncthreads();

        float mx = -1e30f;
        #pragma unroll
        for (int k = 0; k < 16; ++k) mx = fmaxf(mx, sd[k]);
        float a[16]; float ssum = 0.f;
        #pragma unroll
        for (int k = 0; k < 16; ++k) { a[k] = __expf(sd[k] - mx); ssum += a[k]; }
        float inv = 1.f / ssum;

        for (int e = tid; e < 384; e += 256) {
            float accv = 0.f;
            #pragma unroll
            for (int k = 0; k < 16; ++k)
                accv += a[k] * tv[((size_t)b * N_ + nbr_i[k]) * 384 + e];
            accv *= inv;
            float ce = center[e];
            int t = e >> 7, c = e & 127;
            size_t gb = ((size_t)(b * N_ + n) * 3 + t) * 256;
            gbuf[gb + c]       = f2bf(accv - ce);
            gbuf[gb + 128 + c] = f2bf(ce);
        }
    }
}

// ---------------------------------------------------------------------------
// split-K reduce: combine KSPLIT partials -> bf16 ao
// ---------------------------------------------------------------------------
__global__ __launch_bounds__(256) void attn_reduce_kernel(
    const ush* __restrict__ pacc, const float* __restrict__ pml,
    ush* __restrict__ ao)
{
    const int nt = blockIdx.x, bh = blockIdx.y;
    const int b = bh >> 3, h = bh & 7;
    const int tid = threadIdx.x;
    const int q = tid & 63, dg = tid >> 6;

    size_t pb[KSPLIT];
    float m[KSPLIT], l[KSPLIT];
    #pragma unroll
    for (int kz = 0; kz < KSPLIT; ++kz) {
        pb[kz] = (size_t)(kz * 16 + bh) * 32 + nt;
        m[kz] = pml[pb[kz] * 128 + q];
        l[kz] = pml[pb[kz] * 128 + 64 + q];
    }
    float ms = -1e30f;
    #pragma unroll
    for (int kz = 0; kz < KSPLIT; ++kz) ms = fmaxf(ms, m[kz]);
    float w[KSPLIT], ls = 0.f;
    #pragma unroll
    for (int kz = 0; kz < KSPLIT; ++kz) { w[kz] = __expf(m[kz] - ms); ls += l[kz] * w[kz]; }
    const float inv = 1.f / ls;

    const size_t hb = ((size_t)(b * C_ + h * 16)) * 3 * N_;
    #pragma unroll
    for (int j = 0; j < 12; ++j) {
        int d = dg * 12 + j;
        float o = 0.f;
        #pragma unroll
        for (int kz = 0; kz < KSPLIT; ++kz)
            o += bf2f(pacc[pb[kz] * 3072 + d * 64 + q]) * w[kz];
        ao[hb + (size_t)d * N_ + nt * 64 + q] = f2bf(o * inv);
    }
}

// ---------------------------------------------------------------------------
// vn_leaky: fp32 x,d in -> split u32 out
// ---------------------------------------------------------------------------
__global__ __launch_bounds__(256) void leaky_kernel(const float* __restrict__ x,
                                                    const float* __restrict__ d,
                                                    u32* __restrict__ y)
{
    size_t p = (size_t)blockIdx.x * 256 + threadIdx.x;
    size_t bh = p / N_, n = p % N_;
    size_t base = bh * 3 * N_ + n;
    float x0 = x[base], x1 = x[base + N_], x2 = x[base + 2 * N_];
    float d0 = d[base], d1 = d[base + N_], d2 = d[base + 2 * N_];
    float dot = x0 * d0 + x1 * d1 + x2 * d2;
    float dsq = d0 * d0 + d1 * d1 + d2 * d2;
    float f = dot / (dsq + EPS_);
    bool pos = dot >= 0.f;
    float y0 = pos ? x0 : x0 - f * d0;
    float y1 = pos ? x1 : x1 - f * d1;
    float y2 = pos ? x2 : x2 - f * d2;
    y[base]          = splitpack(NS_ * x0 + (1.f - NS_) * y0);
    y[base + N_]     = splitpack(NS_ * x1 + (1.f - NS_) * y1);
    y[base + 2 * N_] = splitpack(NS_ * x2 + (1.f - NS_) * y2);
}

// ---------------------------------------------------------------------------
extern "C" void kernel_launch(void* const* d_in, const int* in_sizes, int n_in,
                              void* d_out, int out_size, void* d_ws, size_t ws_size,
                              hipStream_t stream)
{
    const float* q_in = (const float*)d_in[0];
    const float* v_in = (const float*)d_in[1];
    const int*   idx_s = (const int*)d_in[4];
    const int*   idx_c = (const int*)d_in[5];
    const float* g1 = (const float*)d_in[6];
    const float* b1 = (const float*)d_in[7];
    const float* g2 = (const float*)d_in[8];
    const float* b2 = (const float*)d_in[9];
    const float* gq = (const float*)d_in[10];
    const float* bq = (const float*)d_in[11];
    const float* gv = (const float*)d_in[12];
    const float* bv = (const float*)d_in[13];
    float* out = (float*)d_out;
    float* ws  = (float*)d_ws;

    const size_t S1 = (size_t)B_ * C_ * 3 * N_; // 1572864 elems
    float* nx    = ws;                 // 0
    float* nv    = ws + S1;            // 1
    ush*   nx_b  = (ush*)(ws + 2*S1);  // 2 (half)
    ush*   nv_b  = (ush*)(ws + 3*S1);  // 3 (half)
    ush*   vfm   = (ush*)(ws + 4*S1);  // 4: 16*98304*2B = 3MB
    ush*   qktb  = (ush*)(ws + 5*S1) + S1;  // 5.5-6.84: 32*131072*2B = 8.4MB
    ush*   ao_b  = (ush*)(ws + 7*S1);  // 7 (half)
    u32*   f12_s = (u32*)(ws + 8*S1);  // 8-9
    float* qa    = ws + 12*S1;         // 12
    float* qb    = ws + 13*S1;         // 13 (gbuf_b aliases pre-Wm)
    ush*   gbuf_b= (ush*)(ws + 13*S1); // 13 as ush (6.3MB), consumed before qb write
    float* t1    = ws + 14*S1;         // 14
    float* t2    = ws + 15*S1;         // 15
    u32*   wsp   = (u32*)(ws + 16*S1); // 16+
    // split-K attention partials (attn->reduce window only)
    ush*   pacc  = (ush*)(ws + 8*S1);  // 8-11: 4096*3072*2B = 25.2MB
    float* pml   = (float*)(ws + 2*S1);// 2 (attn after qkv consumed nx_b)
    // phase C aliases:
    float* hd    = ws;                 // 0-3
    float* h1    = ws + 4*S1;          // 4-7
    u32*   h1_s  = (u32*)(ws + 8*S1);  // 8-11
    ush*   h1_b  = (ush*)(ws + 14*S1); // 14-15

    const int wn[15]  = {16384,16384,16384,16384,32768,32768,
                         16384,16384,16384,16384,32768,32768,
                         65536,262144,65536};
    u32* wd[15];
    {
        int off = 0;
        for (int i = 0; i < 15; ++i) { wd[i] = wsp + off; off += wn[i]; }
    }
    u32 *Wq_s = wd[0], *Wk_s = wd[1], *Wv_s = wd[2], *Wo_s = wd[3], *We_s = wd[4], *Wm_s = wd[5];
    u32 *Wq_c = wd[6], *Wk_c = wd[7], *Wv_c = wd[8], *Wo_c = wd[9], *We_c = wd[10], *Wm_c = wd[11];
    u32 *W1 = wd[12], *Dact = wd[13], *W2 = wd[14];

    // zero qktb once (d=48..63 pad slots must be 0; qkv only writes d<48)
    hipMemsetAsync(qktb, 0, (size_t)32 * 131072 * sizeof(ush), stream);

    {
        WCArgs a;
        for (int i = 0; i < 15; ++i) {
            a.src[i] = (const float*)d_in[14 + i];
            a.dst[i] = wd[i];
            a.n[i]   = wn[i];
            a.scale[i] = 1.f;
        }
        a.scale[0] = 0.14433756729740643f;  // Wq_s: fold 1/sqrt(48)
        a.scale[6] = 0.14433756729740643f;  // Wq_c
        wconv_kernel<<<dim3(1024, 15), 256, 0, stream>>>(a);
    }

    dim3 gar(N_ / 64, B_ * HEADS_);
    dim3 gwe(96, 4, B_);
    dim3 gg128(96, 2, B_);
    dim3 gg512(96, 8, B_);

    // ---- Phase A: self attention block ----
    {
        LNArgs la{};
        la.x[0] = q_in; la.g[0] = g1; la.bt[0] = b1; la.y[0] = nx; la.ysp[0] = nx_b;
        ln_kernel<<<dim3(64, B_, 1), 256, 0, stream>>>(la);
    }
    {
        QKVArgs A{Wq_s, Wk_s, Wv_s, nx_b, nx_b, nx_b};
        qkv_tr_kernel<<<dim3(1152 + 1536), 256, 0, stream>>>(A, vfm, qktb, nx, t1, nullptr, nullptr);
    }
    attn_graph_kernel<<<dim3(6144), 256, 0, stream>>>(vfm, qktb, pacc, pml, t1, t1, idx_s, gbuf_b);
    attn_reduce_kernel<<<gar, 256, 0, stream>>>(pacc, pml, ao_b);
    wowe_kernel<<<gwe, 256, 0, stream>>>(Wo_s, ao_b, We_s, gbuf_b, f12_s);
    gemm_kernel2<0,0,true,false><<<gg128, 256, 0, stream>>>(Wm_s, 256, f12_s, q_in, qa, nullptr, nullptr, 128, 0, 256);

    // ---- Phase B: cross attention block ----
    {
        LNArgs la{};
        la.x[0] = qa;   la.g[0] = gq; la.bt[0] = bq; la.y[0] = nx; la.ysp[0] = nx_b;
        la.x[1] = v_in; la.g[1] = gv; la.bt[1] = bv; la.y[1] = nv; la.ysp[1] = nv_b;
        ln_kernel<<<dim3(64, B_, 2), 256, 0, stream>>>(la);
    }
    {
        QKVArgs A{Wq_c, Wk_c, Wv_c, nx_b, nv_b, nv_b};
        qkv_tr_kernel<<<dim3(1152 + 3072), 256, 0, stream>>>(A, vfm, qktb, nx, t1, nv, t2);
    }
    attn_graph_kernel<<<dim3(6144), 256, 0, stream>>>(vfm, qktb, pacc, pml, t1, t2, idx_c, gbuf_b);
    attn_reduce_kernel<<<gar, 256, 0, stream>>>(pacc, pml, ao_b);
    wowe_kernel<<<gwe, 256, 0, stream>>>(Wo_c, ao_b, We_c, gbuf_b, f12_s);
    gemm_kernel2<0,0,true,false><<<gg128, 256, 0, stream>>>(Wm_c, 256, f12_s, qa, qb, nullptr, nullptr, 128, 0, 256);

    // ---- Phase C: vector MLP ----
    {
        LNArgs la{};
        la.x[0] = qb; la.g[0] = g2; la.bt[0] = b2; la.y[0] = nullptr; la.ysp[0] = nx_b;
        ln_kernel<<<dim3(64, B_, 1), 256, 0, stream>>>(la);
    }
    gemm_kernel2<0,5,false,true><<<gg512, 256, 0, stream>>>(W1, 128, nx_b, nullptr, h1, nullptr, h1_b, 512, 0, 128);
    gemm_kernel2<0,0,false,true><<<gg512, 256, 0, stream>>>(Dact, 512, h1_b, nullptr, hd, nullptr, nullptr, 512, 0, 512);
    leaky_kernel<<<dim3((B_ * HID_ * N_) / 256), 256, 0, stream>>>(h1, hd, h1_s);
    gemm_kernel2<0,0,true,false><<<gg128, 256, 0, stream>>>(W2, 512, h1_s, qb, out, nullptr, nullptr, 128, 0, 512);
}

// Round 13
// 293.740 us; speedup vs baseline: 1.1040x; 1.1040x over previous
//
#include <hip/hip_runtime.h>
#include <math.h>

#define B_    2
#define C_    128
#define N_    2048
#define HID_  512
#define HEADS_ 8
#define EPS_  1e-6f
#define NS_   0.2f
#define KSPLIT 8

typedef __attribute__((ext_vector_type(8))) short short8v;  // 8 bf16
typedef __attribute__((ext_vector_type(4))) float f32x4;
typedef unsigned short ush;
typedef unsigned int u32;

__device__ inline ush f2bf(float f) {
    unsigned u = __float_as_uint(f);
    u += 0x7FFF + ((u >> 16) & 1);          // round-to-nearest-even
    return (ush)(u >> 16);
}
__device__ inline float bf2f(ush u) { return __uint_as_float((u32)u << 16); }

// pack float -> (hi bf16 << 16) | lo bf16, with hi+lo ~ x to ~2^-17 rel
__device__ inline u32 splitpack(float x) {
    ush hi = f2bf(x);
    float hf = __uint_as_float((u32)hi << 16);
    ush lo = f2bf(x - hf);
    return ((u32)hi << 16) | (u32)lo;
}

__device__ inline void unpack16(const u32* buf, short8v& h0, short8v& h1,
                                short8v& l0, short8v& l1) {
    ush h[16], l[16];
    #pragma unroll
    for (int j = 0; j < 16; ++j) { u32 u = buf[j]; h[j] = (ush)(u >> 16); l[j] = (ush)(u & 0xffff); }
    h0 = *(short8v*)&h[0]; h1 = *(short8v*)&h[8];
    l0 = *(short8v*)&l[0]; l1 = *(short8v*)&l[8];
}

__device__ inline void unpack_hi(const u32* buf, short8v& h0, short8v& h1) {
    ush h[16];
    #pragma unroll
    for (int j = 0; j < 16; ++j) h[j] = (ush)(buf[j] >> 16);
    h0 = *(short8v*)&h[0]; h1 = *(short8v*)&h[8];
}

// ---------------------------------------------------------------------------
// vec_layernorm, z-indexed multi-input: writes bf16 plane ysp and optional
// fp32 y (for transpose/graph consumers)
// ---------------------------------------------------------------------------
struct LNArgs {
    const float* x[2]; const float* g[2]; const float* bt[2];
    float* y[2]; ush* ysp[2];
};
__global__ __launch_bounds__(256) void ln_kernel(LNArgs a)
{
    __shared__ float norms[128][32];
    __shared__ float red1[8][32];
    __shared__ float red2[8][32];
    const int s = blockIdx.z;
    const float* x = a.x[s];
    const float* gma = a.g[s];
    const float* bta = a.bt[s];
    float* y = a.y[s];
    ush* ysp = a.ysp[s];

    const int b  = blockIdx.y;
    const int n0 = blockIdx.x * 32;
    const int nn = threadIdx.x & 31;
    const int cg = threadIdx.x >> 5;

    float s1 = 0.f, s2 = 0.f;
    for (int it = 0; it < 16; ++it) {
        int c = it * 8 + cg;
        size_t base = ((size_t)(b * C_ + c) * 3) * N_ + n0 + nn;
        float x0 = x[base], x1 = x[base + N_], x2 = x[base + 2 * N_];
        float nr = sqrtf(x0 * x0 + x1 * x1 + x2 * x2 + EPS_);
        norms[c][nn] = nr;
        s1 += nr; s2 += nr * nr;
    }
    red1[cg][nn] = s1; red2[cg][nn] = s2;
    __syncthreads();
    float S1 = 0.f, S2 = 0.f;
    #pragma unroll
    for (int g = 0; g < 8; ++g) { S1 += red1[g][nn]; S2 += red2[g][nn]; }
    float mu   = S1 * (1.f / 128.f);
    float var  = S2 * (1.f / 128.f) - mu * mu;
    float rstd = rsqrtf(var + EPS_);

    for (int it = 0; it < 16; ++it) {
        int c = it * 8 + cg;
        float nr = norms[c][nn];
        float ln = (nr - mu) * rstd * gma[c] + bta[c];
        float sc = ln / (nr + EPS_);
        size_t base = ((size_t)(b * C_ + c) * 3) * N_ + n0 + nn;
        float y0 = x[base] * sc, y1 = x[base + N_] * sc, y2 = x[base + 2 * N_] * sc;
        if (y) {
            y[base]          = y0;
            y[base + N_]     = y1;
            y[base + 2 * N_] = y2;
        }
        ysp[base]          = f2bf(y0);
        ysp[base + N_]     = f2bf(y1);
        ysp[base + 2 * N_] = f2bf(y2);
    }
}

// ---------------------------------------------------------------------------
// weight split-conversion: 15 weights, one launch (with optional pre-scale)
// ---------------------------------------------------------------------------
struct WCArgs { const float* src[15]; u32* dst[15]; int n[15]; float scale[15]; };
__global__ __launch_bounds__(256) void wconv_kernel(WCArgs a)
{
    const int w = blockIdx.y;
    const int i = blockIdx.x * 256 + threadIdx.x;
    if (i < a.n[w]) a.dst[w][i] = splitpack(a.src[w][i] * a.scale[w]);
}

// ---------------------------------------------------------------------------
// bf16 MFMA GEMM core. SPLIT: 3-term fp32-quality. XBF: X input is bf16 ush.
// XMODE 0: X[(b*K + c)*M + m]   XMODE 1: X[((b*N+n)*3+t)*K + c], m = t*N+n
// OMODE 0: fp32(+Z)  1: split u32  4: qkv fragment-major  5: fp32 + bf16
// ---------------------------------------------------------------------------
template <int XMODE, int OMODE, bool SPLIT, bool XBF>
__device__ __forceinline__ void gemm_tile(
    const u32* __restrict__ Wsp, int wstride,
    const void* __restrict__ Xv, int K,
    const float* __restrict__ Z, float* __restrict__ Y, u32* __restrict__ Ysp,
    ush* __restrict__ Ybf, ush* __restrict__ Ytr,
    int b, int m0, int o0loc, int oglob, int Ostr,
    ush (*Wh)[64], ush (*Wl)[64], ush (*Xh)[64], ush (*Xl)[64])
{
    const int M = 3 * N_;
    const int tid = threadIdx.x;
    const int lane = tid & 63, wv = tid >> 6;
    const int col = lane & 15, grp = lane >> 4;
    const int wo = wv >> 1, wm = wv & 1;

    f32x4 acc[2][2];
    #pragma unroll
    for (int i = 0; i < 2; ++i)
        #pragma unroll
        for (int j = 0; j < 2; ++j) { f32x4 z = {0.f,0.f,0.f,0.f}; acc[i][j] = z; }

    for (int kk = 0; kk < K; kk += 64) {
        // ---- stage W tile (64 o x 64 k), split u32 source ----
        {
            const int o = tid >> 2, kg = tid & 3;
            const u32* src = Wsp + (size_t)(o0loc + o) * wstride + kk + kg * 16;
            u32 buf[16];
            #pragma unroll
            for (int j = 0; j < 4; ++j) *(uint4*)&buf[j * 4] = *(const uint4*)(src + j * 4);
            const int s0 = ((kg * 2)     ^ (o & 7)) << 3;
            const int s1 = ((kg * 2 + 1) ^ (o & 7)) << 3;
            if (SPLIT) {
                short8v h0, h1, l0, l1; unpack16(buf, h0, h1, l0, l1);
                *(short8v*)&Wh[o][s0] = h0; *(short8v*)&Wh[o][s1] = h1;
                *(short8v*)&Wl[o][s0] = l0; *(short8v*)&Wl[o][s1] = l1;
            } else {
                short8v h0, h1; unpack_hi(buf, h0, h1);
                *(short8v*)&Wh[o][s0] = h0; *(short8v*)&Wh[o][s1] = h1;
            }
        }
        // ---- stage X tile (64 k x 64 m), stored transposed Xs[m][k] ----
        if (XMODE == 0) {
            const int m = lane, kq = wv;
            const int s0 = ((kq * 2)     ^ (m & 7)) << 3;
            const int s1 = ((kq * 2 + 1) ^ (m & 7)) << 3;
            if (XBF) {
                const ush* src = (const ush*)Xv + ((size_t)b * K + kk + kq * 16) * M + m0 + m;
                ush h[16];
                #pragma unroll
                for (int j = 0; j < 16; ++j) h[j] = src[(size_t)j * M];
                *(short8v*)&Xh[m][s0] = *(short8v*)&h[0];
                *(short8v*)&Xh[m][s1] = *(short8v*)&h[8];
            } else {
                const u32* src = (const u32*)Xv + ((size_t)b * K + kk + kq * 16) * M + m0 + m;
                u32 buf[16];
                #pragma unroll
                for (int j = 0; j < 16; ++j) buf[j] = src[(size_t)j * M];
                if (SPLIT) {
                    short8v h0, h1, l0, l1; unpack16(buf, h0, h1, l0, l1);
                    *(short8v*)&Xh[m][s0] = h0; *(short8v*)&Xh[m][s1] = h1;
                    *(short8v*)&Xl[m][s0] = l0; *(short8v*)&Xl[m][s1] = l1;
                } else {
                    short8v h0, h1; unpack_hi(buf, h0, h1);
                    *(short8v*)&Xh[m][s0] = h0; *(short8v*)&Xh[m][s1] = h1;
                }
            }
        } else {
            const int m = tid >> 2, kg = tid & 3;
            const int mg = m0 + m;
            const int n = mg & (N_ - 1), t = mg >> 11;
            const int s0 = ((kg * 2)     ^ (m & 7)) << 3;
            const int s1 = ((kg * 2 + 1) ^ (m & 7)) << 3;
            if (XBF) {
                const ush* src = (const ush*)Xv + ((size_t)(b * N_ + n) * 3 + t) * K + kk + kg * 16;
                ush h[16];
                *(uint4*)&h[0] = *(const uint4*)(src);
                *(uint4*)&h[8] = *(const uint4*)(src + 8);
                *(short8v*)&Xh[m][s0] = *(short8v*)&h[0];
                *(short8v*)&Xh[m][s1] = *(short8v*)&h[8];
            } else {
                const u32* src = (const u32*)Xv + ((size_t)(b * N_ + n) * 3 + t) * K + kk + kg * 16;
                u32 buf[16];
                #pragma unroll
                for (int j = 0; j < 4; ++j) *(uint4*)&buf[j * 4] = *(const uint4*)(src + j * 4);
                if (SPLIT) {
                    short8v h0, h1, l0, l1; unpack16(buf, h0, h1, l0, l1);
                    *(short8v*)&Xh[m][s0] = h0; *(short8v*)&Xh[m][s1] = h1;
                    *(short8v*)&Xl[m][s0] = l0; *(short8v*)&Xl[m][s1] = l1;
                } else {
                    short8v h0, h1; unpack_hi(buf, h0, h1);
                    *(short8v*)&Xh[m][s0] = h0; *(short8v*)&Xh[m][s1] = h1;
                }
            }
        }
        __syncthreads();
        // ---- MFMAs per K-step: 8 (hi-only) or 24 (split) ----
        #pragma unroll
        for (int kc = 0; kc < 2; ++kc) {
            const int sk = ((kc * 4 + grp) ^ (col & 7)) << 3;
            short8v ah0 = *(const short8v*)&Wh[wo * 32 + col][sk];
            short8v ah1 = *(const short8v*)&Wh[wo * 32 + 16 + col][sk];
            short8v xh0 = *(const short8v*)&Xh[wm * 32 + col][sk];
            short8v xh1 = *(const short8v*)&Xh[wm * 32 + 16 + col][sk];
            acc[0][0] = __builtin_amdgcn_mfma_f32_16x16x32_bf16(ah0, xh0, acc[0][0], 0, 0, 0);
            acc[0][1] = __builtin_amdgcn_mfma_f32_16x16x32_bf16(ah0, xh1, acc[0][1], 0, 0, 0);
            acc[1][0] = __builtin_amdgcn_mfma_f32_16x16x32_bf16(ah1, xh0, acc[1][0], 0, 0, 0);
            acc[1][1] = __builtin_amdgcn_mfma_f32_16x16x32_bf16(ah1, xh1, acc[1][1], 0, 0, 0);
            if (SPLIT) {
                short8v al0 = *(const short8v*)&Wl[wo * 32 + col][sk];
                short8v al1 = *(const short8v*)&Wl[wo * 32 + 16 + col][sk];
                short8v xl0 = *(const short8v*)&Xl[wm * 32 + col][sk];
                short8v xl1 = *(const short8v*)&Xl[wm * 32 + 16 + col][sk];
                acc[0][0] = __builtin_amdgcn_mfma_f32_16x16x32_bf16(ah0, xl0, acc[0][0], 0, 0, 0);
                acc[0][1] = __builtin_amdgcn_mfma_f32_16x16x32_bf16(ah0, xl1, acc[0][1], 0, 0, 0);
                acc[1][0] = __builtin_amdgcn_mfma_f32_16x16x32_bf16(ah1, xl0, acc[1][0], 0, 0, 0);
                acc[1][1] = __builtin_amdgcn_mfma_f32_16x16x32_bf16(ah1, xl1, acc[1][1], 0, 0, 0);
                acc[0][0] = __builtin_amdgcn_mfma_f32_16x16x32_bf16(al0, xh0, acc[0][0], 0, 0, 0);
                acc[0][1] = __builtin_amdgcn_mfma_f32_16x16x32_bf16(al0, xh1, acc[0][1], 0, 0, 0);
                acc[1][0] = __builtin_amdgcn_mfma_f32_16x16x32_bf16(al1, xh0, acc[1][0], 0, 0, 0);
                acc[1][1] = __builtin_amdgcn_mfma_f32_16x16x32_bf16(al1, xh1, acc[1][1], 0, 0, 0);
            }
        }
        __syncthreads();
    }
    // ---- epilogue ----
    #pragma unroll
    for (int of = 0; of < 2; ++of) {
        #pragma unroll
        for (int r = 0; r < 4; ++r) {
            const int o = oglob + wo * 32 + of * 16 + grp * 4 + r;
            #pragma unroll
            for (int mf = 0; mf < 2; ++mf) {
                const int mloc = m0 + wm * 32 + mf * 16 + col;
                const size_t idx = ((size_t)b * Ostr + o) * M + mloc;
                float v = acc[of][mf][r];
                if (OMODE == 0 || OMODE == 5) {
                    if (Z) v += Z[idx];
                    Y[idx] = v;
                }
                if (OMODE == 1) Ysp[idx] = splitpack(v);
                if (OMODE == 5) Ybf[idx] = f2bf(v);
                if (OMODE == 4) {
                    ush bv = f2bf(v);
                    const int t = mloc >> 11, n = mloc & (N_ - 1);
                    const int h = (o >> 4) & 7, cl = o & 15;
                    const int d = cl * 3 + t;
                    if (o >= 256) {
                        const int kt = n >> 6, hh = (n >> 5) & 1, db = d >> 4;
                        const size_t idx2 = ((size_t)(b * 8 + h) * 192
                                           + (kt * 2 + hh) * 3 + db) * 512
                                          + (((n >> 3) & 3) * 16 + (d & 15)) * 8 + (n & 7);
                        Ybf[idx2] = bv;
                    } else {
                        const int isK = (o >> 7) & 1;
                        const int qg = n >> 4, half = d >> 5;
                        const size_t idx2 = ((size_t)(isK * 16 + b * 8 + h) * 256
                                           + qg * 2 + half) * 512
                                          + (((d >> 3) & 3) * 16 + (n & 15)) * 8 + (d & 7);
                        Ytr[idx2] = bv;
                    }
                }
            }
        }
    }
}

template <int XMODE, int OMODE, bool SPLIT, bool XBF>
__global__ __launch_bounds__(256) void gemm_kernel2(
    const u32* __restrict__ Wsp, int wstride,
    const void* __restrict__ Xv,
    const float* __restrict__ Z,
    float* __restrict__ Y, u32* __restrict__ Ysp, ush* __restrict__ Ybf,
    int Ostr, int obase, int K)
{
    if (SPLIT) {
        __shared__ __align__(16) ush Wh[64][64];
        __shared__ __align__(16) ush Wl[64][64];
        __shared__ __align__(16) ush Xh[64][64];
        __shared__ __align__(16) ush Xl[64][64];
        gemm_tile<XMODE, OMODE, true, XBF>(Wsp, wstride, Xv, K, Z, Y, Ysp, Ybf, nullptr,
                                blockIdx.z, blockIdx.x * 64,
                                blockIdx.y * 64, obase + blockIdx.y * 64, Ostr,
                                Wh, Wl, Xh, Xl);
    } else {
        __shared__ __align__(16) ush Wh[64][64];
        __shared__ __align__(16) ush Xh[64][64];
        gemm_tile<XMODE, OMODE, false, XBF>(Wsp, wstride, Xv, K, Z, Y, Ysp, Ybf, nullptr,
                                blockIdx.z, blockIdx.x * 64,
                                blockIdx.y * 64, obase + blockIdx.y * 64, Ostr,
                                Wh, nullptr, Xh, nullptr);
    }
}

struct QKVArgs {
    const u32* W0; const u32* W1; const u32* W2;
    const ush* X0; const ush* X1; const ush* X2;
};

// fused: qkv projections (blocks 0..1151, fragment-major outputs) +
// transpose(s) (blocks 1152.., (B,C,3,N) fp32 -> (B,N,3,C))
__global__ __launch_bounds__(256) void qkv_tr_kernel(QKVArgs A,
        ush* __restrict__ vfm, ush* __restrict__ qktb,
        const float* __restrict__ ts0, float* __restrict__ td0,
        const float* __restrict__ ts1, float* __restrict__ td1)
{
    __shared__ __align__(16) ush Wh[64][64];
    __shared__ __align__(16) ush Xh[64][64];
    const int bx = blockIdx.x;
    if (bx < 1152) {
        const int z = bx / 576, rem = bx % 576;
        const int y = rem / 96, x = rem % 96;
        const int wi = y >> 1;
        const u32* W = wi == 0 ? A.W0 : (wi == 1 ? A.W1 : A.W2);
        const ush* X = wi == 0 ? A.X0 : (wi == 1 ? A.X1 : A.X2);
        gemm_tile<0, 4, false, true>(W, 128, X, 128, nullptr, nullptr, nullptr, vfm, qktb,
                        z, x * 64, (y & 1) * 64, y * 64, 384,
                        Wh, nullptr, Xh, nullptr);
    } else {
        int i = bx - 1152;
        const int which = i / 1536; i %= 1536;
        const float* src = which ? ts1 : ts0;
        float* dst = which ? td1 : td0;
        const int x = i & 63, y = (i >> 6) & 3, z = i >> 8;
        const int b = z / 3, t = z % 3;
        const int n0 = x * 32, c0 = y * 32;
        float (*tile)[33] = (float(*)[33])Wh;
        const int tx = threadIdx.x & 31, ty = threadIdx.x >> 5;
        #pragma unroll
        for (int p = 0; p < 4; ++p) {
            int c = c0 + ty + p * 8;
            tile[ty + p * 8][tx] = src[((size_t)(b * C_ + c) * 3 + t) * N_ + n0 + tx];
        }
        __syncthreads();
        #pragma unroll
        for (int p = 0; p < 4; ++p) {
            int n = n0 + ty + p * 8;
            dst[((size_t)(b * N_ + n) * 3 + t) * C_ + c0 + tx] = tile[tx][ty + p * 8];
        }
    }
}

// fused Wo (XMODE0, y=0,1) + We (XMODE1, y=2,3) -> f12 split (Ostr 256)
__global__ __launch_bounds__(256) void wowe_kernel(
    const u32* __restrict__ Wo, const ush* __restrict__ ao,
    const u32* __restrict__ We, const ush* __restrict__ gb,
    u32* __restrict__ f12)
{
    __shared__ __align__(16) ush Wh[64][64];
    __shared__ __align__(16) ush Xh[64][64];
    const int y = blockIdx.y;
    if (y < 2)
        gemm_tile<0, 1, false, true>(Wo, 128, ao, 128, nullptr, nullptr, f12, nullptr, nullptr,
                        blockIdx.z, blockIdx.x * 64, y * 64, y * 64, 256,
                        Wh, nullptr, Xh, nullptr);
    else
        gemm_tile<1, 1, false, true>(We, 256, gb, 256, nullptr, nullptr, f12, nullptr, nullptr,
                        blockIdx.z, blockIdx.x * 64, (y - 2) * 64, 128 + (y - 2) * 64, 256,
                        Wh, nullptr, Xh, nullptr);
}

// ---------------------------------------------------------------------------
// barrier-free split-K flash attention, XCD-chunked 1D grid (2048 blocks),
// fragment-major coalesced operands (verified round-10/11 configuration).
// ---------------------------------------------------------------------------
__global__ __launch_bounds__(256) void attn_mfma_kernel(
    const ush* __restrict__ vfm, const ush* __restrict__ qktb,
    ush* __restrict__ pacc, float* __restrict__ pml)
{
    __shared__ __align__(16) ush Pl[4][2][16][64];   // 16 KB

    const int flat = blockIdx.x;
    const int xcd  = flat & 7;
    const int slot = flat >> 3;
    const int gid  = xcd * 4 + (slot >> 6);
    const int q32  = slot & 63;
    const int bh   = gid & 15;
    const int zz   = gid >> 4;

    const int tid = threadIdx.x;
    const int lane = tid & 63, wv = tid >> 6;
    const int col = lane & 15, grp = lane >> 4;
    const int c7  = col & 7;
    const int kz  = zz * 4 + wv;
    const int ks0 = kz * (N_ / KSPLIT);

    const ush* Qpl = qktb + (size_t)bh * 131072;
    const ush* Kpl = qktb + (size_t)(16 + bh) * 131072;
    const ush* Vpl = vfm  + (size_t)bh * 98304;

    short8v qf[2][2];
    #pragma unroll
    for (int qi = 0; qi < 2; ++qi) {
        const int qg = q32 * 2 + qi;
        qf[qi][0] = *(const short8v*)(Qpl + ((size_t)qg * 2 + 0) * 512 + lane * 8);
        qf[qi][1] = *(const short8v*)(Qpl + ((size_t)qg * 2 + 1) * 512 + lane * 8);
    }

    f32x4 acc[2][3];
    #pragma unroll
    for (int qi = 0; qi < 2; ++qi)
        #pragma unroll
        for (int db = 0; db < 3; ++db) { f32x4 z = {0.f,0.f,0.f,0.f}; acc[qi][db] = z; }
    float m_i[2] = {0.f, 0.f};
    float l_l[2] = {0.f, 0.f};

    const int NT = (N_ / KSPLIT) / 64;
    for (int mt = 0; mt < NT; ++mt) {
        const int m0 = ks0 + mt * 64;

        short8v ka[4][2];
        #pragma unroll
        for (int kb = 0; kb < 4; ++kb) {
            const size_t kg = (m0 >> 4) + kb;
            ka[kb][0] = *(const short8v*)(Kpl + (kg * 2 + 0) * 512 + lane * 8);
            ka[kb][1] = *(const short8v*)(Kpl + (kg * 2 + 1) * 512 + lane * 8);
        }
        const int kt = m0 >> 6;
        short8v vf[2][3];
        #pragma unroll
        for (int hh = 0; hh < 2; ++hh)
            #pragma unroll
            for (int db = 0; db < 3; ++db)
                vf[hh][db] = *(const short8v*)(Vpl + (size_t)((kt * 2 + hh) * 3 + db) * 512 + lane * 8);

        f32x4 sf[2][4];
        __builtin_amdgcn_s_setprio(1);
        #pragma unroll
        for (int qi = 0; qi < 2; ++qi)
            #pragma unroll
            for (int kb = 0; kb < 4; ++kb) {
                f32x4 z = {0.f, 0.f, 0.f, 0.f};
                z = __builtin_amdgcn_mfma_f32_16x16x32_bf16(ka[kb][0], qf[qi][0], z, 0, 0, 0);
                z = __builtin_amdgcn_mfma_f32_16x16x32_bf16(ka[kb][1], qf[qi][1], z, 0, 0, 0);
                sf[qi][kb] = z;
            }
        __builtin_amdgcn_s_setprio(0);

        #pragma unroll
        for (int qi = 0; qi < 2; ++qi) {
            float psum = 0.f;
            #pragma unroll
            for (int kb = 0; kb < 4; ++kb) {
                float e0 = __expf(sf[qi][kb][0] - m_i[qi]);
                float e1 = __expf(sf[qi][kb][1] - m_i[qi]);
                float e2 = __expf(sf[qi][kb][2] - m_i[qi]);
                float e3 = __expf(sf[qi][kb][3] - m_i[qi]);
                psum += (e0 + e1) + (e2 + e3);
                u32 r0, r1;
                asm("v_cvt_pk_bf16_f32 %0, %1, %2" : "=v"(r0) : "v"(e0), "v"(e1));
                asm("v_cvt_pk_bf16_f32 %0, %1, %2" : "=v"(r1) : "v"(e2), "v"(e3));
                const int un = (4 * kb + grp) ^ (c7 << 1);
                uint2 pk2; pk2.x = r0; pk2.y = r1;
                *(uint2*)&Pl[wv][qi][col][un << 2] = pk2;
            }
            l_l[qi] += psum;
        }

        __builtin_amdgcn_s_setprio(1);
        #pragma unroll
        for (int qi = 0; qi < 2; ++qi)
            #pragma unroll
            for (int hh = 0; hh < 2; ++hh) {
                const int ur = (8 * hh + 2 * grp) ^ (c7 << 1);
                short8v pf = *(const short8v*)&Pl[wv][qi][col][ur << 2];
                #pragma unroll
                for (int db = 0; db < 3; ++db)
                    acc[qi][db] = __builtin_amdgcn_mfma_f32_16x16x32_bf16(vf[hh][db], pf, acc[qi][db], 0, 0, 0);
            }
        __builtin_amdgcn_s_setprio(0);

        #pragma unroll
        for (int qi = 0; qi < 2; ++qi) {
            float pmax = -1e30f;
            #pragma unroll
            for (int kb = 0; kb < 4; ++kb)
                #pragma unroll
                for (int r = 0; r < 4; ++r) pmax = fmaxf(pmax, sf[qi][kb][r]);
            pmax = fmaxf(pmax, __shfl_xor(pmax, 16, 64));
            pmax = fmaxf(pmax, __shfl_xor(pmax, 32, 64));
            if (!__all(pmax - m_i[qi] <= 8.0f)) {
                float mnew = fmaxf(m_i[qi], pmax);
                float sc = __expf(m_i[qi] - mnew);
                l_l[qi] *= sc;
                #pragma unroll
                for (int db = 0; db < 3; ++db) {
                    acc[qi][db][0] *= sc; acc[qi][db][1] *= sc;
                    acc[qi][db][2] *= sc; acc[qi][db][3] *= sc;
                }
                m_i[qi] = mnew;
            }
        }
    }

    const int ntile = q32 >> 1, qh = q32 & 1;
    const size_t pb = (size_t)(kz * 16 + bh) * 32 + ntile;
    #pragma unroll
    for (int qi = 0; qi < 2; ++qi) {
        float l = l_l[qi];
        l += __shfl_xor(l, 16, 64);
        l += __shfl_xor(l, 32, 64);
        const int q = qh * 32 + qi * 16 + col;
        #pragma unroll
        for (int db = 0; db < 3; ++db)
            #pragma unroll
            for (int r = 0; r < 4; ++r) {
                int d = db * 16 + grp * 4 + r;
                pacc[pb * 3072 + d * 64 + q] = f2bf(acc[qi][db][r]);
            }
        if (grp == 0) {
            pml[pb * 128 + q]      = m_i[qi];
            pml[pb * 128 + 64 + q] = l;
        }
    }
}

// ---------------------------------------------------------------------------
// graph attention: fp32 in (B,N,3,C), bf16 edge buffer out
// ---------------------------------------------------------------------------
__global__ __launch_bounds__(256) void graph_kernel(
    const float* __restrict__ tq, const float* __restrict__ tv,
    const int* __restrict__ idx, ush* __restrict__ gbuf)
{
    __shared__ float center[384];
    __shared__ float sd[16];
    __shared__ int nbr_i[16];
    const int b = blockIdx.y, n = blockIdx.x;
    const int tid = threadIdx.x;
    const float* qrow = tq + (size_t)(b * N_ + n) * 384;
    for (int e = tid; e < 384; e += 256) center[e] = qrow[e];
    if (tid < 16) nbr_i[tid] = idx[(size_t)(b * N_ + n) * 16 + tid];
    __syncthreads();

    const int lane = tid & 63, wv = tid >> 6;
    for (int kk = 0; kk < 4; ++kk) {
        int k = wv * 4 + kk;
        const float* vrow = tv + ((size_t)b * N_ + nbr_i[k]) * 384;
        float p = 0.f;
        #pragma unroll
        for (int jj = 0; jj < 6; ++jj) {
            int e = lane + jj * 64;
            p += center[e] * vrow[e];
        }
        #pragma unroll
        for (int off = 32; off; off >>= 1) p += __shfl_down(p, off, 64);
        if (lane == 0) sd[k] = p * 0.05103103630798288f;
    }
    __syncthreads();

    float mx = -1e30f;
    #pragma unroll
    for (int k = 0; k < 16; ++k) mx = fmaxf(mx, sd[k]);
    float a[16]; float ssum = 0.f;
    #pragma unroll
    for (int k = 0; k < 16; ++k) { a[k] = __expf(sd[k] - mx); ssum += a[k]; }
    float inv = 1.f / ssum;

    for (int e = tid; e < 384; e += 256) {
        float accv = 0.f;
        #pragma unroll
        for (int k = 0; k < 16; ++k)
            accv += a[k] * tv[((size_t)b * N_ + nbr_i[k]) * 384 + e];
        accv *= inv;
        float ce = center[e];
        int t = e >> 7, c = e & 127;
        size_t gb = ((size_t)(b * N_ + n) * 3 + t) * 256;
        gbuf[gb + c]       = f2bf(accv - ce);
        gbuf[gb + 128 + c] = f2bf(ce);
    }
}

// ---------------------------------------------------------------------------
// split-K reduce: combine KSPLIT partials -> bf16 ao
// ---------------------------------------------------------------------------
__global__ __launch_bounds__(256) void attn_reduce_kernel(
    const ush* __restrict__ pacc, const float* __restrict__ pml,
    ush* __restrict__ ao)
{
    const int nt = blockIdx.x, bh = blockIdx.y;
    const int b = bh >> 3, h = bh & 7;
    const int tid = threadIdx.x;
    const int q = tid & 63, dg = tid >> 6;

    size_t pb[KSPLIT];
    float m[KSPLIT], l[KSPLIT];
    #pragma unroll
    for (int kz = 0; kz < KSPLIT; ++kz) {
        pb[kz] = (size_t)(kz * 16 + bh) * 32 + nt;
        m[kz] = pml[pb[kz] * 128 + q];
        l[kz] = pml[pb[kz] * 128 + 64 + q];
    }
    float ms = -1e30f;
    #pragma unroll
    for (int kz = 0; kz < KSPLIT; ++kz) ms = fmaxf(ms, m[kz]);
    float w[KSPLIT], ls = 0.f;
    #pragma unroll
    for (int kz = 0; kz < KSPLIT; ++kz) { w[kz] = __expf(m[kz] - ms); ls += l[kz] * w[kz]; }
    const float inv = 1.f / ls;

    const size_t hb = ((size_t)(b * C_ + h * 16)) * 3 * N_;
    #pragma unroll
    for (int j = 0; j < 12; ++j) {
        int d = dg * 12 + j;
        float o = 0.f;
        #pragma unroll
        for (int kz = 0; kz < KSPLIT; ++kz)
            o += bf2f(pacc[pb[kz] * 3072 + d * 64 + q]) * w[kz];
        ao[hb + (size_t)d * N_ + nt * 64 + q] = f2bf(o * inv);
    }
}

// ---------------------------------------------------------------------------
// vn_leaky: fp32 x,d in -> split u32 out
// ---------------------------------------------------------------------------
__global__ __launch_bounds__(256) void leaky_kernel(const float* __restrict__ x,
                                                    const float* __restrict__ d,
                                                    u32* __restrict__ y)
{
    size_t p = (size_t)blockIdx.x * 256 + threadIdx.x;
    size_t bh = p / N_, n = p % N_;
    size_t base = bh * 3 * N_ + n;
    float x0 = x[base], x1 = x[base + N_], x2 = x[base + 2 * N_];
    float d0 = d[base], d1 = d[base + N_], d2 = d[base + 2 * N_];
    float dot = x0 * d0 + x1 * d1 + x2 * d2;
    float dsq = d0 * d0 + d1 * d1 + d2 * d2;
    float f = dot / (dsq + EPS_);
    bool pos = dot >= 0.f;
    float y0 = pos ? x0 : x0 - f * d0;
    float y1 = pos ? x1 : x1 - f * d1;
    float y2 = pos ? x2 : x2 - f * d2;
    y[base]          = splitpack(NS_ * x0 + (1.f - NS_) * y0);
    y[base + N_]     = splitpack(NS_ * x1 + (1.f - NS_) * y1);
    y[base + 2 * N_] = splitpack(NS_ * x2 + (1.f - NS_) * y2);
}

// ---------------------------------------------------------------------------
extern "C" void kernel_launch(void* const* d_in, const int* in_sizes, int n_in,
                              void* d_out, int out_size, void* d_ws, size_t ws_size,
                              hipStream_t stream)
{
    const float* q_in = (const float*)d_in[0];
    const float* v_in = (const float*)d_in[1];
    const int*   idx_s = (const int*)d_in[4];
    const int*   idx_c = (const int*)d_in[5];
    const float* g1 = (const float*)d_in[6];
    const float* b1 = (const float*)d_in[7];
    const float* g2 = (const float*)d_in[8];
    const float* b2 = (const float*)d_in[9];
    const float* gq = (const float*)d_in[10];
    const float* bq = (const float*)d_in[11];
    const float* gv = (const float*)d_in[12];
    const float* bv = (const float*)d_in[13];
    float* out = (float*)d_out;
    float* ws  = (float*)d_ws;

    const size_t S1 = (size_t)B_ * C_ * 3 * N_; // 1572864 elems
    float* nx    = ws;                 // 0
    float* nv    = ws + S1;            // 1
    ush*   nx_b  = (ush*)(ws + 2*S1);  // 2 (half)
    ush*   nv_b  = (ush*)(ws + 3*S1);  // 3 (half)
    ush*   vfm   = (ush*)(ws + 4*S1);  // 4: 16*98304*2B = 3MB
    ush*   qktb  = (ush*)(ws + 5*S1) + S1;  // 5.5-6.84: 32*131072*2B = 8.4MB
    ush*   ao_b  = (ush*)(ws + 7*S1);  // 7 (half)
    u32*   f12_s = (u32*)(ws + 8*S1);  // 8-9
    float* qa    = ws + 12*S1;         // 12
    float* qb    = ws + 13*S1;         // 13 (gbuf_b aliases pre-Wm)
    ush*   gbuf_b= (ush*)(ws + 13*S1); // 13 as ush (6.3MB), consumed before qb write
    float* t1    = ws + 14*S1;         // 14
    float* t2    = ws + 15*S1;         // 15
    u32*   wsp   = (u32*)(ws + 16*S1); // 16+
    // split-K attention partials (attn->reduce window only)
    ush*   pacc  = (ush*)(ws + 8*S1);  // 8-11: 4096*3072*2B = 25.2MB
    float* pml   = (float*)(ws + 2*S1);// 2 (attn after qkv consumed nx_b)
    // phase C aliases:
    float* hd    = ws;                 // 0-3
    float* h1    = ws + 4*S1;          // 4-7
    u32*   h1_s  = (u32*)(ws + 8*S1);  // 8-11
    ush*   h1_b  = (ush*)(ws + 14*S1); // 14-15

    const int wn[15]  = {16384,16384,16384,16384,32768,32768,
                         16384,16384,16384,16384,32768,32768,
                         65536,262144,65536};
    u32* wd[15];
    {
        int off = 0;
        for (int i = 0; i < 15; ++i) { wd[i] = wsp + off; off += wn[i]; }
    }
    u32 *Wq_s = wd[0], *Wk_s = wd[1], *Wv_s = wd[2], *Wo_s = wd[3], *We_s = wd[4], *Wm_s = wd[5];
    u32 *Wq_c = wd[6], *Wk_c = wd[7], *Wv_c = wd[8], *Wo_c = wd[9], *We_c = wd[10], *Wm_c = wd[11];
    u32 *W1 = wd[12], *Dact = wd[13], *W2 = wd[14];

    // zero qktb once (d=48..63 pad slots must be 0; qkv only writes d<48)
    hipMemsetAsync(qktb, 0, (size_t)32 * 131072 * sizeof(ush), stream);

    {
        WCArgs a;
        for (int i = 0; i < 15; ++i) {
            a.src[i] = (const float*)d_in[14 + i];
            a.dst[i] = wd[i];
            a.n[i]   = wn[i];
            a.scale[i] = 1.f;
        }
        a.scale[0] = 0.14433756729740643f;  // Wq_s: fold 1/sqrt(48)
        a.scale[6] = 0.14433756729740643f;  // Wq_c
        wconv_kernel<<<dim3(1024, 15), 256, 0, stream>>>(a);
    }

    dim3 gar(N_ / 64, B_ * HEADS_);
    dim3 ggr(N_, B_);
    dim3 gwe(96, 4, B_);
    dim3 gg128(96, 2, B_);
    dim3 gg512(96, 8, B_);

    // ---- Phase A: self attention block ----
    {
        LNArgs la{};
        la.x[0] = q_in; la.g[0] = g1; la.bt[0] = b1; la.y[0] = nx; la.ysp[0] = nx_b;
        ln_kernel<<<dim3(64, B_, 1), 256, 0, stream>>>(la);
    }
    {
        QKVArgs A{Wq_s, Wk_s, Wv_s, nx_b, nx_b, nx_b};
        qkv_tr_kernel<<<dim3(1152 + 1536), 256, 0, stream>>>(A, vfm, qktb, nx, t1, nullptr, nullptr);
    }
    attn_mfma_kernel<<<dim3(2048), 256, 0, stream>>>(vfm, qktb, pacc, pml);
    attn_reduce_kernel<<<gar, 256, 0, stream>>>(pacc, pml, ao_b);
    graph_kernel<<<ggr, 256, 0, stream>>>(t1, t1, idx_s, gbuf_b);
    wowe_kernel<<<gwe, 256, 0, stream>>>(Wo_s, ao_b, We_s, gbuf_b, f12_s);
    gemm_kernel2<0,0,true,false><<<gg128, 256, 0, stream>>>(Wm_s, 256, f12_s, q_in, qa, nullptr, nullptr, 128, 0, 256);

    // ---- Phase B: cross attention block ----
    {
        LNArgs la{};
        la.x[0] = qa;   la.g[0] = gq; la.bt[0] = bq; la.y[0] = nx; la.ysp[0] = nx_b;
        la.x[1] = v_in; la.g[1] = gv; la.bt[1] = bv; la.y[1] = nv; la.ysp[1] = nv_b;
        ln_kernel<<<dim3(64, B_, 2), 256, 0, stream>>>(la);
    }
    {
        QKVArgs A{Wq_c, Wk_c, Wv_c, nx_b, nv_b, nv_b};
        qkv_tr_kernel<<<dim3(1152 + 3072), 256, 0, stream>>>(A, vfm, qktb, nx, t1, nv, t2);
    }
    attn_mfma_kernel<<<dim3(2048), 256, 0, stream>>>(vfm, qktb, pacc, pml);
    attn_reduce_kernel<<<gar, 256, 0, stream>>>(pacc, pml, ao_b);
    graph_kernel<<<ggr, 256, 0, stream>>>(t1, t2, idx_c, gbuf_b);
    wowe_kernel<<<gwe, 256, 0, stream>>>(Wo_c, ao_b, We_c, gbuf_b, f12_s);
    gemm_kernel2<0,0,true,false><<<gg128, 256, 0, stream>>>(Wm_c, 256, f12_s, qa, qb, nullptr, nullptr, 128, 0, 256);

    // ---- Phase C: vector MLP ----
    {
        LNArgs la{};
        la.x[0] = qb; la.g[0] = g2; la.bt[0] = b2; la.y[0] = nullptr; la.ysp[0] = nx_b;
        ln_kernel<<<dim3(64, B_, 1), 256, 0, stream>>>(la);
    }
    gemm_kernel2<0,5,false,true><<<gg512, 256, 0, stream>>>(W1, 128, nx_b, nullptr, h1, nullptr, h1_b, 512, 0, 128);
    gemm_kernel2<0,0,false,true><<<gg512, 256, 0, stream>>>(Dact, 512, h1_b, nullptr, hd, nullptr, nullptr, 512, 0, 512);
    leaky_kernel<<<dim3((B_ * HID_ * N_) / 256), 256, 0, stream>>>(h1, hd, h1_s);
    gemm_kernel2<0,0,true,false><<<gg128, 256, 0, stream>>>(W2, 512, h1_s, qb, out, nullptr, nullptr, 128, 0, 512);
}

// Round 14
// 263.902 us; speedup vs baseline: 1.2288x; 1.1131x over previous
//
#include <hip/hip_runtime.h>
#include <math.h>

#define B_    2
#define C_    128
#define N_    2048
#define HID_  512
#define HEADS_ 8
#define EPS_  1e-6f
#define NS_   0.2f
#define KSPLIT 8

typedef __attribute__((ext_vector_type(8))) short short8v;  // 8 bf16
typedef __attribute__((ext_vector_type(4))) float f32x4;
typedef unsigned short ush;
typedef unsigned int u32;

__device__ inline ush f2bf(float f) {
    unsigned u = __float_as_uint(f);
    u += 0x7FFF + ((u >> 16) & 1);          // round-to-nearest-even
    return (ush)(u >> 16);
}
__device__ inline float bf2f(ush u) { return __uint_as_float((u32)u << 16); }

// pack float -> (hi bf16 << 16) | lo bf16
__device__ inline u32 splitpack(float x) {
    ush hi = f2bf(x);
    float hf = __uint_as_float((u32)hi << 16);
    ush lo = f2bf(x - hf);
    return ((u32)hi << 16) | (u32)lo;
}

__device__ inline void unpack_hi(const u32* buf, short8v& h0, short8v& h1) {
    ush h[16];
    #pragma unroll
    for (int j = 0; j < 16; ++j) h[j] = (ush)(buf[j] >> 16);
    h0 = *(short8v*)&h[0]; h1 = *(short8v*)&h[8];
}

// ---------------------------------------------------------------------------
// vec_layernorm, z-indexed multi-input: writes bf16 plane only
// ---------------------------------------------------------------------------
struct LNArgs {
    const float* x[2]; const float* g[2]; const float* bt[2]; ush* ysp[2];
};
__global__ __launch_bounds__(256) void ln_kernel(LNArgs a)
{
    __shared__ float norms[128][32];
    __shared__ float red1[8][32];
    __shared__ float red2[8][32];
    const int s = blockIdx.z;
    const float* x = a.x[s];
    const float* gma = a.g[s];
    const float* bta = a.bt[s];
    ush* ysp = a.ysp[s];

    const int b  = blockIdx.y;
    const int n0 = blockIdx.x * 32;
    const int nn = threadIdx.x & 31;
    const int cg = threadIdx.x >> 5;

    float s1 = 0.f, s2 = 0.f;
    for (int it = 0; it < 16; ++it) {
        int c = it * 8 + cg;
        size_t base = ((size_t)(b * C_ + c) * 3) * N_ + n0 + nn;
        float x0 = x[base], x1 = x[base + N_], x2 = x[base + 2 * N_];
        float nr = sqrtf(x0 * x0 + x1 * x1 + x2 * x2 + EPS_);
        norms[c][nn] = nr;
        s1 += nr; s2 += nr * nr;
    }
    red1[cg][nn] = s1; red2[cg][nn] = s2;
    __syncthreads();
    float S1 = 0.f, S2 = 0.f;
    #pragma unroll
    for (int g = 0; g < 8; ++g) { S1 += red1[g][nn]; S2 += red2[g][nn]; }
    float mu   = S1 * (1.f / 128.f);
    float var  = S2 * (1.f / 128.f) - mu * mu;
    float rstd = rsqrtf(var + EPS_);

    for (int it = 0; it < 16; ++it) {
        int c = it * 8 + cg;
        float nr = norms[c][nn];
        float ln = (nr - mu) * rstd * gma[c] + bta[c];
        float sc = ln / (nr + EPS_);
        size_t base = ((size_t)(b * C_ + c) * 3) * N_ + n0 + nn;
        ysp[base]          = f2bf(x[base] * sc);
        ysp[base + N_]     = f2bf(x[base + N_] * sc);
        ysp[base + 2 * N_] = f2bf(x[base + 2 * N_] * sc);
    }
}

// ---------------------------------------------------------------------------
// weight split-conversion: 15 weights, one launch (with optional pre-scale)
// ---------------------------------------------------------------------------
struct WCArgs { const float* src[15]; u32* dst[15]; int n[15]; float scale[15]; };
__global__ __launch_bounds__(256) void wconv_kernel(WCArgs a)
{
    const int w = blockIdx.y;
    const int i = blockIdx.x * 256 + threadIdx.x;
    if (i < a.n[w]) a.dst[w][i] = splitpack(a.src[w][i] * a.scale[w]);
}

// ---------------------------------------------------------------------------
// bf16 MFMA GEMM core (hi-only). XBF: X input is bf16 ush (else split u32).
// XMODE 0: X[(b*K + c)*M + m]   XMODE 1: X[((b*N+n)*3+t)*K + c], m = t*N+n
// OMODE 0: fp32(+Z)  3: bf16 Ybf  4: qkv fragment-major  5: fp32(+Z) + bf16
// ---------------------------------------------------------------------------
template <int XMODE, int OMODE, bool XBF>
__device__ __forceinline__ void gemm_tile(
    const u32* __restrict__ Wsp, int wstride,
    const void* __restrict__ Xv, int K,
    const float* __restrict__ Z, float* __restrict__ Y,
    ush* __restrict__ Ybf, ush* __restrict__ Ytr,
    int b, int m0, int o0loc, int oglob, int Ostr,
    ush (*Wh)[64], ush (*Xh)[64])
{
    const int M = 3 * N_;
    const int tid = threadIdx.x;
    const int lane = tid & 63, wv = tid >> 6;
    const int col = lane & 15, grp = lane >> 4;
    const int wo = wv >> 1, wm = wv & 1;

    f32x4 acc[2][2];
    #pragma unroll
    for (int i = 0; i < 2; ++i)
        #pragma unroll
        for (int j = 0; j < 2; ++j) { f32x4 z = {0.f,0.f,0.f,0.f}; acc[i][j] = z; }

    for (int kk = 0; kk < K; kk += 64) {
        // ---- stage W tile (64 o x 64 k), split u32 source, hi half ----
        {
            const int o = tid >> 2, kg = tid & 3;
            const u32* src = Wsp + (size_t)(o0loc + o) * wstride + kk + kg * 16;
            u32 buf[16];
            #pragma unroll
            for (int j = 0; j < 4; ++j) *(uint4*)&buf[j * 4] = *(const uint4*)(src + j * 4);
            const int s0 = ((kg * 2)     ^ (o & 7)) << 3;
            const int s1 = ((kg * 2 + 1) ^ (o & 7)) << 3;
            short8v h0, h1; unpack_hi(buf, h0, h1);
            *(short8v*)&Wh[o][s0] = h0; *(short8v*)&Wh[o][s1] = h1;
        }
        // ---- stage X tile (64 k x 64 m), stored transposed Xs[m][k] ----
        if (XMODE == 0) {
            const int m = lane, kq = wv;
            const int s0 = ((kq * 2)     ^ (m & 7)) << 3;
            const int s1 = ((kq * 2 + 1) ^ (m & 7)) << 3;
            if (XBF) {
                const ush* src = (const ush*)Xv + ((size_t)b * K + kk + kq * 16) * M + m0 + m;
                ush h[16];
                #pragma unroll
                for (int j = 0; j < 16; ++j) h[j] = src[(size_t)j * M];
                *(short8v*)&Xh[m][s0] = *(short8v*)&h[0];
                *(short8v*)&Xh[m][s1] = *(short8v*)&h[8];
            } else {
                const u32* src = (const u32*)Xv + ((size_t)b * K + kk + kq * 16) * M + m0 + m;
                u32 buf[16];
                #pragma unroll
                for (int j = 0; j < 16; ++j) buf[j] = src[(size_t)j * M];
                short8v h0, h1; unpack_hi(buf, h0, h1);
                *(short8v*)&Xh[m][s0] = h0; *(short8v*)&Xh[m][s1] = h1;
            }
        } else {
            const int m = tid >> 2, kg = tid & 3;
            const int mg = m0 + m;
            const int n = mg & (N_ - 1), t = mg >> 11;
            const int s0 = ((kg * 2)     ^ (m & 7)) << 3;
            const int s1 = ((kg * 2 + 1) ^ (m & 7)) << 3;
            const ush* src = (const ush*)Xv + ((size_t)(b * N_ + n) * 3 + t) * K + kk + kg * 16;
            ush h[16];
            *(uint4*)&h[0] = *(const uint4*)(src);
            *(uint4*)&h[8] = *(const uint4*)(src + 8);
            *(short8v*)&Xh[m][s0] = *(short8v*)&h[0];
            *(short8v*)&Xh[m][s1] = *(short8v*)&h[8];
        }
        __syncthreads();
        // ---- 8 MFMAs per K-step ----
        #pragma unroll
        for (int kc = 0; kc < 2; ++kc) {
            const int sk = ((kc * 4 + grp) ^ (col & 7)) << 3;
            short8v ah0 = *(const short8v*)&Wh[wo * 32 + col][sk];
            short8v ah1 = *(const short8v*)&Wh[wo * 32 + 16 + col][sk];
            short8v xh0 = *(const short8v*)&Xh[wm * 32 + col][sk];
            short8v xh1 = *(const short8v*)&Xh[wm * 32 + 16 + col][sk];
            acc[0][0] = __builtin_amdgcn_mfma_f32_16x16x32_bf16(ah0, xh0, acc[0][0], 0, 0, 0);
            acc[0][1] = __builtin_amdgcn_mfma_f32_16x16x32_bf16(ah0, xh1, acc[0][1], 0, 0, 0);
            acc[1][0] = __builtin_amdgcn_mfma_f32_16x16x32_bf16(ah1, xh0, acc[1][0], 0, 0, 0);
            acc[1][1] = __builtin_amdgcn_mfma_f32_16x16x32_bf16(ah1, xh1, acc[1][1], 0, 0, 0);
        }
        __syncthreads();
    }
    // ---- epilogue ----
    #pragma unroll
    for (int of = 0; of < 2; ++of) {
        #pragma unroll
        for (int r = 0; r < 4; ++r) {
            const int o = oglob + wo * 32 + of * 16 + grp * 4 + r;
            #pragma unroll
            for (int mf = 0; mf < 2; ++mf) {
                const int mloc = m0 + wm * 32 + mf * 16 + col;
                const size_t idx = ((size_t)b * Ostr + o) * M + mloc;
                float v = acc[of][mf][r];
                if (OMODE == 0 || OMODE == 5) {
                    if (Z) v += Z[idx];
                    Y[idx] = v;
                }
                if (OMODE == 3 || OMODE == 5) Ybf[idx] = f2bf(v);
                if (OMODE == 4) {
                    ush bv = f2bf(v);
                    const int t = mloc >> 11, n = mloc & (N_ - 1);
                    const int h = (o >> 4) & 7, cl = o & 15;
                    const int d = cl * 3 + t;
                    if (o >= 256) {
                        const int kt = n >> 6, hh = (n >> 5) & 1, db = d >> 4;
                        const size_t idx2 = ((size_t)(b * 8 + h) * 192
                                           + (kt * 2 + hh) * 3 + db) * 512
                                          + (((n >> 3) & 3) * 16 + (d & 15)) * 8 + (n & 7);
                        Ybf[idx2] = bv;
                    } else {
                        const int isK = (o >> 7) & 1;
                        const int qg = n >> 4, half = d >> 5;
                        const size_t idx2 = ((size_t)(isK * 16 + b * 8 + h) * 256
                                           + qg * 2 + half) * 512
                                          + (((d >> 3) & 3) * 16 + (n & 15)) * 8 + (d & 7);
                        Ytr[idx2] = bv;
                    }
                }
            }
        }
    }
}

template <int XMODE, int OMODE, bool XBF>
__global__ __launch_bounds__(256) void gemm_kernel2(
    const u32* __restrict__ Wsp, int wstride,
    const void* __restrict__ Xv,
    const float* __restrict__ Z,
    float* __restrict__ Y, ush* __restrict__ Ybf,
    int Ostr, int obase, int K)
{
    __shared__ __align__(16) ush Wh[64][64];
    __shared__ __align__(16) ush Xh[64][64];
    gemm_tile<XMODE, OMODE, XBF>(Wsp, wstride, Xv, K, Z, Y, Ybf, nullptr,
                            blockIdx.z, blockIdx.x * 64,
                            blockIdx.y * 64, obase + blockIdx.y * 64, Ostr,
                            Wh, Xh);
}

struct QKVArgs {
    const u32* W0; const u32* W1; const u32* W2;
    const ush* X0; const ush* X1; const ush* X2;
};

// fused: qkv projections (blocks 0..1151, fragment-major outputs) +
// bf16 transpose(s) (blocks 1152.., (B,C,3,N) bf16 -> (B,N,3,C) bf16)
__global__ __launch_bounds__(256) void qkv_tr_kernel(QKVArgs A,
        ush* __restrict__ vfm, ush* __restrict__ qktb,
        const ush* __restrict__ ts0, ush* __restrict__ td0,
        const ush* __restrict__ ts1, ush* __restrict__ td1)
{
    __shared__ __align__(16) ush Wh[64][64];
    __shared__ __align__(16) ush Xh[64][64];
    __shared__ ush ttile[32][34];
    const int bx = blockIdx.x;
    if (bx < 1152) {
        const int z = bx / 576, rem = bx % 576;
        const int y = rem / 96, x = rem % 96;
        const int wi = y >> 1;
        const u32* W = wi == 0 ? A.W0 : (wi == 1 ? A.W1 : A.W2);
        const ush* X = wi == 0 ? A.X0 : (wi == 1 ? A.X1 : A.X2);
        gemm_tile<0, 4, true>(W, 128, X, 128, nullptr, nullptr, vfm, qktb,
                        z, x * 64, (y & 1) * 64, y * 64, 384,
                        Wh, Xh);
    } else {
        int i = bx - 1152;
        const int which = i / 1536; i %= 1536;
        const ush* src = which ? ts1 : ts0;
        ush* dst = which ? td1 : td0;
        const int x = i & 63, y = (i >> 6) & 3, z = i >> 8;
        const int b = z / 3, t = z % 3;
        const int n0 = x * 32, c0 = y * 32;
        const int tx = threadIdx.x & 31, ty = threadIdx.x >> 5;
        #pragma unroll
        for (int p = 0; p < 4; ++p) {
            int c = c0 + ty + p * 8;
            ttile[ty + p * 8][tx] = src[((size_t)(b * C_ + c) * 3 + t) * N_ + n0 + tx];
        }
        __syncthreads();
        #pragma unroll
        for (int p = 0; p < 4; ++p) {
            int n = n0 + ty + p * 8;
            dst[((size_t)(b * N_ + n) * 3 + t) * C_ + c0 + tx] = ttile[tx][ty + p * 8];
        }
    }
}

// fused Wo (XMODE0, y=0,1) + We (XMODE1, y=2,3) -> bf16 f12 (Ostr 256)
__global__ __launch_bounds__(256) void wowe_kernel(
    const u32* __restrict__ Wo, const ush* __restrict__ ao,
    const u32* __restrict__ We, const ush* __restrict__ gb,
    ush* __restrict__ f12)
{
    __shared__ __align__(16) ush Wh[64][64];
    __shared__ __align__(16) ush Xh[64][64];
    const int y = blockIdx.y;
    if (y < 2)
        gemm_tile<0, 3, true>(Wo, 128, ao, 128, nullptr, nullptr, f12, nullptr,
                        blockIdx.z, blockIdx.x * 64, y * 64, y * 64, 256,
                        Wh, Xh);
    else
        gemm_tile<1, 3, true>(We, 256, gb, 256, nullptr, nullptr, f12, nullptr,
                        blockIdx.z, blockIdx.x * 64, (y - 2) * 64, 128 + (y - 2) * 64, 256,
                        Wh, Xh);
}

// ---------------------------------------------------------------------------
// barrier-free split-K flash attention, XCD-chunked 1D grid (2048 blocks),
// fragment-major coalesced operands (verified round-10/11 configuration).
// ---------------------------------------------------------------------------
__global__ __launch_bounds__(256) void attn_mfma_kernel(
    const ush* __restrict__ vfm, const ush* __restrict__ qktb,
    ush* __restrict__ pacc, float* __restrict__ pml)
{
    __shared__ __align__(16) ush Pl[4][2][16][64];   // 16 KB

    const int flat = blockIdx.x;
    const int xcd  = flat & 7;
    const int slot = flat >> 3;
    const int gid  = xcd * 4 + (slot >> 6);
    const int q32  = slot & 63;
    const int bh   = gid & 15;
    const int zz   = gid >> 4;

    const int tid = threadIdx.x;
    const int lane = tid & 63, wv = tid >> 6;
    const int col = lane & 15, grp = lane >> 4;
    const int c7  = col & 7;
    const int kz  = zz * 4 + wv;
    const int ks0 = kz * (N_ / KSPLIT);

    const ush* Qpl = qktb + (size_t)bh * 131072;
    const ush* Kpl = qktb + (size_t)(16 + bh) * 131072;
    const ush* Vpl = vfm  + (size_t)bh * 98304;

    short8v qf[2][2];
    #pragma unroll
    for (int qi = 0; qi < 2; ++qi) {
        const int qg = q32 * 2 + qi;
        qf[qi][0] = *(const short8v*)(Qpl + ((size_t)qg * 2 + 0) * 512 + lane * 8);
        qf[qi][1] = *(const short8v*)(Qpl + ((size_t)qg * 2 + 1) * 512 + lane * 8);
    }

    f32x4 acc[2][3];
    #pragma unroll
    for (int qi = 0; qi < 2; ++qi)
        #pragma unroll
        for (int db = 0; db < 3; ++db) { f32x4 z = {0.f,0.f,0.f,0.f}; acc[qi][db] = z; }
    float m_i[2] = {0.f, 0.f};
    float l_l[2] = {0.f, 0.f};

    const int NT = (N_ / KSPLIT) / 64;
    for (int mt = 0; mt < NT; ++mt) {
        const int m0 = ks0 + mt * 64;

        short8v ka[4][2];
        #pragma unroll
        for (int kb = 0; kb < 4; ++kb) {
            const size_t kg = (m0 >> 4) + kb;
            ka[kb][0] = *(const short8v*)(Kpl + (kg * 2 + 0) * 512 + lane * 8);
            ka[kb][1] = *(const short8v*)(Kpl + (kg * 2 + 1) * 512 + lane * 8);
        }
        const int kt = m0 >> 6;
        short8v vf[2][3];
        #pragma unroll
        for (int hh = 0; hh < 2; ++hh)
            #pragma unroll
            for (int db = 0; db < 3; ++db)
                vf[hh][db] = *(const short8v*)(Vpl + (size_t)((kt * 2 + hh) * 3 + db) * 512 + lane * 8);

        f32x4 sf[2][4];
        __builtin_amdgcn_s_setprio(1);
        #pragma unroll
        for (int qi = 0; qi < 2; ++qi)
            #pragma unroll
            for (int kb = 0; kb < 4; ++kb) {
                f32x4 z = {0.f, 0.f, 0.f, 0.f};
                z = __builtin_amdgcn_mfma_f32_16x16x32_bf16(ka[kb][0], qf[qi][0], z, 0, 0, 0);
                z = __builtin_amdgcn_mfma_f32_16x16x32_bf16(ka[kb][1], qf[qi][1], z, 0, 0, 0);
                sf[qi][kb] = z;
            }
        __builtin_amdgcn_s_setprio(0);

        #pragma unroll
        for (int qi = 0; qi < 2; ++qi) {
            float psum = 0.f;
            #pragma unroll
            for (int kb = 0; kb < 4; ++kb) {
                float e0 = __expf(sf[qi][kb][0] - m_i[qi]);
                float e1 = __expf(sf[qi][kb][1] - m_i[qi]);
                float e2 = __expf(sf[qi][kb][2] - m_i[qi]);
                float e3 = __expf(sf[qi][kb][3] - m_i[qi]);
                psum += (e0 + e1) + (e2 + e3);
                u32 r0, r1;
                asm("v_cvt_pk_bf16_f32 %0, %1, %2" : "=v"(r0) : "v"(e0), "v"(e1));
                asm("v_cvt_pk_bf16_f32 %0, %1, %2" : "=v"(r1) : "v"(e2), "v"(e3));
                const int un = (4 * kb + grp) ^ (c7 << 1);
                uint2 pk2; pk2.x = r0; pk2.y = r1;
                *(uint2*)&Pl[wv][qi][col][un << 2] = pk2;
            }
            l_l[qi] += psum;
        }

        __builtin_amdgcn_s_setprio(1);
        #pragma unroll
        for (int qi = 0; qi < 2; ++qi)
            #pragma unroll
            for (int hh = 0; hh < 2; ++hh) {
                const int ur = (8 * hh + 2 * grp) ^ (c7 << 1);
                short8v pf = *(const short8v*)&Pl[wv][qi][col][ur << 2];
                #pragma unroll
                for (int db = 0; db < 3; ++db)
                    acc[qi][db] = __builtin_amdgcn_mfma_f32_16x16x32_bf16(vf[hh][db], pf, acc[qi][db], 0, 0, 0);
            }
        __builtin_amdgcn_s_setprio(0);

        #pragma unroll
        for (int qi = 0; qi < 2; ++qi) {
            float pmax = -1e30f;
            #pragma unroll
            for (int kb = 0; kb < 4; ++kb)
                #pragma unroll
                for (int r = 0; r < 4; ++r) pmax = fmaxf(pmax, sf[qi][kb][r]);
            pmax = fmaxf(pmax, __shfl_xor(pmax, 16, 64));
            pmax = fmaxf(pmax, __shfl_xor(pmax, 32, 64));
            if (!__all(pmax - m_i[qi] <= 8.0f)) {
                float mnew = fmaxf(m_i[qi], pmax);
                float sc = __expf(m_i[qi] - mnew);
                l_l[qi] *= sc;
                #pragma unroll
                for (int db = 0; db < 3; ++db) {
                    acc[qi][db][0] *= sc; acc[qi][db][1] *= sc;
                    acc[qi][db][2] *= sc; acc[qi][db][3] *= sc;
                }
                m_i[qi] = mnew;
            }
        }
    }

    const int ntile = q32 >> 1, qh = q32 & 1;
    const size_t pb = (size_t)(kz * 16 + bh) * 32 + ntile;
    #pragma unroll
    for (int qi = 0; qi < 2; ++qi) {
        float l = l_l[qi];
        l += __shfl_xor(l, 16, 64);
        l += __shfl_xor(l, 32, 64);
        const int q = qh * 32 + qi * 16 + col;
        #pragma unroll
        for (int db = 0; db < 3; ++db)
            #pragma unroll
            for (int r = 0; r < 4; ++r) {
                int d = db * 16 + grp * 4 + r;
                pacc[pb * 3072 + d * 64 + q] = f2bf(acc[qi][db][r]);
            }
        if (grp == 0) {
            pml[pb * 128 + q]      = m_i[qi];
            pml[pb * 128 + 64 + q] = l;
        }
    }
}

// ---------------------------------------------------------------------------
// graph attention: bf16 in (B,N,3,C), LDS neighbor cache, bf16 edge out
// ---------------------------------------------------------------------------
__global__ __launch_bounds__(256) void graph_kernel(
    const ush* __restrict__ tq, const ush* __restrict__ tv,
    const int* __restrict__ idx, ush* __restrict__ gbuf)
{
    __shared__ float centerf[384];
    __shared__ ush nbr_l[16][384];
    __shared__ float sd[16];
    __shared__ int nbr_i[16];
    const int b = blockIdx.y, n = blockIdx.x;
    const int tid = threadIdx.x;
    const ush* qrow = tq + (size_t)(b * N_ + n) * 384;
    for (int e = tid; e < 384; e += 256) centerf[e] = bf2f(qrow[e]);
    if (tid < 16) nbr_i[tid] = idx[(size_t)(b * N_ + n) * 16 + tid];
    __syncthreads();

    const int lane = tid & 63, wv = tid >> 6;
    for (int kk = 0; kk < 4; ++kk) {
        int k = wv * 4 + kk;
        const u32* vrow = (const u32*)(tv + ((size_t)b * N_ + nbr_i[k]) * 384);
        float p = 0.f;
        #pragma unroll
        for (int jj = 0; jj < 3; ++jj) {
            int e2 = lane + jj * 64;
            u32 v2 = vrow[e2];
            ((u32*)nbr_l[k])[e2] = v2;
            p += centerf[e2 * 2]     * bf2f((ush)(v2 & 0xffff))
               + centerf[e2 * 2 + 1] * bf2f((ush)(v2 >> 16));
        }
        #pragma unroll
        for (int off = 32; off; off >>= 1) p += __shfl_down(p, off, 64);
        if (lane == 0) sd[k] = p * 0.05103103630798288f;
    }
    __syncthreads();

    float mx = -1e30f;
    #pragma unroll
    for (int k = 0; k < 16; ++k) mx = fmaxf(mx, sd[k]);
    float a[16]; float ssum = 0.f;
    #pragma unroll
    for (int k = 0; k < 16; ++k) { a[k] = __expf(sd[k] - mx); ssum += a[k]; }
    float inv = 1.f / ssum;

    for (int e = tid; e < 384; e += 256) {
        float accv = 0.f;
        #pragma unroll
        for (int k = 0; k < 16; ++k)
            accv += a[k] * bf2f(nbr_l[k][e]);
        accv *= inv;
        float ce = centerf[e];
        int t = e >> 7, c = e & 127;
        size_t gb = ((size_t)(b * N_ + n) * 3 + t) * 256;
        gbuf[gb + c]       = f2bf(accv - ce);
        gbuf[gb + 128 + c] = f2bf(ce);
    }
}

// ---------------------------------------------------------------------------
// split-K reduce: combine KSPLIT partials -> bf16 ao
// ---------------------------------------------------------------------------
__global__ __launch_bounds__(256) void attn_reduce_kernel(
    const ush* __restrict__ pacc, const float* __restrict__ pml,
    ush* __restrict__ ao)
{
    const int nt = blockIdx.x, bh = blockIdx.y;
    const int b = bh >> 3, h = bh & 7;
    const int tid = threadIdx.x;
    const int q = tid & 63, dg = tid >> 6;

    size_t pb[KSPLIT];
    float m[KSPLIT], l[KSPLIT];
    #pragma unroll
    for (int kz = 0; kz < KSPLIT; ++kz) {
        pb[kz] = (size_t)(kz * 16 + bh) * 32 + nt;
        m[kz] = pml[pb[kz] * 128 + q];
        l[kz] = pml[pb[kz] * 128 + 64 + q];
    }
    float ms = -1e30f;
    #pragma unroll
    for (int kz = 0; kz < KSPLIT; ++kz) ms = fmaxf(ms, m[kz]);
    float w[KSPLIT], ls = 0.f;
    #pragma unroll
    for (int kz = 0; kz < KSPLIT; ++kz) { w[kz] = __expf(m[kz] - ms); ls += l[kz] * w[kz]; }
    const float inv = 1.f / ls;

    const size_t hb = ((size_t)(b * C_ + h * 16)) * 3 * N_;
    #pragma unroll
    for (int j = 0; j < 12; ++j) {
        int d = dg * 12 + j;
        float o = 0.f;
        #pragma unroll
        for (int kz = 0; kz < KSPLIT; ++kz)
            o += bf2f(pacc[pb[kz] * 3072 + d * 64 + q]) * w[kz];
        ao[hb + (size_t)d * N_ + nt * 64 + q] = f2bf(o * inv);
    }
}

// ---------------------------------------------------------------------------
// vn_leaky: fp32 x,d in -> bf16 out
// ---------------------------------------------------------------------------
__global__ __launch_bounds__(256) void leaky_kernel(const float* __restrict__ x,
                                                    const float* __restrict__ d,
                                                    ush* __restrict__ y)
{
    size_t p = (size_t)blockIdx.x * 256 + threadIdx.x;
    size_t bh = p / N_, n = p % N_;
    size_t base = bh * 3 * N_ + n;
    float x0 = x[base], x1 = x[base + N_], x2 = x[base + 2 * N_];
    float d0 = d[base], d1 = d[base + N_], d2 = d[base + 2 * N_];
    float dot = x0 * d0 + x1 * d1 + x2 * d2;
    float dsq = d0 * d0 + d1 * d1 + d2 * d2;
    float f = dot / (dsq + EPS_);
    bool pos = dot >= 0.f;
    float y0 = pos ? x0 : x0 - f * d0;
    float y1 = pos ? x1 : x1 - f * d1;
    float y2 = pos ? x2 : x2 - f * d2;
    y[base]          = f2bf(NS_ * x0 + (1.f - NS_) * y0);
    y[base + N_]     = f2bf(NS_ * x1 + (1.f - NS_) * y1);
    y[base + 2 * N_] = f2bf(NS_ * x2 + (1.f - NS_) * y2);
}

// ---------------------------------------------------------------------------
extern "C" void kernel_launch(void* const* d_in, const int* in_sizes, int n_in,
                              void* d_out, int out_size, void* d_ws, size_t ws_size,
                              hipStream_t stream)
{
    const float* q_in = (const float*)d_in[0];
    const float* v_in = (const float*)d_in[1];
    const int*   idx_s = (const int*)d_in[4];
    const int*   idx_c = (const int*)d_in[5];
    const float* g1 = (const float*)d_in[6];
    const float* b1 = (const float*)d_in[7];
    const float* g2 = (const float*)d_in[8];
    const float* b2 = (const float*)d_in[9];
    const float* gq = (const float*)d_in[10];
    const float* bq = (const float*)d_in[11];
    const float* gv = (const float*)d_in[12];
    const float* bv = (const float*)d_in[13];
    float* out = (float*)d_out;
    float* ws  = (float*)d_ws;

    const size_t S1 = (size_t)B_ * C_ * 3 * N_; // 1572864 elems
    ush*   nx_b  = (ush*)(ws + 2*S1);  // 2 (half)
    ush*   nv_b  = (ush*)(ws + 3*S1);  // 3 (half)
    ush*   vfm   = (ush*)(ws + 4*S1);  // 4: 3MB
    ush*   qktb  = (ush*)(ws + 5*S1) + S1;  // 5.5-6.84: 8.4MB
    ush*   ao_b  = (ush*)(ws + 7*S1);  // 7 (half)
    ush*   f12_b = (ush*)(ws + 8*S1);  // 8 (written after pacc dead)
    float* qa    = ws + 12*S1;         // 12
    float* qb    = ws + 13*S1;         // 13 (gbuf_b aliases pre-Wm)
    ush*   gbuf_b= (ush*)(ws + 13*S1); // 13 as ush, consumed before qb write
    ush*   t1_b  = (ush*)(ws + 14*S1); // 14 (half)
    ush*   t2_b  = (ush*)(ws + 15*S1); // 15 (half)
    u32*   wsp   = (u32*)(ws + 16*S1); // 16+
    // split-K attention partials (attn->reduce window only)
    ush*   pacc  = (ush*)(ws + 8*S1);  // 8-11: 25.2MB
    float* pml   = (float*)(ws + 2*S1);// 2 (attn after qkv consumed nx_b)
    // phase C aliases:
    float* hd    = ws;                 // 0-3
    float* h1    = ws + 4*S1;          // 4-7
    ush*   h1_b  = (ush*)(ws + 14*S1); // 14-15 (t1/t2 dead)
    ush*   h1_b2 = (ush*)(ws + 8*S1);  // 8-9 (f12 dead)

    const int wn[15]  = {16384,16384,16384,16384,32768,32768,
                         16384,16384,16384,16384,32768,32768,
                         65536,262144,65536};
    u32* wd[15];
    {
        int off = 0;
        for (int i = 0; i < 15; ++i) { wd[i] = wsp + off; off += wn[i]; }
    }
    u32 *Wq_s = wd[0], *Wk_s = wd[1], *Wv_s = wd[2], *Wo_s = wd[3], *We_s = wd[4], *Wm_s = wd[5];
    u32 *Wq_c = wd[6], *Wk_c = wd[7], *Wv_c = wd[8], *Wo_c = wd[9], *We_c = wd[10], *Wm_c = wd[11];
    u32 *W1 = wd[12], *Dact = wd[13], *W2 = wd[14];

    // zero qktb once per launch (d=48..63 pad slots must be 0)
    hipMemsetAsync(qktb, 0, (size_t)32 * 131072 * sizeof(ush), stream);

    {
        WCArgs a;
        for (int i = 0; i < 15; ++i) {
            a.src[i] = (const float*)d_in[14 + i];
            a.dst[i] = wd[i];
            a.n[i]   = wn[i];
            a.scale[i] = 1.f;
        }
        a.scale[0] = 0.14433756729740643f;  // Wq_s: fold 1/sqrt(48)
        a.scale[6] = 0.14433756729740643f;  // Wq_c
        wconv_kernel<<<dim3(1024, 15), 256, 0, stream>>>(a);
    }

    dim3 gar(N_ / 64, B_ * HEADS_);
    dim3 ggr(N_, B_);
    dim3 gwe(96, 4, B_);
    dim3 gg128(96, 2, B_);
    dim3 gg512(96, 8, B_);

    // ---- Phase A: self attention block ----
    {
        LNArgs la{};
        la.x[0] = q_in; la.g[0] = g1; la.bt[0] = b1; la.ysp[0] = nx_b;
        ln_kernel<<<dim3(64, B_, 1), 256, 0, stream>>>(la);
    }
    {
        QKVArgs A{Wq_s, Wk_s, Wv_s, nx_b, nx_b, nx_b};
        qkv_tr_kernel<<<dim3(1152 + 1536), 256, 0, stream>>>(A, vfm, qktb, nx_b, t1_b, nullptr, nullptr);
    }
    attn_mfma_kernel<<<dim3(2048), 256, 0, stream>>>(vfm, qktb, pacc, pml);
    attn_reduce_kernel<<<gar, 256, 0, stream>>>(pacc, pml, ao_b);
    graph_kernel<<<ggr, 256, 0, stream>>>(t1_b, t1_b, idx_s, gbuf_b);
    wowe_kernel<<<gwe, 256, 0, stream>>>(Wo_s, ao_b, We_s, gbuf_b, f12_b);
    gemm_kernel2<0,0,true><<<gg128, 256, 0, stream>>>(Wm_s, 256, f12_b, q_in, qa, nullptr, 128, 0, 256);

    // ---- Phase B: cross attention block ----
    {
        LNArgs la{};
        la.x[0] = qa;   la.g[0] = gq; la.bt[0] = bq; la.ysp[0] = nx_b;
        la.x[1] = v_in; la.g[1] = gv; la.bt[1] = bv; la.ysp[1] = nv_b;
        ln_kernel<<<dim3(64, B_, 2), 256, 0, stream>>>(la);
    }
    {
        QKVArgs A{Wq_c, Wk_c, Wv_c, nx_b, nv_b, nv_b};
        qkv_tr_kernel<<<dim3(1152 + 3072), 256, 0, stream>>>(A, vfm, qktb, nx_b, t1_b, nv_b, t2_b);
    }
    attn_mfma_kernel<<<dim3(2048), 256, 0, stream>>>(vfm, qktb, pacc, pml);
    attn_reduce_kernel<<<gar, 256, 0, stream>>>(pacc, pml, ao_b);
    graph_kernel<<<ggr, 256, 0, stream>>>(t1_b, t2_b, idx_c, gbuf_b);
    wowe_kernel<<<gwe, 256, 0, stream>>>(Wo_c, ao_b, We_c, gbuf_b, f12_b);
    gemm_kernel2<0,0,true><<<gg128, 256, 0, stream>>>(Wm_c, 256, f12_b, qa, qb, nullptr, 128, 0, 256);

    // ---- Phase C: vector MLP ----
    {
        LNArgs la{};
        la.x[0] = qb; la.g[0] = g2; la.bt[0] = b2; la.ysp[0] = nx_b;
        ln_kernel<<<dim3(64, B_, 1), 256, 0, stream>>>(la);
    }
    gemm_kernel2<0,5,true><<<gg512, 256, 0, stream>>>(W1, 128, nx_b, nullptr, h1, h1_b, 512, 0, 128);
    gemm_kernel2<0,0,true><<<gg512, 256, 0, stream>>>(Dact, 512, h1_b, nullptr, hd, nullptr, 512, 0, 512);
    leaky_kernel<<<dim3((B_ * HID_ * N_) / 256), 256, 0, stream>>>(h1, hd, h1_b2);
    gemm_kernel2<0,0,true><<<gg128, 256, 0, stream>>>(W2, 512, h1_b2, qb, out, nullptr, 128, 0, 512);
}

// Round 15
// 251.647 us; speedup vs baseline: 1.2887x; 1.0487x over previous
//
#include <hip/hip_runtime.h>
#include <math.h>

#define B_    2
#define C_    128
#define N_    2048
#define HID_  512
#define HEADS_ 8
#define EPS_  1e-6f
#define NS_   0.2f
#define KSPLIT 8

typedef __attribute__((ext_vector_type(8))) short short8v;  // 8 bf16
typedef __attribute__((ext_vector_type(4))) float f32x4;
typedef unsigned short ush;
typedef unsigned int u32;

__device__ inline ush f2bf(float f) {
    unsigned u = __float_as_uint(f);
    u += 0x7FFF + ((u >> 16) & 1);          // round-to-nearest-even
    return (ush)(u >> 16);
}
__device__ inline float bf2f(ush u) { return __uint_as_float((u32)u << 16); }

// pack float -> (hi bf16 << 16) | lo bf16
__device__ inline u32 splitpack(float x) {
    ush hi = f2bf(x);
    float hf = __uint_as_float((u32)hi << 16);
    ush lo = f2bf(x - hf);
    return ((u32)hi << 16) | (u32)lo;
}

__device__ inline void unpack_hi(const u32* buf, short8v& h0, short8v& h1) {
    ush h[16];
    #pragma unroll
    for (int j = 0; j < 16; ++j) h[j] = (ush)(buf[j] >> 16);
    h0 = *(short8v*)&h[0]; h1 = *(short8v*)&h[8];
}

// ---------------------------------------------------------------------------
// vec_layernorm, z-indexed multi-input: writes bf16 plane only
// ---------------------------------------------------------------------------
struct LNArgs {
    const float* x[2]; const float* g[2]; const float* bt[2]; ush* ysp[2];
};
__global__ __launch_bounds__(256) void ln_kernel(LNArgs a)
{
    __shared__ float norms[128][32];
    __shared__ float red1[8][32];
    __shared__ float red2[8][32];
    const int s = blockIdx.z;
    const float* x = a.x[s];
    const float* gma = a.g[s];
    const float* bta = a.bt[s];
    ush* ysp = a.ysp[s];

    const int b  = blockIdx.y;
    const int n0 = blockIdx.x * 32;
    const int nn = threadIdx.x & 31;
    const int cg = threadIdx.x >> 5;

    float s1 = 0.f, s2 = 0.f;
    for (int it = 0; it < 16; ++it) {
        int c = it * 8 + cg;
        size_t base = ((size_t)(b * C_ + c) * 3) * N_ + n0 + nn;
        float x0 = x[base], x1 = x[base + N_], x2 = x[base + 2 * N_];
        float nr = sqrtf(x0 * x0 + x1 * x1 + x2 * x2 + EPS_);
        norms[c][nn] = nr;
        s1 += nr; s2 += nr * nr;
    }
    red1[cg][nn] = s1; red2[cg][nn] = s2;
    __syncthreads();
    float S1 = 0.f, S2 = 0.f;
    #pragma unroll
    for (int g = 0; g < 8; ++g) { S1 += red1[g][nn]; S2 += red2[g][nn]; }
    float mu   = S1 * (1.f / 128.f);
    float var  = S2 * (1.f / 128.f) - mu * mu;
    float rstd = rsqrtf(var + EPS_);

    for (int it = 0; it < 16; ++it) {
        int c = it * 8 + cg;
        float nr = norms[c][nn];
        float ln = (nr - mu) * rstd * gma[c] + bta[c];
        float sc = ln / (nr + EPS_);
        size_t base = ((size_t)(b * C_ + c) * 3) * N_ + n0 + nn;
        ysp[base]          = f2bf(x[base] * sc);
        ysp[base + N_]     = f2bf(x[base + N_] * sc);
        ysp[base + 2 * N_] = f2bf(x[base + 2 * N_] * sc);
    }
}

// ---------------------------------------------------------------------------
// weight split-conversion: 9 weights, one launch (with optional pre-scale)
// ---------------------------------------------------------------------------
struct WCArgs { const float* src[9]; u32* dst[9]; int n[9]; float scale[9]; };
__global__ __launch_bounds__(256) void wconv_kernel(WCArgs a)
{
    const int w = blockIdx.y;
    const int i = blockIdx.x * 256 + threadIdx.x;
    if (i < a.n[w]) a.dst[w][i] = splitpack(a.src[w][i] * a.scale[w]);
}

// ---------------------------------------------------------------------------
// fused output-mix weights: Wfa = Wm[:,0:128]*Wo, Wfb = Wm[:,128:256]*We
// (fp32 dot, split-packed out). 2 phases in one launch; grid 384 x 256.
// ---------------------------------------------------------------------------
struct WFArgs {
    const float* Wm[2]; const float* Wo[2]; const float* We[2];
    u32* Wfa[2]; u32* Wfb[2];
};
__global__ __launch_bounds__(256) void wfuse_kernel(WFArgs a)
{
    const int tg = blockIdx.x * 256 + threadIdx.x;   // 0..98303
    const int p = tg / 49152;
    const int rem = tg % 49152;
    if (rem < 16384) {
        const int o = rem >> 7, k = rem & 127;
        const float* Wm = a.Wm[p];
        const float* Wo = a.Wo[p];
        float acc = 0.f;
        #pragma unroll 4
        for (int c = 0; c < 128; ++c)
            acc += Wm[o * 256 + c] * Wo[c * 128 + k];
        a.Wfa[p][o * 128 + k] = splitpack(acc);
    } else {
        const int r2 = rem - 16384;
        const int o = r2 >> 8, k = r2 & 255;
        const float* Wm = a.Wm[p];
        const float* We = a.We[p];
        float acc = 0.f;
        #pragma unroll 4
        for (int c = 0; c < 128; ++c)
            acc += Wm[o * 256 + 128 + c] * We[c * 256 + k];
        a.Wfb[p][o * 256 + k] = splitpack(acc);
    }
}

// ---------------------------------------------------------------------------
// bf16 MFMA GEMM core (hi-only). XBF: X input is bf16 ush (else split u32).
// XMODE 0: X[(b*K + c)*M + m]   XMODE 1: X[((b*N+n)*3+t)*K + c], m = t*N+n
// OMODE 0: fp32(+Z)  3: bf16 Ybf  4: qkv fragment-major  5: fp32(+Z) + bf16
// ---------------------------------------------------------------------------
template <int XMODE, int OMODE, bool XBF>
__device__ __forceinline__ void gemm_tile(
    const u32* __restrict__ Wsp, int wstride,
    const void* __restrict__ Xv, int K,
    const float* __restrict__ Z, float* __restrict__ Y,
    ush* __restrict__ Ybf, ush* __restrict__ Ytr,
    int b, int m0, int o0loc, int oglob, int Ostr,
    ush (*Wh)[64], ush (*Xh)[64])
{
    const int M = 3 * N_;
    const int tid = threadIdx.x;
    const int lane = tid & 63, wv = tid >> 6;
    const int col = lane & 15, grp = lane >> 4;
    const int wo = wv >> 1, wm = wv & 1;

    f32x4 acc[2][2];
    #pragma unroll
    for (int i = 0; i < 2; ++i)
        #pragma unroll
        for (int j = 0; j < 2; ++j) { f32x4 z = {0.f,0.f,0.f,0.f}; acc[i][j] = z; }

    for (int kk = 0; kk < K; kk += 64) {
        {
            const int o = tid >> 2, kg = tid & 3;
            const u32* src = Wsp + (size_t)(o0loc + o) * wstride + kk + kg * 16;
            u32 buf[16];
            #pragma unroll
            for (int j = 0; j < 4; ++j) *(uint4*)&buf[j * 4] = *(const uint4*)(src + j * 4);
            const int s0 = ((kg * 2)     ^ (o & 7)) << 3;
            const int s1 = ((kg * 2 + 1) ^ (o & 7)) << 3;
            short8v h0, h1; unpack_hi(buf, h0, h1);
            *(short8v*)&Wh[o][s0] = h0; *(short8v*)&Wh[o][s1] = h1;
        }
        if (XMODE == 0) {
            const int m = lane, kq = wv;
            const int s0 = ((kq * 2)     ^ (m & 7)) << 3;
            const int s1 = ((kq * 2 + 1) ^ (m & 7)) << 3;
            if (XBF) {
                const ush* src = (const ush*)Xv + ((size_t)b * K + kk + kq * 16) * M + m0 + m;
                ush h[16];
                #pragma unroll
                for (int j = 0; j < 16; ++j) h[j] = src[(size_t)j * M];
                *(short8v*)&Xh[m][s0] = *(short8v*)&h[0];
                *(short8v*)&Xh[m][s1] = *(short8v*)&h[8];
            } else {
                const u32* src = (const u32*)Xv + ((size_t)b * K + kk + kq * 16) * M + m0 + m;
                u32 buf[16];
                #pragma unroll
                for (int j = 0; j < 16; ++j) buf[j] = src[(size_t)j * M];
                short8v h0, h1; unpack_hi(buf, h0, h1);
                *(short8v*)&Xh[m][s0] = h0; *(short8v*)&Xh[m][s1] = h1;
            }
        } else {
            const int m = tid >> 2, kg = tid & 3;
            const int mg = m0 + m;
            const int n = mg & (N_ - 1), t = mg >> 11;
            const int s0 = ((kg * 2)     ^ (m & 7)) << 3;
            const int s1 = ((kg * 2 + 1) ^ (m & 7)) << 3;
            const ush* src = (const ush*)Xv + ((size_t)(b * N_ + n) * 3 + t) * K + kk + kg * 16;
            ush h[16];
            *(uint4*)&h[0] = *(const uint4*)(src);
            *(uint4*)&h[8] = *(const uint4*)(src + 8);
            *(short8v*)&Xh[m][s0] = *(short8v*)&h[0];
            *(short8v*)&Xh[m][s1] = *(short8v*)&h[8];
        }
        __syncthreads();
        #pragma unroll
        for (int kc = 0; kc < 2; ++kc) {
            const int sk = ((kc * 4 + grp) ^ (col & 7)) << 3;
            short8v ah0 = *(const short8v*)&Wh[wo * 32 + col][sk];
            short8v ah1 = *(const short8v*)&Wh[wo * 32 + 16 + col][sk];
            short8v xh0 = *(const short8v*)&Xh[wm * 32 + col][sk];
            short8v xh1 = *(const short8v*)&Xh[wm * 32 + 16 + col][sk];
            acc[0][0] = __builtin_amdgcn_mfma_f32_16x16x32_bf16(ah0, xh0, acc[0][0], 0, 0, 0);
            acc[0][1] = __builtin_amdgcn_mfma_f32_16x16x32_bf16(ah0, xh1, acc[0][1], 0, 0, 0);
            acc[1][0] = __builtin_amdgcn_mfma_f32_16x16x32_bf16(ah1, xh0, acc[1][0], 0, 0, 0);
            acc[1][1] = __builtin_amdgcn_mfma_f32_16x16x32_bf16(ah1, xh1, acc[1][1], 0, 0, 0);
        }
        __syncthreads();
    }
    #pragma unroll
    for (int of = 0; of < 2; ++of) {
        #pragma unroll
        for (int r = 0; r < 4; ++r) {
            const int o = oglob + wo * 32 + of * 16 + grp * 4 + r;
            #pragma unroll
            for (int mf = 0; mf < 2; ++mf) {
                const int mloc = m0 + wm * 32 + mf * 16 + col;
                const size_t idx = ((size_t)b * Ostr + o) * M + mloc;
                float v = acc[of][mf][r];
                if (OMODE == 0 || OMODE == 5) {
                    if (Z) v += Z[idx];
                    Y[idx] = v;
                }
                if (OMODE == 3 || OMODE == 5) Ybf[idx] = f2bf(v);
                if (OMODE == 4) {
                    ush bv = f2bf(v);
                    const int t = mloc >> 11, n = mloc & (N_ - 1);
                    const int h = (o >> 4) & 7, cl = o & 15;
                    const int d = cl * 3 + t;
                    if (o >= 256) {
                        const int kt = n >> 6, hh = (n >> 5) & 1, db = d >> 4;
                        const size_t idx2 = ((size_t)(b * 8 + h) * 192
                                           + (kt * 2 + hh) * 3 + db) * 512
                                          + (((n >> 3) & 3) * 16 + (d & 15)) * 8 + (n & 7);
                        Ybf[idx2] = bv;
                    } else {
                        const int isK = (o >> 7) & 1;
                        const int qg = n >> 4, half = d >> 5;
                        const size_t idx2 = ((size_t)(isK * 16 + b * 8 + h) * 256
                                           + qg * 2 + half) * 512
                                          + (((d >> 3) & 3) * 16 + (n & 15)) * 8 + (d & 7);
                        Ytr[idx2] = bv;
                    }
                }
            }
        }
    }
}

template <int XMODE, int OMODE, bool XBF>
__global__ __launch_bounds__(256) void gemm_kernel2(
    const u32* __restrict__ Wsp, int wstride,
    const void* __restrict__ Xv,
    const float* __restrict__ Z,
    float* __restrict__ Y, ush* __restrict__ Ybf,
    int Ostr, int obase, int K)
{
    __shared__ __align__(16) ush Wh[64][64];
    __shared__ __align__(16) ush Xh[64][64];
    gemm_tile<XMODE, OMODE, XBF>(Wsp, wstride, Xv, K, Z, Y, Ybf, nullptr,
                            blockIdx.z, blockIdx.x * 64,
                            blockIdx.y * 64, obase + blockIdx.y * 64, Ostr,
                            Wh, Xh);
}

// ---------------------------------------------------------------------------
// fused output mix: Y = Wfa*ao (K=128, XMODE0) + Wfb*gbuf (K=256, XMODE1) + Z
// grid (96, 2, B), 64x64 tiles, hi-only.
// ---------------------------------------------------------------------------
__global__ __launch_bounds__(256) void wm2_kernel(
    const u32* __restrict__ Wfa, const u32* __restrict__ Wfb,
    const ush* __restrict__ ao, const ush* __restrict__ gb,
    const float* __restrict__ Z, float* __restrict__ Y)
{
    __shared__ __align__(16) ush Wh[64][64];
    __shared__ __align__(16) ush Xh[64][64];
    const int M = 3 * N_;
    const int b = blockIdx.z;
    const int m0 = blockIdx.x * 64;
    const int o0 = blockIdx.y * 64;
    const int tid = threadIdx.x;
    const int lane = tid & 63, wv = tid >> 6;
    const int col = lane & 15, grp = lane >> 4;
    const int wo = wv >> 1, wm = wv & 1;

    f32x4 acc[2][2];
    #pragma unroll
    for (int i = 0; i < 2; ++i)
        #pragma unroll
        for (int j = 0; j < 2; ++j) { f32x4 z = {0.f,0.f,0.f,0.f}; acc[i][j] = z; }

    // ---- segment A: Wfa (stride 128) x ao (XMODE0, K=128) ----
    for (int kk = 0; kk < 128; kk += 64) {
        {
            const int o = tid >> 2, kg = tid & 3;
            const u32* src = Wfa + (size_t)(o0 + o) * 128 + kk + kg * 16;
            u32 buf[16];
            #pragma unroll
            for (int j = 0; j < 4; ++j) *(uint4*)&buf[j * 4] = *(const uint4*)(src + j * 4);
            const int s0 = ((kg * 2)     ^ (o & 7)) << 3;
            const int s1 = ((kg * 2 + 1) ^ (o & 7)) << 3;
            short8v h0, h1; unpack_hi(buf, h0, h1);
            *(short8v*)&Wh[o][s0] = h0; *(short8v*)&Wh[o][s1] = h1;
        }
        {
            const int m = lane, kq = wv;
            const int s0 = ((kq * 2)     ^ (m & 7)) << 3;
            const int s1 = ((kq * 2 + 1) ^ (m & 7)) << 3;
            const ush* src = ao + ((size_t)b * 128 + kk + kq * 16) * M + m0 + m;
            ush h[16];
            #pragma unroll
            for (int j = 0; j < 16; ++j) h[j] = src[(size_t)j * M];
            *(short8v*)&Xh[m][s0] = *(short8v*)&h[0];
            *(short8v*)&Xh[m][s1] = *(short8v*)&h[8];
        }
        __syncthreads();
        #pragma unroll
        for (int kc = 0; kc < 2; ++kc) {
            const int sk = ((kc * 4 + grp) ^ (col & 7)) << 3;
            short8v ah0 = *(const short8v*)&Wh[wo * 32 + col][sk];
            short8v ah1 = *(const short8v*)&Wh[wo * 32 + 16 + col][sk];
            short8v xh0 = *(const short8v*)&Xh[wm * 32 + col][sk];
            short8v xh1 = *(const short8v*)&Xh[wm * 32 + 16 + col][sk];
            acc[0][0] = __builtin_amdgcn_mfma_f32_16x16x32_bf16(ah0, xh0, acc[0][0], 0, 0, 0);
            acc[0][1] = __builtin_amdgcn_mfma_f32_16x16x32_bf16(ah0, xh1, acc[0][1], 0, 0, 0);
            acc[1][0] = __builtin_amdgcn_mfma_f32_16x16x32_bf16(ah1, xh0, acc[1][0], 0, 0, 0);
            acc[1][1] = __builtin_amdgcn_mfma_f32_16x16x32_bf16(ah1, xh1, acc[1][1], 0, 0, 0);
        }
        __syncthreads();
    }

    // ---- segment B: Wfb (stride 256) x gbuf (XMODE1, K=256) ----
    for (int kk = 0; kk < 256; kk += 64) {
        {
            const int o = tid >> 2, kg = tid & 3;
            const u32* src = Wfb + (size_t)(o0 + o) * 256 + kk + kg * 16;
            u32 buf[16];
            #pragma unroll
            for (int j = 0; j < 4; ++j) *(uint4*)&buf[j * 4] = *(const uint4*)(src + j * 4);
            const int s0 = ((kg * 2)     ^ (o & 7)) << 3;
            const int s1 = ((kg * 2 + 1) ^ (o & 7)) << 3;
            short8v h0, h1; unpack_hi(buf, h0, h1);
            *(short8v*)&Wh[o][s0] = h0; *(short8v*)&Wh[o][s1] = h1;
        }
        {
            const int m = tid >> 2, kg = tid & 3;
            const int mg = m0 + m;
            const int n = mg & (N_ - 1), t = mg >> 11;
            const int s0 = ((kg * 2)     ^ (m & 7)) << 3;
            const int s1 = ((kg * 2 + 1) ^ (m & 7)) << 3;
            const ush* src = gb + ((size_t)(b * N_ + n) * 3 + t) * 256 + kk + kg * 16;
            ush h[16];
            *(uint4*)&h[0] = *(const uint4*)(src);
            *(uint4*)&h[8] = *(const uint4*)(src + 8);
            *(short8v*)&Xh[m][s0] = *(short8v*)&h[0];
            *(short8v*)&Xh[m][s1] = *(short8v*)&h[8];
        }
        __syncthreads();
        #pragma unroll
        for (int kc = 0; kc < 2; ++kc) {
            const int sk = ((kc * 4 + grp) ^ (col & 7)) << 3;
            short8v ah0 = *(const short8v*)&Wh[wo * 32 + col][sk];
            short8v ah1 = *(const short8v*)&Wh[wo * 32 + 16 + col][sk];
            short8v xh0 = *(const short8v*)&Xh[wm * 32 + col][sk];
            short8v xh1 = *(const short8v*)&Xh[wm * 32 + 16 + col][sk];
            acc[0][0] = __builtin_amdgcn_mfma_f32_16x16x32_bf16(ah0, xh0, acc[0][0], 0, 0, 0);
            acc[0][1] = __builtin_amdgcn_mfma_f32_16x16x32_bf16(ah0, xh1, acc[0][1], 0, 0, 0);
            acc[1][0] = __builtin_amdgcn_mfma_f32_16x16x32_bf16(ah1, xh0, acc[1][0], 0, 0, 0);
            acc[1][1] = __builtin_amdgcn_mfma_f32_16x16x32_bf16(ah1, xh1, acc[1][1], 0, 0, 0);
        }
        __syncthreads();
    }

    // ---- epilogue: Y = acc + Z ----
    #pragma unroll
    for (int of = 0; of < 2; ++of) {
        #pragma unroll
        for (int r = 0; r < 4; ++r) {
            const int o = o0 + wo * 32 + of * 16 + grp * 4 + r;
            #pragma unroll
            for (int mf = 0; mf < 2; ++mf) {
                const int mloc = m0 + wm * 32 + mf * 16 + col;
                const size_t idx = ((size_t)b * 128 + o) * M + mloc;
                Y[idx] = acc[of][mf][r] + Z[idx];
            }
        }
    }
}

struct QKVArgs {
    const u32* W0; const u32* W1; const u32* W2;
    const ush* X0; const ush* X1; const ush* X2;
};

// fused: qkv projections (blocks 0..1151, fragment-major outputs) +
// bf16 transpose(s) (blocks 1152.., (B,C,3,N) bf16 -> (B,N,3,C) bf16)
__global__ __launch_bounds__(256) void qkv_tr_kernel(QKVArgs A,
        ush* __restrict__ vfm, ush* __restrict__ qktb,
        const ush* __restrict__ ts0, ush* __restrict__ td0,
        const ush* __restrict__ ts1, ush* __restrict__ td1)
{
    __shared__ __align__(16) ush Wh[64][64];
    __shared__ __align__(16) ush Xh[64][64];
    __shared__ ush ttile[32][34];
    const int bx = blockIdx.x;
    if (bx < 1152) {
        const int z = bx / 576, rem = bx % 576;
        const int y = rem / 96, x = rem % 96;
        const int wi = y >> 1;
        const u32* W = wi == 0 ? A.W0 : (wi == 1 ? A.W1 : A.W2);
        const ush* X = wi == 0 ? A.X0 : (wi == 1 ? A.X1 : A.X2);
        gemm_tile<0, 4, true>(W, 128, X, 128, nullptr, nullptr, vfm, qktb,
                        z, x * 64, (y & 1) * 64, y * 64, 384,
                        Wh, Xh);
    } else {
        int i = bx - 1152;
        const int which = i / 1536; i %= 1536;
        const ush* src = which ? ts1 : ts0;
        ush* dst = which ? td1 : td0;
        const int x = i & 63, y = (i >> 6) & 3, z = i >> 8;
        const int b = z / 3, t = z % 3;
        const int n0 = x * 32, c0 = y * 32;
        const int tx = threadIdx.x & 31, ty = threadIdx.x >> 5;
        #pragma unroll
        for (int p = 0; p < 4; ++p) {
            int c = c0 + ty + p * 8;
            ttile[ty + p * 8][tx] = src[((size_t)(b * C_ + c) * 3 + t) * N_ + n0 + tx];
        }
        __syncthreads();
        #pragma unroll
        for (int p = 0; p < 4; ++p) {
            int n = n0 + ty + p * 8;
            dst[((size_t)(b * N_ + n) * 3 + t) * C_ + c0 + tx] = ttile[tx][ty + p * 8];
        }
    }
}

// ---------------------------------------------------------------------------
// barrier-free split-K flash attention, XCD-chunked 1D grid (2048 blocks),
// fragment-major coalesced operands (verified round-10/11 configuration).
// ---------------------------------------------------------------------------
__global__ __launch_bounds__(256) void attn_mfma_kernel(
    const ush* __restrict__ vfm, const ush* __restrict__ qktb,
    ush* __restrict__ pacc, float* __restrict__ pml)
{
    __shared__ __align__(16) ush Pl[4][2][16][64];   // 16 KB

    const int flat = blockIdx.x;
    const int xcd  = flat & 7;
    const int slot = flat >> 3;
    const int gid  = xcd * 4 + (slot >> 6);
    const int q32  = slot & 63;
    const int bh   = gid & 15;
    const int zz   = gid >> 4;

    const int tid = threadIdx.x;
    const int lane = tid & 63, wv = tid >> 6;
    const int col = lane & 15, grp = lane >> 4;
    const int c7  = col & 7;
    const int kz  = zz * 4 + wv;
    const int ks0 = kz * (N_ / KSPLIT);

    const ush* Qpl = qktb + (size_t)bh * 131072;
    const ush* Kpl = qktb + (size_t)(16 + bh) * 131072;
    const ush* Vpl = vfm  + (size_t)bh * 98304;

    short8v qf[2][2];
    #pragma unroll
    for (int qi = 0; qi < 2; ++qi) {
        const int qg = q32 * 2 + qi;
        qf[qi][0] = *(const short8v*)(Qpl + ((size_t)qg * 2 + 0) * 512 + lane * 8);
        qf[qi][1] = *(const short8v*)(Qpl + ((size_t)qg * 2 + 1) * 512 + lane * 8);
    }

    f32x4 acc[2][3];
    #pragma unroll
    for (int qi = 0; qi < 2; ++qi)
        #pragma unroll
        for (int db = 0; db < 3; ++db) { f32x4 z = {0.f,0.f,0.f,0.f}; acc[qi][db] = z; }
    float m_i[2] = {0.f, 0.f};
    float l_l[2] = {0.f, 0.f};

    const int NT = (N_ / KSPLIT) / 64;
    for (int mt = 0; mt < NT; ++mt) {
        const int m0 = ks0 + mt * 64;

        short8v ka[4][2];
        #pragma unroll
        for (int kb = 0; kb < 4; ++kb) {
            const size_t kg = (m0 >> 4) + kb;
            ka[kb][0] = *(const short8v*)(Kpl + (kg * 2 + 0) * 512 + lane * 8);
            ka[kb][1] = *(const short8v*)(Kpl + (kg * 2 + 1) * 512 + lane * 8);
        }
        const int kt = m0 >> 6;
        short8v vf[2][3];
        #pragma unroll
        for (int hh = 0; hh < 2; ++hh)
            #pragma unroll
            for (int db = 0; db < 3; ++db)
                vf[hh][db] = *(const short8v*)(Vpl + (size_t)((kt * 2 + hh) * 3 + db) * 512 + lane * 8);

        f32x4 sf[2][4];
        __builtin_amdgcn_s_setprio(1);
        #pragma unroll
        for (int qi = 0; qi < 2; ++qi)
            #pragma unroll
            for (int kb = 0; kb < 4; ++kb) {
                f32x4 z = {0.f, 0.f, 0.f, 0.f};
                z = __builtin_amdgcn_mfma_f32_16x16x32_bf16(ka[kb][0], qf[qi][0], z, 0, 0, 0);
                z = __builtin_amdgcn_mfma_f32_16x16x32_bf16(ka[kb][1], qf[qi][1], z, 0, 0, 0);
                sf[qi][kb] = z;
            }
        __builtin_amdgcn_s_setprio(0);

        #pragma unroll
        for (int qi = 0; qi < 2; ++qi) {
            float psum = 0.f;
            #pragma unroll
            for (int kb = 0; kb < 4; ++kb) {
                float e0 = __expf(sf[qi][kb][0] - m_i[qi]);
                float e1 = __expf(sf[qi][kb][1] - m_i[qi]);
                float e2 = __expf(sf[qi][kb][2] - m_i[qi]);
                float e3 = __expf(sf[qi][kb][3] - m_i[qi]);
                psum += (e0 + e1) + (e2 + e3);
                u32 r0, r1;
                asm("v_cvt_pk_bf16_f32 %0, %1, %2" : "=v"(r0) : "v"(e0), "v"(e1));
                asm("v_cvt_pk_bf16_f32 %0, %1, %2" : "=v"(r1) : "v"(e2), "v"(e3));
                const int un = (4 * kb + grp) ^ (c7 << 1);
                uint2 pk2; pk2.x = r0; pk2.y = r1;
                *(uint2*)&Pl[wv][qi][col][un << 2] = pk2;
            }
            l_l[qi] += psum;
        }

        __builtin_amdgcn_s_setprio(1);
        #pragma unroll
        for (int qi = 0; qi < 2; ++qi)
            #pragma unroll
            for (int hh = 0; hh < 2; ++hh) {
                const int ur = (8 * hh + 2 * grp) ^ (c7 << 1);
                short8v pf = *(const short8v*)&Pl[wv][qi][col][ur << 2];
                #pragma unroll
                for (int db = 0; db < 3; ++db)
                    acc[qi][db] = __builtin_amdgcn_mfma_f32_16x16x32_bf16(vf[hh][db], pf, acc[qi][db], 0, 0, 0);
            }
        __builtin_amdgcn_s_setprio(0);

        #pragma unroll
        for (int qi = 0; qi < 2; ++qi) {
            float pmax = -1e30f;
            #pragma unroll
            for (int kb = 0; kb < 4; ++kb)
                #pragma unroll
                for (int r = 0; r < 4; ++r) pmax = fmaxf(pmax, sf[qi][kb][r]);
            pmax = fmaxf(pmax, __shfl_xor(pmax, 16, 64));
            pmax = fmaxf(pmax, __shfl_xor(pmax, 32, 64));
            if (!__all(pmax - m_i[qi] <= 8.0f)) {
                float mnew = fmaxf(m_i[qi], pmax);
                float sc = __expf(m_i[qi] - mnew);
                l_l[qi] *= sc;
                #pragma unroll
                for (int db = 0; db < 3; ++db) {
                    acc[qi][db][0] *= sc; acc[qi][db][1] *= sc;
                    acc[qi][db][2] *= sc; acc[qi][db][3] *= sc;
                }
                m_i[qi] = mnew;
            }
        }
    }

    const int ntile = q32 >> 1, qh = q32 & 1;
    const size_t pb = (size_t)(kz * 16 + bh) * 32 + ntile;
    #pragma unroll
    for (int qi = 0; qi < 2; ++qi) {
        float l = l_l[qi];
        l += __shfl_xor(l, 16, 64);
        l += __shfl_xor(l, 32, 64);
        const int q = qh * 32 + qi * 16 + col;
        #pragma unroll
        for (int db = 0; db < 3; ++db)
            #pragma unroll
            for (int r = 0; r < 4; ++r) {
                int d = db * 16 + grp * 4 + r;
                pacc[pb * 3072 + d * 64 + q] = f2bf(acc[qi][db][r]);
            }
        if (grp == 0) {
            pml[pb * 128 + q]      = m_i[qi];
            pml[pb * 128 + 64 + q] = l;
        }
    }
}

// ---------------------------------------------------------------------------
// graph attention: bf16 in (B,N,3,C), LDS neighbor cache, bf16 edge out
// ---------------------------------------------------------------------------
__global__ __launch_bounds__(256) void graph_kernel(
    const ush* __restrict__ tq, const ush* __restrict__ tv,
    const int* __restrict__ idx, ush* __restrict__ gbuf)
{
    __shared__ float centerf[384];
    __shared__ ush nbr_l[16][384];
    __shared__ float sd[16];
    __shared__ int nbr_i[16];
    const int b = blockIdx.y, n = blockIdx.x;
    const int tid = threadIdx.x;
    const ush* qrow = tq + (size_t)(b * N_ + n) * 384;
    for (int e = tid; e < 384; e += 256) centerf[e] = bf2f(qrow[e]);
    if (tid < 16) nbr_i[tid] = idx[(size_t)(b * N_ + n) * 16 + tid];
    __syncthreads();

    const int lane = tid & 63, wv = tid >> 6;
    for (int kk = 0; kk < 4; ++kk) {
        int k = wv * 4 + kk;
        const u32* vrow = (const u32*)(tv + ((size_t)b * N_ + nbr_i[k]) * 384);
        float p = 0.f;
        #pragma unroll
        for (int jj = 0; jj < 3; ++jj) {
            int e2 = lane + jj * 64;
            u32 v2 = vrow[e2];
            ((u32*)nbr_l[k])[e2] = v2;
            p += centerf[e2 * 2]     * bf2f((ush)(v2 & 0xffff))
               + centerf[e2 * 2 + 1] * bf2f((ush)(v2 >> 16));
        }
        #pragma unroll
        for (int off = 32; off; off >>= 1) p += __shfl_down(p, off, 64);
        if (lane == 0) sd[k] = p * 0.05103103630798288f;
    }
    __syncthreads();

    float mx = -1e30f;
    #pragma unroll
    for (int k = 0; k < 16; ++k) mx = fmaxf(mx, sd[k]);
    float a[16]; float ssum = 0.f;
    #pragma unroll
    for (int k = 0; k < 16; ++k) { a[k] = __expf(sd[k] - mx); ssum += a[k]; }
    float inv = 1.f / ssum;

    for (int e = tid; e < 384; e += 256) {
        float accv = 0.f;
        #pragma unroll
        for (int k = 0; k < 16; ++k)
            accv += a[k] * bf2f(nbr_l[k][e]);
        accv *= inv;
        float ce = centerf[e];
        int t = e >> 7, c = e & 127;
        size_t gb = ((size_t)(b * N_ + n) * 3 + t) * 256;
        gbuf[gb + c]       = f2bf(accv - ce);
        gbuf[gb + 128 + c] = f2bf(ce);
    }
}

// ---------------------------------------------------------------------------
// split-K reduce: combine KSPLIT partials -> bf16 ao
// ---------------------------------------------------------------------------
__global__ __launch_bounds__(256) void attn_reduce_kernel(
    const ush* __restrict__ pacc, const float* __restrict__ pml,
    ush* __restrict__ ao)
{
    const int nt = blockIdx.x, bh = blockIdx.y;
    const int b = bh >> 3, h = bh & 7;
    const int tid = threadIdx.x;
    const int q = tid & 63, dg = tid >> 6;

    size_t pb[KSPLIT];
    float m[KSPLIT], l[KSPLIT];
    #pragma unroll
    for (int kz = 0; kz < KSPLIT; ++kz) {
        pb[kz] = (size_t)(kz * 16 + bh) * 32 + nt;
        m[kz] = pml[pb[kz] * 128 + q];
        l[kz] = pml[pb[kz] * 128 + 64 + q];
    }
    float ms = -1e30f;
    #pragma unroll
    for (int kz = 0; kz < KSPLIT; ++kz) ms = fmaxf(ms, m[kz]);
    float w[KSPLIT], ls = 0.f;
    #pragma unroll
    for (int kz = 0; kz < KSPLIT; ++kz) { w[kz] = __expf(m[kz] - ms); ls += l[kz] * w[kz]; }
    const float inv = 1.f / ls;

    const size_t hb = ((size_t)(b * C_ + h * 16)) * 3 * N_;
    #pragma unroll
    for (int j = 0; j < 12; ++j) {
        int d = dg * 12 + j;
        float o = 0.f;
        #pragma unroll
        for (int kz = 0; kz < KSPLIT; ++kz)
            o += bf2f(pacc[pb[kz] * 3072 + d * 64 + q]) * w[kz];
        ao[hb + (size_t)d * N_ + nt * 64 + q] = f2bf(o * inv);
    }
}

// ---------------------------------------------------------------------------
// vn_leaky: fp32 x,d in -> bf16 out
// ---------------------------------------------------------------------------
__global__ __launch_bounds__(256) void leaky_kernel(const float* __restrict__ x,
                                                    const float* __restrict__ d,
                                                    ush* __restrict__ y)
{
    size_t p = (size_t)blockIdx.x * 256 + threadIdx.x;
    size_t bh = p / N_, n = p % N_;
    size_t base = bh * 3 * N_ + n;
    float x0 = x[base], x1 = x[base + N_], x2 = x[base + 2 * N_];
    float d0 = d[base], d1 = d[base + N_], d2 = d[base + 2 * N_];
    float dot = x0 * d0 + x1 * d1 + x2 * d2;
    float dsq = d0 * d0 + d1 * d1 + d2 * d2;
    float f = dot / (dsq + EPS_);
    bool pos = dot >= 0.f;
    float y0 = pos ? x0 : x0 - f * d0;
    float y1 = pos ? x1 : x1 - f * d1;
    float y2 = pos ? x2 : x2 - f * d2;
    y[base]          = f2bf(NS_ * x0 + (1.f - NS_) * y0);
    y[base + N_]     = f2bf(NS_ * x1 + (1.f - NS_) * y1);
    y[base + 2 * N_] = f2bf(NS_ * x2 + (1.f - NS_) * y2);
}

// ---------------------------------------------------------------------------
extern "C" void kernel_launch(void* const* d_in, const int* in_sizes, int n_in,
                              void* d_out, int out_size, void* d_ws, size_t ws_size,
                              hipStream_t stream)
{
    const float* q_in = (const float*)d_in[0];
    const float* v_in = (const float*)d_in[1];
    const int*   idx_s = (const int*)d_in[4];
    const int*   idx_c = (const int*)d_in[5];
    const float* g1 = (const float*)d_in[6];
    const float* b1 = (const float*)d_in[7];
    const float* g2 = (const float*)d_in[8];
    const float* b2 = (const float*)d_in[9];
    const float* gq = (const float*)d_in[10];
    const float* bq = (const float*)d_in[11];
    const float* gv = (const float*)d_in[12];
    const float* bv = (const float*)d_in[13];
    float* out = (float*)d_out;
    float* ws  = (float*)d_ws;

    const size_t S1 = (size_t)B_ * C_ * 3 * N_; // 1572864 elems
    ush*   nx_b  = (ush*)(ws + 2*S1);  // 2 (half)
    ush*   nv_b  = (ush*)(ws + 3*S1);  // 3 (half)
    ush*   vfm   = (ush*)(ws + 4*S1);  // 4: 3MB
    ush*   qktb  = (ush*)(ws + 5*S1) + S1;  // 5.5-6.84: 8.4MB
    ush*   ao_b  = (ush*)(ws + 7*S1);  // 7 (half)
    ush*   gbuf_b= (ush*)(ws + 8*S1);  // 8 (written after pacc dead)
    float* qa    = ws + 12*S1;         // 12
    float* qb    = ws + 13*S1;         // 13
    ush*   t1_b  = (ush*)(ws + 14*S1); // 14 (half)
    ush*   t2_b  = (ush*)(ws + 15*S1); // 15 (half)
    u32*   wsp   = (u32*)(ws + 16*S1); // 16+
    // split-K attention partials (attn->reduce window only)
    ush*   pacc  = (ush*)(ws + 8*S1);  // 8-11: 25.2MB (dead before graph writes gbuf)
    float* pml   = (float*)(ws + 2*S1);// 2 (attn after qkv consumed nx_b)
    // phase C aliases:
    float* hd    = ws;                 // 0-3
    float* h1    = ws + 4*S1;          // 4-7
    ush*   h1_b  = (ush*)(ws + 14*S1); // 14-15 (t1/t2 dead)
    ush*   h1_b2 = (ush*)(ws + 8*S1);  // 8-9 (gbuf dead)

    // weight planes: 9 split-converted + 4 fused (Wfa/Wfb per phase)
    const int wn[9]   = {16384,16384,16384, 16384,16384,16384, 65536,262144,65536};
    const int wsrc[9] = {14,15,16, 20,21,22, 26,27,28};
    u32* wd[9];
    {
        int off = 0;
        for (int i = 0; i < 9; ++i) { wd[i] = wsp + off; off += wn[i]; }
    }
    u32 *Wq_s = wd[0], *Wk_s = wd[1], *Wv_s = wd[2];
    u32 *Wq_c = wd[3], *Wk_c = wd[4], *Wv_c = wd[5];
    u32 *W1 = wd[6], *Dact = wd[7], *W2 = wd[8];
    u32* Wfa_s = wsp + 491520;
    u32* Wfb_s = Wfa_s + 16384;
    u32* Wfa_c = Wfb_s + 32768;
    u32* Wfb_c = Wfa_c + 16384;

    // zero qktb once per launch (d=48..63 pad slots must be 0)
    hipMemsetAsync(qktb, 0, (size_t)32 * 131072 * sizeof(ush), stream);

    {
        WCArgs a;
        for (int i = 0; i < 9; ++i) {
            a.src[i] = (const float*)d_in[wsrc[i]];
            a.dst[i] = wd[i];
            a.n[i]   = wn[i];
            a.scale[i] = 1.f;
        }
        a.scale[0] = 0.14433756729740643f;  // Wq_s: fold 1/sqrt(48)
        a.scale[3] = 0.14433756729740643f;  // Wq_c
        wconv_kernel<<<dim3(1024, 9), 256, 0, stream>>>(a);
    }
    {
        WFArgs a;
        a.Wm[0] = (const float*)d_in[19]; a.Wo[0] = (const float*)d_in[17]; a.We[0] = (const float*)d_in[18];
        a.Wm[1] = (const float*)d_in[25]; a.Wo[1] = (const float*)d_in[23]; a.We[1] = (const float*)d_in[24];
        a.Wfa[0] = Wfa_s; a.Wfb[0] = Wfb_s;
        a.Wfa[1] = Wfa_c; a.Wfb[1] = Wfb_c;
        wfuse_kernel<<<dim3(384), 256, 0, stream>>>(a);
    }

    dim3 gar(N_ / 64, B_ * HEADS_);
    dim3 ggr(N_, B_);
    dim3 gwm(96, 2, B_);
    dim3 gg512(96, 8, B_);

    // ---- Phase A: self attention block ----
    {
        LNArgs la{};
        la.x[0] = q_in; la.g[0] = g1; la.bt[0] = b1; la.ysp[0] = nx_b;
        ln_kernel<<<dim3(64, B_, 1), 256, 0, stream>>>(la);
    }
    {
        QKVArgs A{Wq_s, Wk_s, Wv_s, nx_b, nx_b, nx_b};
        qkv_tr_kernel<<<dim3(1152 + 1536), 256, 0, stream>>>(A, vfm, qktb, nx_b, t1_b, nullptr, nullptr);
    }
    attn_mfma_kernel<<<dim3(2048), 256, 0, stream>>>(vfm, qktb, pacc, pml);
    attn_reduce_kernel<<<gar, 256, 0, stream>>>(pacc, pml, ao_b);
    graph_kernel<<<ggr, 256, 0, stream>>>(t1_b, t1_b, idx_s, gbuf_b);
    wm2_kernel<<<gwm, 256, 0, stream>>>(Wfa_s, Wfb_s, ao_b, gbuf_b, q_in, qa);

    // ---- Phase B: cross attention block ----
    {
        LNArgs la{};
        la.x[0] = qa;   la.g[0] = gq; la.bt[0] = bq; la.ysp[0] = nx_b;
        la.x[1] = v_in; la.g[1] = gv; la.bt[1] = bv; la.ysp[1] = nv_b;
        ln_kernel<<<dim3(64, B_, 2), 256, 0, stream>>>(la);
    }
    {
        QKVArgs A{Wq_c, Wk_c, Wv_c, nx_b, nv_b, nv_b};
        qkv_tr_kernel<<<dim3(1152 + 3072), 256, 0, stream>>>(A, vfm, qktb, nx_b, t1_b, nv_b, t2_b);
    }
    attn_mfma_kernel<<<dim3(2048), 256, 0, stream>>>(vfm, qktb, pacc, pml);
    attn_reduce_kernel<<<gar, 256, 0, stream>>>(pacc, pml, ao_b);
    graph_kernel<<<ggr, 256, 0, stream>>>(t1_b, t2_b, idx_c, gbuf_b);
    wm2_kernel<<<gwm, 256, 0, stream>>>(Wfa_c, Wfb_c, ao_b, gbuf_b, qa, qb);

    // ---- Phase C: vector MLP ----
    {
        LNArgs la{};
        la.x[0] = qb; la.g[0] = g2; la.bt[0] = b2; la.ysp[0] = nx_b;
        ln_kernel<<<dim3(64, B_, 1), 256, 0, stream>>>(la);
    }
    gemm_kernel2<0,5,true><<<gg512, 256, 0, stream>>>(W1, 128, nx_b, nullptr, h1, h1_b, 512, 0, 128);
    gemm_kernel2<0,0,true><<<gg512, 256, 0, stream>>>(Dact, 512, h1_b, nullptr, hd, nullptr, 512, 0, 512);
    leaky_kernel<<<dim3((B_ * HID_ * N_) / 256), 256, 0, stream>>>(h1, hd, h1_b2);
    gemm_kernel2<0,0,true><<<dim3(96, 2, B_), 256, 0, stream>>>(W2, 512, h1_b2, qb, out, nullptr, 128, 0, 512);
}

// Round 16
// 239.207 us; speedup vs baseline: 1.3557x; 1.0520x over previous
//
#include <hip/hip_runtime.h>
#include <math.h>

#define B_    2
#define C_    128
#define N_    2048
#define HID_  512
#define HEADS_ 8
#define EPS_  1e-6f
#define NS_   0.2f
#define KSPLIT 8

typedef __attribute__((ext_vector_type(8))) short short8v;  // 8 bf16
typedef __attribute__((ext_vector_type(4))) float f32x4;
typedef unsigned short ush;
typedef unsigned int u32;

__device__ inline ush f2bf(float f) {
    unsigned u = __float_as_uint(f);
    u += 0x7FFF + ((u >> 16) & 1);          // round-to-nearest-even
    return (ush)(u >> 16);
}
__device__ inline float bf2f(ush u) { return __uint_as_float((u32)u << 16); }

// pack float -> (hi bf16 << 16) | lo bf16
__device__ inline u32 splitpack(float x) {
    ush hi = f2bf(x);
    float hf = __uint_as_float((u32)hi << 16);
    ush lo = f2bf(x - hf);
    return ((u32)hi << 16) | (u32)lo;
}

__device__ inline void unpack_hi(const u32* buf, short8v& h0, short8v& h1) {
    ush h[16];
    #pragma unroll
    for (int j = 0; j < 16; ++j) h[j] = (ush)(buf[j] >> 16);
    h0 = *(short8v*)&h[0]; h1 = *(short8v*)&h[8];
}

// ---------------------------------------------------------------------------
// vec_layernorm, z-indexed multi-input: writes bf16 plane only
// ---------------------------------------------------------------------------
struct LNArgs {
    const float* x[2]; const float* g[2]; const float* bt[2]; ush* ysp[2];
};
__global__ __launch_bounds__(256) void ln_kernel(LNArgs a)
{
    __shared__ float norms[128][32];
    __shared__ float red1[8][32];
    __shared__ float red2[8][32];
    const int s = blockIdx.z;
    const float* x = a.x[s];
    const float* gma = a.g[s];
    const float* bta = a.bt[s];
    ush* ysp = a.ysp[s];

    const int b  = blockIdx.y;
    const int n0 = blockIdx.x * 32;
    const int nn = threadIdx.x & 31;
    const int cg = threadIdx.x >> 5;

    float s1 = 0.f, s2 = 0.f;
    for (int it = 0; it < 16; ++it) {
        int c = it * 8 + cg;
        size_t base = ((size_t)(b * C_ + c) * 3) * N_ + n0 + nn;
        float x0 = x[base], x1 = x[base + N_], x2 = x[base + 2 * N_];
        float nr = sqrtf(x0 * x0 + x1 * x1 + x2 * x2 + EPS_);
        norms[c][nn] = nr;
        s1 += nr; s2 += nr * nr;
    }
    red1[cg][nn] = s1; red2[cg][nn] = s2;
    __syncthreads();
    float S1 = 0.f, S2 = 0.f;
    #pragma unroll
    for (int g = 0; g < 8; ++g) { S1 += red1[g][nn]; S2 += red2[g][nn]; }
    float mu   = S1 * (1.f / 128.f);
    float var  = S2 * (1.f / 128.f) - mu * mu;
    float rstd = rsqrtf(var + EPS_);

    for (int it = 0; it < 16; ++it) {
        int c = it * 8 + cg;
        float nr = norms[c][nn];
        float ln = (nr - mu) * rstd * gma[c] + bta[c];
        float sc = ln / (nr + EPS_);
        size_t base = ((size_t)(b * C_ + c) * 3) * N_ + n0 + nn;
        ysp[base]          = f2bf(x[base] * sc);
        ysp[base + N_]     = f2bf(x[base + N_] * sc);
        ysp[base + 2 * N_] = f2bf(x[base + 2 * N_] * sc);
    }
}

// ---------------------------------------------------------------------------
// weight split-conversion: 9 weights, one launch (with optional pre-scale)
// ---------------------------------------------------------------------------
struct WCArgs { const float* src[9]; u32* dst[9]; int n[9]; float scale[9]; };
__global__ __launch_bounds__(256) void wconv_kernel(WCArgs a)
{
    const int w = blockIdx.y;
    const int i = blockIdx.x * 256 + threadIdx.x;
    if (i < a.n[w]) a.dst[w][i] = splitpack(a.src[w][i] * a.scale[w]);
}

// ---------------------------------------------------------------------------
// fused output-mix weights: Wfa = Wm[:,0:128]*Wo, Wfb = Wm[:,128:256]*We
// ---------------------------------------------------------------------------
struct WFArgs {
    const float* Wm[2]; const float* Wo[2]; const float* We[2];
    u32* Wfa[2]; u32* Wfb[2];
};
__global__ __launch_bounds__(256) void wfuse_kernel(WFArgs a)
{
    const int tg = blockIdx.x * 256 + threadIdx.x;   // 0..98303
    const int p = tg / 49152;
    const int rem = tg % 49152;
    if (rem < 16384) {
        const int o = rem >> 7, k = rem & 127;
        const float* Wm = a.Wm[p];
        const float* Wo = a.Wo[p];
        float acc = 0.f;
        #pragma unroll 4
        for (int c = 0; c < 128; ++c)
            acc += Wm[o * 256 + c] * Wo[c * 128 + k];
        a.Wfa[p][o * 128 + k] = splitpack(acc);
    } else {
        const int r2 = rem - 16384;
        const int o = r2 >> 8, k = r2 & 255;
        const float* Wm = a.Wm[p];
        const float* We = a.We[p];
        float acc = 0.f;
        #pragma unroll 4
        for (int c = 0; c < 128; ++c)
            acc += Wm[o * 256 + 128 + c] * We[c * 256 + k];
        a.Wfb[p][o * 256 + k] = splitpack(acc);
    }
}

// ---------------------------------------------------------------------------
// bf16 MFMA GEMM core (hi-only). XBF: X input is bf16 ush (else split u32).
// XMODE 0: X[(b*K + c)*M + m]   XMODE 1: X[((b*N+n)*3+t)*K + c], m = t*N+n
// OMODE 0: fp32(+Z)  3: bf16 Ybf  4: qkv fragment-major
// ---------------------------------------------------------------------------
template <int XMODE, int OMODE, bool XBF>
__device__ __forceinline__ void gemm_tile(
    const u32* __restrict__ Wsp, int wstride,
    const void* __restrict__ Xv, int K,
    const float* __restrict__ Z, float* __restrict__ Y,
    ush* __restrict__ Ybf, ush* __restrict__ Ytr,
    int b, int m0, int o0loc, int oglob, int Ostr,
    ush (*Wh)[64], ush (*Xh)[64])
{
    const int M = 3 * N_;
    const int tid = threadIdx.x;
    const int lane = tid & 63, wv = tid >> 6;
    const int col = lane & 15, grp = lane >> 4;
    const int wo = wv >> 1, wm = wv & 1;

    f32x4 acc[2][2];
    #pragma unroll
    for (int i = 0; i < 2; ++i)
        #pragma unroll
        for (int j = 0; j < 2; ++j) { f32x4 z = {0.f,0.f,0.f,0.f}; acc[i][j] = z; }

    for (int kk = 0; kk < K; kk += 64) {
        {
            const int o = tid >> 2, kg = tid & 3;
            const u32* src = Wsp + (size_t)(o0loc + o) * wstride + kk + kg * 16;
            u32 buf[16];
            #pragma unroll
            for (int j = 0; j < 4; ++j) *(uint4*)&buf[j * 4] = *(const uint4*)(src + j * 4);
            const int s0 = ((kg * 2)     ^ (o & 7)) << 3;
            const int s1 = ((kg * 2 + 1) ^ (o & 7)) << 3;
            short8v h0, h1; unpack_hi(buf, h0, h1);
            *(short8v*)&Wh[o][s0] = h0; *(short8v*)&Wh[o][s1] = h1;
        }
        if (XMODE == 0) {
            const int m = lane, kq = wv;
            const int s0 = ((kq * 2)     ^ (m & 7)) << 3;
            const int s1 = ((kq * 2 + 1) ^ (m & 7)) << 3;
            if (XBF) {
                const ush* src = (const ush*)Xv + ((size_t)b * K + kk + kq * 16) * M + m0 + m;
                ush h[16];
                #pragma unroll
                for (int j = 0; j < 16; ++j) h[j] = src[(size_t)j * M];
                *(short8v*)&Xh[m][s0] = *(short8v*)&h[0];
                *(short8v*)&Xh[m][s1] = *(short8v*)&h[8];
            } else {
                const u32* src = (const u32*)Xv + ((size_t)b * K + kk + kq * 16) * M + m0 + m;
                u32 buf[16];
                #pragma unroll
                for (int j = 0; j < 16; ++j) buf[j] = src[(size_t)j * M];
                short8v h0, h1; unpack_hi(buf, h0, h1);
                *(short8v*)&Xh[m][s0] = h0; *(short8v*)&Xh[m][s1] = h1;
            }
        } else {
            const int m = tid >> 2, kg = tid & 3;
            const int mg = m0 + m;
            const int n = mg & (N_ - 1), t = mg >> 11;
            const int s0 = ((kg * 2)     ^ (m & 7)) << 3;
            const int s1 = ((kg * 2 + 1) ^ (m & 7)) << 3;
            const ush* src = (const ush*)Xv + ((size_t)(b * N_ + n) * 3 + t) * K + kk + kg * 16;
            ush h[16];
            *(uint4*)&h[0] = *(const uint4*)(src);
            *(uint4*)&h[8] = *(const uint4*)(src + 8);
            *(short8v*)&Xh[m][s0] = *(short8v*)&h[0];
            *(short8v*)&Xh[m][s1] = *(short8v*)&h[8];
        }
        __syncthreads();
        #pragma unroll
        for (int kc = 0; kc < 2; ++kc) {
            const int sk = ((kc * 4 + grp) ^ (col & 7)) << 3;
            short8v ah0 = *(const short8v*)&Wh[wo * 32 + col][sk];
            short8v ah1 = *(const short8v*)&Wh[wo * 32 + 16 + col][sk];
            short8v xh0 = *(const short8v*)&Xh[wm * 32 + col][sk];
            short8v xh1 = *(const short8v*)&Xh[wm * 32 + 16 + col][sk];
            acc[0][0] = __builtin_amdgcn_mfma_f32_16x16x32_bf16(ah0, xh0, acc[0][0], 0, 0, 0);
            acc[0][1] = __builtin_amdgcn_mfma_f32_16x16x32_bf16(ah0, xh1, acc[0][1], 0, 0, 0);
            acc[1][0] = __builtin_amdgcn_mfma_f32_16x16x32_bf16(ah1, xh0, acc[1][0], 0, 0, 0);
            acc[1][1] = __builtin_amdgcn_mfma_f32_16x16x32_bf16(ah1, xh1, acc[1][1], 0, 0, 0);
        }
        __syncthreads();
    }
    #pragma unroll
    for (int of = 0; of < 2; ++of) {
        #pragma unroll
        for (int r = 0; r < 4; ++r) {
            const int o = oglob + wo * 32 + of * 16 + grp * 4 + r;
            #pragma unroll
            for (int mf = 0; mf < 2; ++mf) {
                const int mloc = m0 + wm * 32 + mf * 16 + col;
                const size_t idx = ((size_t)b * Ostr + o) * M + mloc;
                float v = acc[of][mf][r];
                if (OMODE == 0) {
                    if (Z) v += Z[idx];
                    Y[idx] = v;
                }
                if (OMODE == 3) Ybf[idx] = f2bf(v);
                if (OMODE == 4) {
                    ush bv = f2bf(v);
                    const int t = mloc >> 11, n = mloc & (N_ - 1);
                    const int h = (o >> 4) & 7, cl = o & 15;
                    const int d = cl * 3 + t;
                    if (o >= 256) {
                        const int kt = n >> 6, hh = (n >> 5) & 1, db = d >> 4;
                        const size_t idx2 = ((size_t)(b * 8 + h) * 192
                                           + (kt * 2 + hh) * 3 + db) * 512
                                          + (((n >> 3) & 3) * 16 + (d & 15)) * 8 + (n & 7);
                        Ybf[idx2] = bv;
                    } else {
                        const int isK = (o >> 7) & 1;
                        const int qg = n >> 4, half = d >> 5;
                        const size_t idx2 = ((size_t)(isK * 16 + b * 8 + h) * 256
                                           + qg * 2 + half) * 512
                                          + (((d >> 3) & 3) * 16 + (n & 15)) * 8 + (d & 7);
                        Ytr[idx2] = bv;
                    }
                }
            }
        }
    }
}

template <int XMODE, int OMODE, bool XBF>
__global__ __launch_bounds__(256) void gemm_kernel2(
    const u32* __restrict__ Wsp, int wstride,
    const void* __restrict__ Xv,
    const float* __restrict__ Z,
    float* __restrict__ Y, ush* __restrict__ Ybf,
    int Ostr, int obase, int K)
{
    __shared__ __align__(16) ush Wh[64][64];
    __shared__ __align__(16) ush Xh[64][64];
    gemm_tile<XMODE, OMODE, XBF>(Wsp, wstride, Xv, K, Z, Y, Ybf, nullptr,
                            blockIdx.z, blockIdx.x * 64,
                            blockIdx.y * 64, obase + blockIdx.y * 64, Ostr,
                            Wh, Xh);
}

// ---------------------------------------------------------------------------
// fused output mix: Y = Wfa*ao (K=128, XMODE0) + Wfb*gbuf (K=256, XMODE1) + Z
// ---------------------------------------------------------------------------
__global__ __launch_bounds__(256) void wm2_kernel(
    const u32* __restrict__ Wfa, const u32* __restrict__ Wfb,
    const ush* __restrict__ ao, const ush* __restrict__ gb,
    const float* __restrict__ Z, float* __restrict__ Y)
{
    __shared__ __align__(16) ush Wh[64][64];
    __shared__ __align__(16) ush Xh[64][64];
    const int M = 3 * N_;
    const int b = blockIdx.z;
    const int m0 = blockIdx.x * 64;
    const int o0 = blockIdx.y * 64;
    const int tid = threadIdx.x;
    const int lane = tid & 63, wv = tid >> 6;
    const int col = lane & 15, grp = lane >> 4;
    const int wo = wv >> 1, wm = wv & 1;

    f32x4 acc[2][2];
    #pragma unroll
    for (int i = 0; i < 2; ++i)
        #pragma unroll
        for (int j = 0; j < 2; ++j) { f32x4 z = {0.f,0.f,0.f,0.f}; acc[i][j] = z; }

    for (int kk = 0; kk < 128; kk += 64) {
        {
            const int o = tid >> 2, kg = tid & 3;
            const u32* src = Wfa + (size_t)(o0 + o) * 128 + kk + kg * 16;
            u32 buf[16];
            #pragma unroll
            for (int j = 0; j < 4; ++j) *(uint4*)&buf[j * 4] = *(const uint4*)(src + j * 4);
            const int s0 = ((kg * 2)     ^ (o & 7)) << 3;
            const int s1 = ((kg * 2 + 1) ^ (o & 7)) << 3;
            short8v h0, h1; unpack_hi(buf, h0, h1);
            *(short8v*)&Wh[o][s0] = h0; *(short8v*)&Wh[o][s1] = h1;
        }
        {
            const int m = lane, kq = wv;
            const int s0 = ((kq * 2)     ^ (m & 7)) << 3;
            const int s1 = ((kq * 2 + 1) ^ (m & 7)) << 3;
            const ush* src = ao + ((size_t)b * 128 + kk + kq * 16) * M + m0 + m;
            ush h[16];
            #pragma unroll
            for (int j = 0; j < 16; ++j) h[j] = src[(size_t)j * M];
            *(short8v*)&Xh[m][s0] = *(short8v*)&h[0];
            *(short8v*)&Xh[m][s1] = *(short8v*)&h[8];
        }
        __syncthreads();
        #pragma unroll
        for (int kc = 0; kc < 2; ++kc) {
            const int sk = ((kc * 4 + grp) ^ (col & 7)) << 3;
            short8v ah0 = *(const short8v*)&Wh[wo * 32 + col][sk];
            short8v ah1 = *(const short8v*)&Wh[wo * 32 + 16 + col][sk];
            short8v xh0 = *(const short8v*)&Xh[wm * 32 + col][sk];
            short8v xh1 = *(const short8v*)&Xh[wm * 32 + 16 + col][sk];
            acc[0][0] = __builtin_amdgcn_mfma_f32_16x16x32_bf16(ah0, xh0, acc[0][0], 0, 0, 0);
            acc[0][1] = __builtin_amdgcn_mfma_f32_16x16x32_bf16(ah0, xh1, acc[0][1], 0, 0, 0);
            acc[1][0] = __builtin_amdgcn_mfma_f32_16x16x32_bf16(ah1, xh0, acc[1][0], 0, 0, 0);
            acc[1][1] = __builtin_amdgcn_mfma_f32_16x16x32_bf16(ah1, xh1, acc[1][1], 0, 0, 0);
        }
        __syncthreads();
    }

    for (int kk = 0; kk < 256; kk += 64) {
        {
            const int o = tid >> 2, kg = tid & 3;
            const u32* src = Wfb + (size_t)(o0 + o) * 256 + kk + kg * 16;
            u32 buf[16];
            #pragma unroll
            for (int j = 0; j < 4; ++j) *(uint4*)&buf[j * 4] = *(const uint4*)(src + j * 4);
            const int s0 = ((kg * 2)     ^ (o & 7)) << 3;
            const int s1 = ((kg * 2 + 1) ^ (o & 7)) << 3;
            short8v h0, h1; unpack_hi(buf, h0, h1);
            *(short8v*)&Wh[o][s0] = h0; *(short8v*)&Wh[o][s1] = h1;
        }
        {
            const int m = tid >> 2, kg = tid & 3;
            const int mg = m0 + m;
            const int n = mg & (N_ - 1), t = mg >> 11;
            const int s0 = ((kg * 2)     ^ (m & 7)) << 3;
            const int s1 = ((kg * 2 + 1) ^ (m & 7)) << 3;
            const ush* src = gb + ((size_t)(b * N_ + n) * 3 + t) * 256 + kk + kg * 16;
            ush h[16];
            *(uint4*)&h[0] = *(const uint4*)(src);
            *(uint4*)&h[8] = *(const uint4*)(src + 8);
            *(short8v*)&Xh[m][s0] = *(short8v*)&h[0];
            *(short8v*)&Xh[m][s1] = *(short8v*)&h[8];
        }
        __syncthreads();
        #pragma unroll
        for (int kc = 0; kc < 2; ++kc) {
            const int sk = ((kc * 4 + grp) ^ (col & 7)) << 3;
            short8v ah0 = *(const short8v*)&Wh[wo * 32 + col][sk];
            short8v ah1 = *(const short8v*)&Wh[wo * 32 + 16 + col][sk];
            short8v xh0 = *(const short8v*)&Xh[wm * 32 + col][sk];
            short8v xh1 = *(const short8v*)&Xh[wm * 32 + 16 + col][sk];
            acc[0][0] = __builtin_amdgcn_mfma_f32_16x16x32_bf16(ah0, xh0, acc[0][0], 0, 0, 0);
            acc[0][1] = __builtin_amdgcn_mfma_f32_16x16x32_bf16(ah0, xh1, acc[0][1], 0, 0, 0);
            acc[1][0] = __builtin_amdgcn_mfma_f32_16x16x32_bf16(ah1, xh0, acc[1][0], 0, 0, 0);
            acc[1][1] = __builtin_amdgcn_mfma_f32_16x16x32_bf16(ah1, xh1, acc[1][1], 0, 0, 0);
        }
        __syncthreads();
    }

    #pragma unroll
    for (int of = 0; of < 2; ++of) {
        #pragma unroll
        for (int r = 0; r < 4; ++r) {
            const int o = o0 + wo * 32 + of * 16 + grp * 4 + r;
            #pragma unroll
            for (int mf = 0; mf < 2; ++mf) {
                const int mloc = m0 + wm * 32 + mf * 16 + col;
                const size_t idx = ((size_t)b * 128 + o) * M + mloc;
                Y[idx] = acc[of][mf][r] + Z[idx];
            }
        }
    }
}

struct QKVArgs {
    const u32* W0; const u32* W1; const u32* W2;
    const ush* X0; const ush* X1; const ush* X2;
};

// fused: qkv projections (blocks 0..1151) + bf16 transpose(s) (blocks 1152..)
__global__ __launch_bounds__(256) void qkv_tr_kernel(QKVArgs A,
        ush* __restrict__ vfm, ush* __restrict__ qktb,
        const ush* __restrict__ ts0, ush* __restrict__ td0,
        const ush* __restrict__ ts1, ush* __restrict__ td1)
{
    __shared__ __align__(16) ush Wh[64][64];
    __shared__ __align__(16) ush Xh[64][64];
    __shared__ ush ttile[32][34];
    const int bx = blockIdx.x;
    if (bx < 1152) {
        const int z = bx / 576, rem = bx % 576;
        const int y = rem / 96, x = rem % 96;
        const int wi = y >> 1;
        const u32* W = wi == 0 ? A.W0 : (wi == 1 ? A.W1 : A.W2);
        const ush* X = wi == 0 ? A.X0 : (wi == 1 ? A.X1 : A.X2);
        gemm_tile<0, 4, true>(W, 128, X, 128, nullptr, nullptr, vfm, qktb,
                        z, x * 64, (y & 1) * 64, y * 64, 384,
                        Wh, Xh);
    } else {
        int i = bx - 1152;
        const int which = i / 1536; i %= 1536;
        const ush* src = which ? ts1 : ts0;
        ush* dst = which ? td1 : td0;
        const int x = i & 63, y = (i >> 6) & 3, z = i >> 8;
        const int b = z / 3, t = z % 3;
        const int n0 = x * 32, c0 = y * 32;
        const int tx = threadIdx.x & 31, ty = threadIdx.x >> 5;
        #pragma unroll
        for (int p = 0; p < 4; ++p) {
            int c = c0 + ty + p * 8;
            ttile[ty + p * 8][tx] = src[((size_t)(b * C_ + c) * 3 + t) * N_ + n0 + tx];
        }
        __syncthreads();
        #pragma unroll
        for (int p = 0; p < 4; ++p) {
            int n = n0 + ty + p * 8;
            dst[((size_t)(b * N_ + n) * 3 + t) * C_ + c0 + tx] = ttile[tx][ty + p * 8];
        }
    }
}

// ---------------------------------------------------------------------------
// barrier-free split-K flash attention, XCD-chunked 1D grid (2048 blocks).
// ---------------------------------------------------------------------------
__global__ __launch_bounds__(256) void attn_mfma_kernel(
    const ush* __restrict__ vfm, const ush* __restrict__ qktb,
    ush* __restrict__ pacc, float* __restrict__ pml)
{
    __shared__ __align__(16) ush Pl[4][2][16][64];   // 16 KB

    const int flat = blockIdx.x;
    const int xcd  = flat & 7;
    const int slot = flat >> 3;
    const int gid  = xcd * 4 + (slot >> 6);
    const int q32  = slot & 63;
    const int bh   = gid & 15;
    const int zz   = gid >> 4;

    const int tid = threadIdx.x;
    const int lane = tid & 63, wv = tid >> 6;
    const int col = lane & 15, grp = lane >> 4;
    const int c7  = col & 7;
    const int kz  = zz * 4 + wv;
    const int ks0 = kz * (N_ / KSPLIT);

    const ush* Qpl = qktb + (size_t)bh * 131072;
    const ush* Kpl = qktb + (size_t)(16 + bh) * 131072;
    const ush* Vpl = vfm  + (size_t)bh * 98304;

    short8v qf[2][2];
    #pragma unroll
    for (int qi = 0; qi < 2; ++qi) {
        const int qg = q32 * 2 + qi;
        qf[qi][0] = *(const short8v*)(Qpl + ((size_t)qg * 2 + 0) * 512 + lane * 8);
        qf[qi][1] = *(const short8v*)(Qpl + ((size_t)qg * 2 + 1) * 512 + lane * 8);
    }

    f32x4 acc[2][3];
    #pragma unroll
    for (int qi = 0; qi < 2; ++qi)
        #pragma unroll
        for (int db = 0; db < 3; ++db) { f32x4 z = {0.f,0.f,0.f,0.f}; acc[qi][db] = z; }
    float m_i[2] = {0.f, 0.f};
    float l_l[2] = {0.f, 0.f};

    const int NT = (N_ / KSPLIT) / 64;
    for (int mt = 0; mt < NT; ++mt) {
        const int m0 = ks0 + mt * 64;

        short8v ka[4][2];
        #pragma unroll
        for (int kb = 0; kb < 4; ++kb) {
            const size_t kg = (m0 >> 4) + kb;
            ka[kb][0] = *(const short8v*)(Kpl + (kg * 2 + 0) * 512 + lane * 8);
            ka[kb][1] = *(const short8v*)(Kpl + (kg * 2 + 1) * 512 + lane * 8);
        }
        const int kt = m0 >> 6;
        short8v vf[2][3];
        #pragma unroll
        for (int hh = 0; hh < 2; ++hh)
            #pragma unroll
            for (int db = 0; db < 3; ++db)
                vf[hh][db] = *(const short8v*)(Vpl + (size_t)((kt * 2 + hh) * 3 + db) * 512 + lane * 8);

        f32x4 sf[2][4];
        __builtin_amdgcn_s_setprio(1);
        #pragma unroll
        for (int qi = 0; qi < 2; ++qi)
            #pragma unroll
            for (int kb = 0; kb < 4; ++kb) {
                f32x4 z = {0.f, 0.f, 0.f, 0.f};
                z = __builtin_amdgcn_mfma_f32_16x16x32_bf16(ka[kb][0], qf[qi][0], z, 0, 0, 0);
                z = __builtin_amdgcn_mfma_f32_16x16x32_bf16(ka[kb][1], qf[qi][1], z, 0, 0, 0);
                sf[qi][kb] = z;
            }
        __builtin_amdgcn_s_setprio(0);

        #pragma unroll
        for (int qi = 0; qi < 2; ++qi) {
            float psum = 0.f;
            #pragma unroll
            for (int kb = 0; kb < 4; ++kb) {
                float e0 = __expf(sf[qi][kb][0] - m_i[qi]);
                float e1 = __expf(sf[qi][kb][1] - m_i[qi]);
                float e2 = __expf(sf[qi][kb][2] - m_i[qi]);
                float e3 = __expf(sf[qi][kb][3] - m_i[qi]);
                psum += (e0 + e1) + (e2 + e3);
                u32 r0, r1;
                asm("v_cvt_pk_bf16_f32 %0, %1, %2" : "=v"(r0) : "v"(e0), "v"(e1));
                asm("v_cvt_pk_bf16_f32 %0, %1, %2" : "=v"(r1) : "v"(e2), "v"(e3));
                const int un = (4 * kb + grp) ^ (c7 << 1);
                uint2 pk2; pk2.x = r0; pk2.y = r1;
                *(uint2*)&Pl[wv][qi][col][un << 2] = pk2;
            }
            l_l[qi] += psum;
        }

        __builtin_amdgcn_s_setprio(1);
        #pragma unroll
        for (int qi = 0; qi < 2; ++qi)
            #pragma unroll
            for (int hh = 0; hh < 2; ++hh) {
                const int ur = (8 * hh + 2 * grp) ^ (c7 << 1);
                short8v pf = *(const short8v*)&Pl[wv][qi][col][ur << 2];
                #pragma unroll
                for (int db = 0; db < 3; ++db)
                    acc[qi][db] = __builtin_amdgcn_mfma_f32_16x16x32_bf16(vf[hh][db], pf, acc[qi][db], 0, 0, 0);
            }
        __builtin_amdgcn_s_setprio(0);

        #pragma unroll
        for (int qi = 0; qi < 2; ++qi) {
            float pmax = -1e30f;
            #pragma unroll
            for (int kb = 0; kb < 4; ++kb)
                #pragma unroll
                for (int r = 0; r < 4; ++r) pmax = fmaxf(pmax, sf[qi][kb][r]);
            pmax = fmaxf(pmax, __shfl_xor(pmax, 16, 64));
            pmax = fmaxf(pmax, __shfl_xor(pmax, 32, 64));
            if (!__all(pmax - m_i[qi] <= 8.0f)) {
                float mnew = fmaxf(m_i[qi], pmax);
                float sc = __expf(m_i[qi] - mnew);
                l_l[qi] *= sc;
                #pragma unroll
                for (int db = 0; db < 3; ++db) {
                    acc[qi][db][0] *= sc; acc[qi][db][1] *= sc;
                    acc[qi][db][2] *= sc; acc[qi][db][3] *= sc;
                }
                m_i[qi] = mnew;
            }
        }
    }

    const int ntile = q32 >> 1, qh = q32 & 1;
    const size_t pb = (size_t)(kz * 16 + bh) * 32 + ntile;
    #pragma unroll
    for (int qi = 0; qi < 2; ++qi) {
        float l = l_l[qi];
        l += __shfl_xor(l, 16, 64);
        l += __shfl_xor(l, 32, 64);
        const int q = qh * 32 + qi * 16 + col;
        #pragma unroll
        for (int db = 0; db < 3; ++db)
            #pragma unroll
            for (int r = 0; r < 4; ++r) {
                int d = db * 16 + grp * 4 + r;
                pacc[pb * 3072 + d * 64 + q] = f2bf(acc[qi][db][r]);
            }
        if (grp == 0) {
            pml[pb * 128 + q]      = m_i[qi];
            pml[pb * 128 + 64 + q] = l;
        }
    }
}

// ---------------------------------------------------------------------------
// fused: split-K reduce (blocks 0..511) + graph attention (blocks 512..4607)
// independent work; neither is XCD-chunked so no locality prerequisite broken.
// ---------------------------------------------------------------------------
__global__ __launch_bounds__(256) void reduce_graph_kernel(
    const ush* __restrict__ pacc, const float* __restrict__ pml,
    ush* __restrict__ ao,
    const ush* __restrict__ tq, const ush* __restrict__ tv,
    const int* __restrict__ idx, ush* __restrict__ gbuf)
{
    __shared__ float centerf[384];
    __shared__ ush nbr_l[16][384];
    __shared__ float sd[16];
    __shared__ int nbr_i[16];
    const int tid = threadIdx.x;

    if (blockIdx.x < 512) {
        // ============ split-K reduce ============
        const int nt = blockIdx.x & 31, bh = blockIdx.x >> 5;
        const int b = bh >> 3, h = bh & 7;
        const int q = tid & 63, dg = tid >> 6;

        size_t pb[KSPLIT];
        float m[KSPLIT], l[KSPLIT];
        #pragma unroll
        for (int kz = 0; kz < KSPLIT; ++kz) {
            pb[kz] = (size_t)(kz * 16 + bh) * 32 + nt;
            m[kz] = pml[pb[kz] * 128 + q];
            l[kz] = pml[pb[kz] * 128 + 64 + q];
        }
        float ms = -1e30f;
        #pragma unroll
        for (int kz = 0; kz < KSPLIT; ++kz) ms = fmaxf(ms, m[kz]);
        float w[KSPLIT], ls = 0.f;
        #pragma unroll
        for (int kz = 0; kz < KSPLIT; ++kz) { w[kz] = __expf(m[kz] - ms); ls += l[kz] * w[kz]; }
        const float inv = 1.f / ls;

        const size_t hb = ((size_t)(b * C_ + h * 16)) * 3 * N_;
        #pragma unroll
        for (int j = 0; j < 12; ++j) {
            int d = dg * 12 + j;
            float o = 0.f;
            #pragma unroll
            for (int kz = 0; kz < KSPLIT; ++kz)
                o += bf2f(pacc[pb[kz] * 3072 + d * 64 + q]) * w[kz];
            ao[hb + (size_t)d * N_ + nt * 64 + q] = f2bf(o * inv);
        }
    } else {
        // ============ graph attention ============
        const int j = blockIdx.x - 512;
        const int b = j >> 11, n = j & 2047;
        const ush* qrow = tq + (size_t)(b * N_ + n) * 384;
        for (int e = tid; e < 384; e += 256) centerf[e] = bf2f(qrow[e]);
        if (tid < 16) nbr_i[tid] = idx[(size_t)(b * N_ + n) * 16 + tid];
        __syncthreads();

        const int lane = tid & 63, wv = tid >> 6;
        for (int kk = 0; kk < 4; ++kk) {
            int k = wv * 4 + kk;
            const u32* vrow = (const u32*)(tv + ((size_t)b * N_ + nbr_i[k]) * 384);
            float p = 0.f;
            #pragma unroll
            for (int jj = 0; jj < 3; ++jj) {
                int e2 = lane + jj * 64;
                u32 v2 = vrow[e2];
                ((u32*)nbr_l[k])[e2] = v2;
                p += centerf[e2 * 2]     * bf2f((ush)(v2 & 0xffff))
                   + centerf[e2 * 2 + 1] * bf2f((ush)(v2 >> 16));
            }
            #pragma unroll
            for (int off = 32; off; off >>= 1) p += __shfl_down(p, off, 64);
            if (lane == 0) sd[k] = p * 0.05103103630798288f;
        }
        __syncthreads();

        float mx = -1e30f;
        #pragma unroll
        for (int k = 0; k < 16; ++k) mx = fmaxf(mx, sd[k]);
        float a[16]; float ssum = 0.f;
        #pragma unroll
        for (int k = 0; k < 16; ++k) { a[k] = __expf(sd[k] - mx); ssum += a[k]; }
        float inv = 1.f / ssum;

        for (int e = tid; e < 384; e += 256) {
            float accv = 0.f;
            #pragma unroll
            for (int k = 0; k < 16; ++k)
                accv += a[k] * bf2f(nbr_l[k][e]);
            accv *= inv;
            float ce = centerf[e];
            int t = e >> 7, c = e & 127;
            size_t gb = ((size_t)(b * N_ + n) * 3 + t) * 256;
            gbuf[gb + c]       = f2bf(accv - ce);
            gbuf[gb + 128 + c] = f2bf(ce);
        }
    }
}

// ---------------------------------------------------------------------------
// vn_leaky: bf16 x,d in -> bf16 out
// ---------------------------------------------------------------------------
__global__ __launch_bounds__(256) void leaky_kernel(const ush* __restrict__ x,
                                                    const ush* __restrict__ d,
                                                    ush* __restrict__ y)
{
    size_t p = (size_t)blockIdx.x * 256 + threadIdx.x;
    size_t bh = p / N_, n = p % N_;
    size_t base = bh * 3 * N_ + n;
    float x0 = bf2f(x[base]), x1 = bf2f(x[base + N_]), x2 = bf2f(x[base + 2 * N_]);
    float d0 = bf2f(d[base]), d1 = bf2f(d[base + N_]), d2 = bf2f(d[base + 2 * N_]);
    float dot = x0 * d0 + x1 * d1 + x2 * d2;
    float dsq = d0 * d0 + d1 * d1 + d2 * d2;
    float f = dot / (dsq + EPS_);
    bool pos = dot >= 0.f;
    float y0 = pos ? x0 : x0 - f * d0;
    float y1 = pos ? x1 : x1 - f * d1;
    float y2 = pos ? x2 : x2 - f * d2;
    y[base]          = f2bf(NS_ * x0 + (1.f - NS_) * y0);
    y[base + N_]     = f2bf(NS_ * x1 + (1.f - NS_) * y1);
    y[base + 2 * N_] = f2bf(NS_ * x2 + (1.f - NS_) * y2);
}

// ---------------------------------------------------------------------------
extern "C" void kernel_launch(void* const* d_in, const int* in_sizes, int n_in,
                              void* d_out, int out_size, void* d_ws, size_t ws_size,
                              hipStream_t stream)
{
    const float* q_in = (const float*)d_in[0];
    const float* v_in = (const float*)d_in[1];
    const int*   idx_s = (const int*)d_in[4];
    const int*   idx_c = (const int*)d_in[5];
    const float* g1 = (const float*)d_in[6];
    const float* b1 = (const float*)d_in[7];
    const float* g2 = (const float*)d_in[8];
    const float* b2 = (const float*)d_in[9];
    const float* gq = (const float*)d_in[10];
    const float* bq = (const float*)d_in[11];
    const float* gv = (const float*)d_in[12];
    const float* bv = (const float*)d_in[13];
    float* out = (float*)d_out;
    float* ws  = (float*)d_ws;

    const size_t S1 = (size_t)B_ * C_ * 3 * N_; // 1572864 elems
    ush*   gbuf_b= (ush*)(ws);         // 0 (6.3MB; live reduce_graph -> wm2)
    ush*   nx_b  = (ush*)(ws + 2*S1);  // 2 (half)
    ush*   nv_b  = (ush*)(ws + 3*S1);  // 3 (half)
    ush*   vfm   = (ush*)(ws + 4*S1);  // 4: 3MB
    ush*   qktb  = (ush*)(ws + 5*S1) + S1;  // 5.5-6.84: 8.4MB
    ush*   ao_b  = (ush*)(ws + 7*S1);  // 7 (half)
    float* qa    = ws + 12*S1;         // 12
    float* qb    = ws + 13*S1;         // 13
    ush*   t1_b  = (ush*)(ws + 14*S1); // 14 (half)
    ush*   t2_b  = (ush*)(ws + 15*S1); // 15 (half)
    u32*   wsp   = (u32*)(ws + 16*S1); // 16+
    // split-K attention partials (attn->reduce window only)
    ush*   pacc  = (ush*)(ws + 8*S1);  // 8-11: 25.2MB
    float* pml   = (float*)(ws + 2*S1);// 2 (attn after qkv consumed nx_b)
    // phase C aliases (all bf16 now):
    ush*   hd_b  = (ush*)(ws + 1*S1);  // 1-2 as ush (12.6MB; nv_b/pml dead)
    ush*   h1_b  = (ush*)(ws + 14*S1); // 14-15 (t1/t2 dead)
    ush*   h1_b2 = (ush*)(ws + 8*S1);  // 8-9 (pacc dead)

    // weight planes: 9 split-converted + 4 fused (Wfa/Wfb per phase)
    const int wn[9]   = {16384,16384,16384, 16384,16384,16384, 65536,262144,65536};
    const int wsrc[9] = {14,15,16, 20,21,22, 26,27,28};
    u32* wd[9];
    {
        int off = 0;
        for (int i = 0; i < 9; ++i) { wd[i] = wsp + off; off += wn[i]; }
    }
    u32 *Wq_s = wd[0], *Wk_s = wd[1], *Wv_s = wd[2];
    u32 *Wq_c = wd[3], *Wk_c = wd[4], *Wv_c = wd[5];
    u32 *W1 = wd[6], *Dact = wd[7], *W2 = wd[8];
    u32* Wfa_s = wsp + 491520;
    u32* Wfb_s = Wfa_s + 16384;
    u32* Wfa_c = Wfb_s + 32768;
    u32* Wfb_c = Wfa_c + 16384;

    // zero qktb once per launch (d=48..63 pad slots must be 0)
    hipMemsetAsync(qktb, 0, (size_t)32 * 131072 * sizeof(ush), stream);

    {
        WCArgs a;
        for (int i = 0; i < 9; ++i) {
            a.src[i] = (const float*)d_in[wsrc[i]];
            a.dst[i] = wd[i];
            a.n[i]   = wn[i];
            a.scale[i] = 1.f;
        }
        a.scale[0] = 0.14433756729740643f;  // Wq_s: fold 1/sqrt(48)
        a.scale[3] = 0.14433756729740643f;  // Wq_c
        wconv_kernel<<<dim3(1024, 9), 256, 0, stream>>>(a);
    }
    {
        WFArgs a;
        a.Wm[0] = (const float*)d_in[19]; a.Wo[0] = (const float*)d_in[17]; a.We[0] = (const float*)d_in[18];
        a.Wm[1] = (const float*)d_in[25]; a.Wo[1] = (const float*)d_in[23]; a.We[1] = (const float*)d_in[24];
        a.Wfa[0] = Wfa_s; a.Wfb[0] = Wfb_s;
        a.Wfa[1] = Wfa_c; a.Wfb[1] = Wfb_c;
        wfuse_kernel<<<dim3(384), 256, 0, stream>>>(a);
    }

    dim3 gwm(96, 2, B_);
    dim3 gg512(96, 8, B_);

    // ---- Phase A: self attention block ----
    {
        LNArgs la{};
        la.x[0] = q_in; la.g[0] = g1; la.bt[0] = b1; la.ysp[0] = nx_b;
        ln_kernel<<<dim3(64, B_, 1), 256, 0, stream>>>(la);
    }
    {
        QKVArgs A{Wq_s, Wk_s, Wv_s, nx_b, nx_b, nx_b};
        qkv_tr_kernel<<<dim3(1152 + 1536), 256, 0, stream>>>(A, vfm, qktb, nx_b, t1_b, nullptr, nullptr);
    }
    attn_mfma_kernel<<<dim3(2048), 256, 0, stream>>>(vfm, qktb, pacc, pml);
    reduce_graph_kernel<<<dim3(512 + 4096), 256, 0, stream>>>(pacc, pml, ao_b, t1_b, t1_b, idx_s, gbuf_b);
    wm2_kernel<<<gwm, 256, 0, stream>>>(Wfa_s, Wfb_s, ao_b, gbuf_b, q_in, qa);

    // ---- Phase B: cross attention block ----
    {
        LNArgs la{};
        la.x[0] = qa;   la.g[0] = gq; la.bt[0] = bq; la.ysp[0] = nx_b;
        la.x[1] = v_in; la.g[1] = gv; la.bt[1] = bv; la.ysp[1] = nv_b;
        ln_kernel<<<dim3(64, B_, 2), 256, 0, stream>>>(la);
    }
    {
        QKVArgs A{Wq_c, Wk_c, Wv_c, nx_b, nv_b, nv_b};
        qkv_tr_kernel<<<dim3(1152 + 3072), 256, 0, stream>>>(A, vfm, qktb, nx_b, t1_b, nv_b, t2_b);
    }
    attn_mfma_kernel<<<dim3(2048), 256, 0, stream>>>(vfm, qktb, pacc, pml);
    reduce_graph_kernel<<<dim3(512 + 4096), 256, 0, stream>>>(pacc, pml, ao_b, t1_b, t2_b, idx_c, gbuf_b);
    wm2_kernel<<<gwm, 256, 0, stream>>>(Wfa_c, Wfb_c, ao_b, gbuf_b, qa, qb);

    // ---- Phase C: vector MLP (all-bf16 intermediates) ----
    {
        LNArgs la{};
        la.x[0] = qb; la.g[0] = g2; la.bt[0] = b2; la.ysp[0] = nx_b;
        ln_kernel<<<dim3(64, B_, 1), 256, 0, stream>>>(la);
    }
    gemm_kernel2<0,3,true><<<gg512, 256, 0, stream>>>(W1, 128, nx_b, nullptr, nullptr, h1_b, 512, 0, 128);
    gemm_kernel2<0,3,true><<<gg512, 256, 0, stream>>>(Dact, 512, h1_b, nullptr, nullptr, hd_b, 512, 0, 512);
    leaky_kernel<<<dim3((B_ * HID_ * N_) / 256), 256, 0, stream>>>(h1_b, hd_b, h1_b2);
    gemm_kernel2<0,0,true><<<dim3(96, 2, B_), 256, 0, stream>>>(W2, 512, h1_b2, qb, out, nullptr, 128, 0, 512);
}

// Round 17
// 231.465 us; speedup vs baseline: 1.4011x; 1.0334x over previous
//
#include <hip/hip_runtime.h>
#include <math.h>

#define B_    2
#define C_    128
#define N_    2048
#define HID_  512
#define HEADS_ 8
#define EPS_  1e-6f
#define NS_   0.2f
#define KSPLIT 4

typedef __attribute__((ext_vector_type(8))) short short8v;  // 8 bf16
typedef __attribute__((ext_vector_type(4))) float f32x4;
typedef unsigned short ush;
typedef unsigned int u32;

__device__ inline ush f2bf(float f) {
    unsigned u = __float_as_uint(f);
    u += 0x7FFF + ((u >> 16) & 1);          // round-to-nearest-even
    return (ush)(u >> 16);
}
__device__ inline float bf2f(ush u) { return __uint_as_float((u32)u << 16); }

// pack float -> (hi bf16 << 16) | lo bf16
__device__ inline u32 splitpack(float x) {
    ush hi = f2bf(x);
    float hf = __uint_as_float((u32)hi << 16);
    ush lo = f2bf(x - hf);
    return ((u32)hi << 16) | (u32)lo;
}

__device__ inline void unpack_hi(const u32* buf, short8v& h0, short8v& h1) {
    ush h[16];
    #pragma unroll
    for (int j = 0; j < 16; ++j) h[j] = (ush)(buf[j] >> 16);
    h0 = *(short8v*)&h[0]; h1 = *(short8v*)&h[8];
}

// ---------------------------------------------------------------------------
// vec_layernorm, z-indexed multi-input: writes bf16 plane only
// ---------------------------------------------------------------------------
struct LNArgs {
    const float* x[2]; const float* g[2]; const float* bt[2]; ush* ysp[2];
};
__global__ __launch_bounds__(256) void ln_kernel(LNArgs a)
{
    __shared__ float norms[128][32];
    __shared__ float red1[8][32];
    __shared__ float red2[8][32];
    const int s = blockIdx.z;
    const float* x = a.x[s];
    const float* gma = a.g[s];
    const float* bta = a.bt[s];
    ush* ysp = a.ysp[s];

    const int b  = blockIdx.y;
    const int n0 = blockIdx.x * 32;
    const int nn = threadIdx.x & 31;
    const int cg = threadIdx.x >> 5;

    float s1 = 0.f, s2 = 0.f;
    for (int it = 0; it < 16; ++it) {
        int c = it * 8 + cg;
        size_t base = ((size_t)(b * C_ + c) * 3) * N_ + n0 + nn;
        float x0 = x[base], x1 = x[base + N_], x2 = x[base + 2 * N_];
        float nr = sqrtf(x0 * x0 + x1 * x1 + x2 * x2 + EPS_);
        norms[c][nn] = nr;
        s1 += nr; s2 += nr * nr;
    }
    red1[cg][nn] = s1; red2[cg][nn] = s2;
    __syncthreads();
    float S1 = 0.f, S2 = 0.f;
    #pragma unroll
    for (int g = 0; g < 8; ++g) { S1 += red1[g][nn]; S2 += red2[g][nn]; }
    float mu   = S1 * (1.f / 128.f);
    float var  = S2 * (1.f / 128.f) - mu * mu;
    float rstd = rsqrtf(var + EPS_);

    for (int it = 0; it < 16; ++it) {
        int c = it * 8 + cg;
        float nr = norms[c][nn];
        float ln = (nr - mu) * rstd * gma[c] + bta[c];
        float sc = ln / (nr + EPS_);
        size_t base = ((size_t)(b * C_ + c) * 3) * N_ + n0 + nn;
        ysp[base]          = f2bf(x[base] * sc);
        ysp[base + N_]     = f2bf(x[base + N_] * sc);
        ysp[base + 2 * N_] = f2bf(x[base + 2 * N_] * sc);
    }
}

// ---------------------------------------------------------------------------
// fused setup: 9 weight split-conversions (blocks 0..9215) + output-mix
// weight products Wfa/Wfb (blocks 9216..9599)
// ---------------------------------------------------------------------------
struct SetupArgs {
    const float* src[9]; u32* dst[9]; int n[9]; float scale[9];
    const float* Wm[2]; const float* Wo[2]; const float* We[2];
    u32* Wfa[2]; u32* Wfb[2];
};
__global__ __launch_bounds__(256) void setup_kernel(SetupArgs a)
{
    const int bx = blockIdx.x;
    if (bx < 9216) {
        const int w = bx / 1024;
        const int i = (bx % 1024) * 256 + threadIdx.x;
        if (i < a.n[w]) a.dst[w][i] = splitpack(a.src[w][i] * a.scale[w]);
    } else {
        const int tg = (bx - 9216) * 256 + threadIdx.x;   // 0..98303
        const int p = tg / 49152;
        const int rem = tg % 49152;
        if (rem < 16384) {
            const int o = rem >> 7, k = rem & 127;
            const float* Wm = a.Wm[p];
            const float* Wo = a.Wo[p];
            float acc = 0.f;
            #pragma unroll 4
            for (int c = 0; c < 128; ++c)
                acc += Wm[o * 256 + c] * Wo[c * 128 + k];
            a.Wfa[p][o * 128 + k] = splitpack(acc);
        } else {
            const int r2 = rem - 16384;
            const int o = r2 >> 8, k = r2 & 255;
            const float* Wm = a.Wm[p];
            const float* We = a.We[p];
            float acc = 0.f;
            #pragma unroll 4
            for (int c = 0; c < 128; ++c)
                acc += Wm[o * 256 + 128 + c] * We[c * 256 + k];
            a.Wfb[p][o * 256 + k] = splitpack(acc);
        }
    }
}

// ---------------------------------------------------------------------------
// bf16 MFMA GEMM core (hi-only). XBF: X input is bf16 ush (else split u32).
// XMODE 0: X[(b*K + c)*M + m]   XMODE 1: X[((b*N+n)*3+t)*K + c], m = t*N+n
// OMODE 0: fp32(+Z)  3: bf16 Ybf  4: qkv fragment-major
// ---------------------------------------------------------------------------
template <int XMODE, int OMODE, bool XBF>
__device__ __forceinline__ void gemm_tile(
    const u32* __restrict__ Wsp, int wstride,
    const void* __restrict__ Xv, int K,
    const float* __restrict__ Z, float* __restrict__ Y,
    ush* __restrict__ Ybf, ush* __restrict__ Ytr,
    int b, int m0, int o0loc, int oglob, int Ostr,
    ush (*Wh)[64], ush (*Xh)[64])
{
    const int M = 3 * N_;
    const int tid = threadIdx.x;
    const int lane = tid & 63, wv = tid >> 6;
    const int col = lane & 15, grp = lane >> 4;
    const int wo = wv >> 1, wm = wv & 1;

    f32x4 acc[2][2];
    #pragma unroll
    for (int i = 0; i < 2; ++i)
        #pragma unroll
        for (int j = 0; j < 2; ++j) { f32x4 z = {0.f,0.f,0.f,0.f}; acc[i][j] = z; }

    for (int kk = 0; kk < K; kk += 64) {
        {
            const int o = tid >> 2, kg = tid & 3;
            const u32* src = Wsp + (size_t)(o0loc + o) * wstride + kk + kg * 16;
            u32 buf[16];
            #pragma unroll
            for (int j = 0; j < 4; ++j) *(uint4*)&buf[j * 4] = *(const uint4*)(src + j * 4);
            const int s0 = ((kg * 2)     ^ (o & 7)) << 3;
            const int s1 = ((kg * 2 + 1) ^ (o & 7)) << 3;
            short8v h0, h1; unpack_hi(buf, h0, h1);
            *(short8v*)&Wh[o][s0] = h0; *(short8v*)&Wh[o][s1] = h1;
        }
        if (XMODE == 0) {
            const int m = lane, kq = wv;
            const int s0 = ((kq * 2)     ^ (m & 7)) << 3;
            const int s1 = ((kq * 2 + 1) ^ (m & 7)) << 3;
            if (XBF) {
                const ush* src = (const ush*)Xv + ((size_t)b * K + kk + kq * 16) * M + m0 + m;
                ush h[16];
                #pragma unroll
                for (int j = 0; j < 16; ++j) h[j] = src[(size_t)j * M];
                *(short8v*)&Xh[m][s0] = *(short8v*)&h[0];
                *(short8v*)&Xh[m][s1] = *(short8v*)&h[8];
            } else {
                const u32* src = (const u32*)Xv + ((size_t)b * K + kk + kq * 16) * M + m0 + m;
                u32 buf[16];
                #pragma unroll
                for (int j = 0; j < 16; ++j) buf[j] = src[(size_t)j * M];
                short8v h0, h1; unpack_hi(buf, h0, h1);
                *(short8v*)&Xh[m][s0] = h0; *(short8v*)&Xh[m][s1] = h1;
            }
        } else {
            const int m = tid >> 2, kg = tid & 3;
            const int mg = m0 + m;
            const int n = mg & (N_ - 1), t = mg >> 11;
            const int s0 = ((kg * 2)     ^ (m & 7)) << 3;
            const int s1 = ((kg * 2 + 1) ^ (m & 7)) << 3;
            const ush* src = (const ush*)Xv + ((size_t)(b * N_ + n) * 3 + t) * K + kk + kg * 16;
            ush h[16];
            *(uint4*)&h[0] = *(const uint4*)(src);
            *(uint4*)&h[8] = *(const uint4*)(src + 8);
            *(short8v*)&Xh[m][s0] = *(short8v*)&h[0];
            *(short8v*)&Xh[m][s1] = *(short8v*)&h[8];
        }
        __syncthreads();
        #pragma unroll
        for (int kc = 0; kc < 2; ++kc) {
            const int sk = ((kc * 4 + grp) ^ (col & 7)) << 3;
            short8v ah0 = *(const short8v*)&Wh[wo * 32 + col][sk];
            short8v ah1 = *(const short8v*)&Wh[wo * 32 + 16 + col][sk];
            short8v xh0 = *(const short8v*)&Xh[wm * 32 + col][sk];
            short8v xh1 = *(const short8v*)&Xh[wm * 32 + 16 + col][sk];
            acc[0][0] = __builtin_amdgcn_mfma_f32_16x16x32_bf16(ah0, xh0, acc[0][0], 0, 0, 0);
            acc[0][1] = __builtin_amdgcn_mfma_f32_16x16x32_bf16(ah0, xh1, acc[0][1], 0, 0, 0);
            acc[1][0] = __builtin_amdgcn_mfma_f32_16x16x32_bf16(ah1, xh0, acc[1][0], 0, 0, 0);
            acc[1][1] = __builtin_amdgcn_mfma_f32_16x16x32_bf16(ah1, xh1, acc[1][1], 0, 0, 0);
        }
        __syncthreads();
    }
    #pragma unroll
    for (int of = 0; of < 2; ++of) {
        #pragma unroll
        for (int r = 0; r < 4; ++r) {
            const int o = oglob + wo * 32 + of * 16 + grp * 4 + r;
            #pragma unroll
            for (int mf = 0; mf < 2; ++mf) {
                const int mloc = m0 + wm * 32 + mf * 16 + col;
                const size_t idx = ((size_t)b * Ostr + o) * M + mloc;
                float v = acc[of][mf][r];
                if (OMODE == 0) {
                    if (Z) v += Z[idx];
                    Y[idx] = v;
                }
                if (OMODE == 3) Ybf[idx] = f2bf(v);
                if (OMODE == 4) {
                    ush bv = f2bf(v);
                    const int t = mloc >> 11, n = mloc & (N_ - 1);
                    const int h = (o >> 4) & 7, cl = o & 15;
                    const int d = cl * 3 + t;
                    if (o >= 256) {
                        const int kt = n >> 6, hh = (n >> 5) & 1, db = d >> 4;
                        const size_t idx2 = ((size_t)(b * 8 + h) * 192
                                           + (kt * 2 + hh) * 3 + db) * 512
                                          + (((n >> 3) & 3) * 16 + (d & 15)) * 8 + (n & 7);
                        Ybf[idx2] = bv;
                    } else {
                        const int isK = (o >> 7) & 1;
                        const int qg = n >> 4, half = d >> 5;
                        const size_t idx2 = ((size_t)(isK * 16 + b * 8 + h) * 256
                                           + qg * 2 + half) * 512
                                          + (((d >> 3) & 3) * 16 + (n & 15)) * 8 + (d & 7);
                        Ytr[idx2] = bv;
                    }
                }
            }
        }
    }
}

template <int XMODE, int OMODE, bool XBF>
__global__ __launch_bounds__(256) void gemm_kernel2(
    const u32* __restrict__ Wsp, int wstride,
    const void* __restrict__ Xv,
    const float* __restrict__ Z,
    float* __restrict__ Y, ush* __restrict__ Ybf,
    int Ostr, int obase, int K)
{
    __shared__ __align__(16) ush Wh[64][64];
    __shared__ __align__(16) ush Xh[64][64];
    gemm_tile<XMODE, OMODE, XBF>(Wsp, wstride, Xv, K, Z, Y, Ybf, nullptr,
                            blockIdx.z, blockIdx.x * 64,
                            blockIdx.y * 64, obase + blockIdx.y * 64, Ostr,
                            Wh, Xh);
}

// ---------------------------------------------------------------------------
// fused output mix: Y = Wfa*ao (K=128, XMODE0) + Wfb*gbuf (K=256, XMODE1) + Z
// ---------------------------------------------------------------------------
__global__ __launch_bounds__(256) void wm2_kernel(
    const u32* __restrict__ Wfa, const u32* __restrict__ Wfb,
    const ush* __restrict__ ao, const ush* __restrict__ gb,
    const float* __restrict__ Z, float* __restrict__ Y)
{
    __shared__ __align__(16) ush Wh[64][64];
    __shared__ __align__(16) ush Xh[64][64];
    const int M = 3 * N_;
    const int b = blockIdx.z;
    const int m0 = blockIdx.x * 64;
    const int o0 = blockIdx.y * 64;
    const int tid = threadIdx.x;
    const int lane = tid & 63, wv = tid >> 6;
    const int col = lane & 15, grp = lane >> 4;
    const int wo = wv >> 1, wm = wv & 1;

    f32x4 acc[2][2];
    #pragma unroll
    for (int i = 0; i < 2; ++i)
        #pragma unroll
        for (int j = 0; j < 2; ++j) { f32x4 z = {0.f,0.f,0.f,0.f}; acc[i][j] = z; }

    for (int kk = 0; kk < 128; kk += 64) {
        {
            const int o = tid >> 2, kg = tid & 3;
            const u32* src = Wfa + (size_t)(o0 + o) * 128 + kk + kg * 16;
            u32 buf[16];
            #pragma unroll
            for (int j = 0; j < 4; ++j) *(uint4*)&buf[j * 4] = *(const uint4*)(src + j * 4);
            const int s0 = ((kg * 2)     ^ (o & 7)) << 3;
            const int s1 = ((kg * 2 + 1) ^ (o & 7)) << 3;
            short8v h0, h1; unpack_hi(buf, h0, h1);
            *(short8v*)&Wh[o][s0] = h0; *(short8v*)&Wh[o][s1] = h1;
        }
        {
            const int m = lane, kq = wv;
            const int s0 = ((kq * 2)     ^ (m & 7)) << 3;
            const int s1 = ((kq * 2 + 1) ^ (m & 7)) << 3;
            const ush* src = ao + ((size_t)b * 128 + kk + kq * 16) * M + m0 + m;
            ush h[16];
            #pragma unroll
            for (int j = 0; j < 16; ++j) h[j] = src[(size_t)j * M];
            *(short8v*)&Xh[m][s0] = *(short8v*)&h[0];
            *(short8v*)&Xh[m][s1] = *(short8v*)&h[8];
        }
        __syncthreads();
        #pragma unroll
        for (int kc = 0; kc < 2; ++kc) {
            const int sk = ((kc * 4 + grp) ^ (col & 7)) << 3;
            short8v ah0 = *(const short8v*)&Wh[wo * 32 + col][sk];
            short8v ah1 = *(const short8v*)&Wh[wo * 32 + 16 + col][sk];
            short8v xh0 = *(const short8v*)&Xh[wm * 32 + col][sk];
            short8v xh1 = *(const short8v*)&Xh[wm * 32 + 16 + col][sk];
            acc[0][0] = __builtin_amdgcn_mfma_f32_16x16x32_bf16(ah0, xh0, acc[0][0], 0, 0, 0);
            acc[0][1] = __builtin_amdgcn_mfma_f32_16x16x32_bf16(ah0, xh1, acc[0][1], 0, 0, 0);
            acc[1][0] = __builtin_amdgcn_mfma_f32_16x16x32_bf16(ah1, xh0, acc[1][0], 0, 0, 0);
            acc[1][1] = __builtin_amdgcn_mfma_f32_16x16x32_bf16(ah1, xh1, acc[1][1], 0, 0, 0);
        }
        __syncthreads();
    }

    for (int kk = 0; kk < 256; kk += 64) {
        {
            const int o = tid >> 2, kg = tid & 3;
            const u32* src = Wfb + (size_t)(o0 + o) * 256 + kk + kg * 16;
            u32 buf[16];
            #pragma unroll
            for (int j = 0; j < 4; ++j) *(uint4*)&buf[j * 4] = *(const uint4*)(src + j * 4);
            const int s0 = ((kg * 2)     ^ (o & 7)) << 3;
            const int s1 = ((kg * 2 + 1) ^ (o & 7)) << 3;
            short8v h0, h1; unpack_hi(buf, h0, h1);
            *(short8v*)&Wh[o][s0] = h0; *(short8v*)&Wh[o][s1] = h1;
        }
        {
            const int m = tid >> 2, kg = tid & 3;
            const int mg = m0 + m;
            const int n = mg & (N_ - 1), t = mg >> 11;
            const int s0 = ((kg * 2)     ^ (m & 7)) << 3;
            const int s1 = ((kg * 2 + 1) ^ (m & 7)) << 3;
            const ush* src = gb + ((size_t)(b * N_ + n) * 3 + t) * 256 + kk + kg * 16;
            ush h[16];
            *(uint4*)&h[0] = *(const uint4*)(src);
            *(uint4*)&h[8] = *(const uint4*)(src + 8);
            *(short8v*)&Xh[m][s0] = *(short8v*)&h[0];
            *(short8v*)&Xh[m][s1] = *(short8v*)&h[8];
        }
        __syncthreads();
        #pragma unroll
        for (int kc = 0; kc < 2; ++kc) {
            const int sk = ((kc * 4 + grp) ^ (col & 7)) << 3;
            short8v ah0 = *(const short8v*)&Wh[wo * 32 + col][sk];
            short8v ah1 = *(const short8v*)&Wh[wo * 32 + 16 + col][sk];
            short8v xh0 = *(const short8v*)&Xh[wm * 32 + col][sk];
            short8v xh1 = *(const short8v*)&Xh[wm * 32 + 16 + col][sk];
            acc[0][0] = __builtin_amdgcn_mfma_f32_16x16x32_bf16(ah0, xh0, acc[0][0], 0, 0, 0);
            acc[0][1] = __builtin_amdgcn_mfma_f32_16x16x32_bf16(ah0, xh1, acc[0][1], 0, 0, 0);
            acc[1][0] = __builtin_amdgcn_mfma_f32_16x16x32_bf16(ah1, xh0, acc[1][0], 0, 0, 0);
            acc[1][1] = __builtin_amdgcn_mfma_f32_16x16x32_bf16(ah1, xh1, acc[1][1], 0, 0, 0);
        }
        __syncthreads();
    }

    #pragma unroll
    for (int of = 0; of < 2; ++of) {
        #pragma unroll
        for (int r = 0; r < 4; ++r) {
            const int o = o0 + wo * 32 + of * 16 + grp * 4 + r;
            #pragma unroll
            for (int mf = 0; mf < 2; ++mf) {
                const int mloc = m0 + wm * 32 + mf * 16 + col;
                const size_t idx = ((size_t)b * 128 + o) * M + mloc;
                Y[idx] = acc[of][mf][r] + Z[idx];
            }
        }
    }
}

struct QKVArgs {
    const u32* W0; const u32* W1; const u32* W2;
    const ush* X0; const ush* X1; const ush* X2;
};

// fused: qkv projections (blocks 0..1151) + bf16 transpose(s) (blocks 1152..)
__global__ __launch_bounds__(256) void qkv_tr_kernel(QKVArgs A,
        ush* __restrict__ vfm, ush* __restrict__ qktb,
        const ush* __restrict__ ts0, ush* __restrict__ td0,
        const ush* __restrict__ ts1, ush* __restrict__ td1)
{
    __shared__ __align__(16) ush Wh[64][64];
    __shared__ __align__(16) ush Xh[64][64];
    __shared__ ush ttile[32][34];
    const int bx = blockIdx.x;
    if (bx < 1152) {
        const int z = bx / 576, rem = bx % 576;
        const int y = rem / 96, x = rem % 96;
        const int wi = y >> 1;
        const u32* W = wi == 0 ? A.W0 : (wi == 1 ? A.W1 : A.W2);
        const ush* X = wi == 0 ? A.X0 : (wi == 1 ? A.X1 : A.X2);
        gemm_tile<0, 4, true>(W, 128, X, 128, nullptr, nullptr, vfm, qktb,
                        z, x * 64, (y & 1) * 64, y * 64, 384,
                        Wh, Xh);
    } else {
        int i = bx - 1152;
        const int which = i / 1536; i %= 1536;
        const ush* src = which ? ts1 : ts0;
        ush* dst = which ? td1 : td0;
        const int x = i & 63, y = (i >> 6) & 3, z = i >> 8;
        const int b = z / 3, t = z % 3;
        const int n0 = x * 32, c0 = y * 32;
        const int tx = threadIdx.x & 31, ty = threadIdx.x >> 5;
        #pragma unroll
        for (int p = 0; p < 4; ++p) {
            int c = c0 + ty + p * 8;
            ttile[ty + p * 8][tx] = src[((size_t)(b * C_ + c) * 3 + t) * N_ + n0 + tx];
        }
        __syncthreads();
        #pragma unroll
        for (int p = 0; p < 4; ++p) {
            int n = n0 + ty + p * 8;
            dst[((size_t)(b * N_ + n) * 3 + t) * C_ + c0 + tx] = ttile[tx][ty + p * 8];
        }
    }
}

// ---------------------------------------------------------------------------
// barrier-free split-K flash attention, XCD-chunked 1D grid (1024 blocks).
// KSPLIT=4: each wave owns kz = its wave index, 32 queries x 512 keys.
// Each XCD owns 2 complete bh groups (~1.4MB working set < 4MB L2).
// ---------------------------------------------------------------------------
__global__ __launch_bounds__(256) void attn_mfma_kernel(
    const ush* __restrict__ vfm, const ush* __restrict__ qktb,
    ush* __restrict__ pacc, float* __restrict__ pml)
{
    __shared__ __align__(16) ush Pl[4][2][16][64];   // 16 KB

    const int flat = blockIdx.x;
    const int xcd  = flat & 7;
    const int slot = flat >> 3;          // 0..127
    const int bh   = xcd * 2 + (slot >> 6);   // 0..15
    const int q32  = slot & 63;

    const int tid = threadIdx.x;
    const int lane = tid & 63, wv = tid >> 6;
    const int col = lane & 15, grp = lane >> 4;
    const int c7  = col & 7;
    const int kz  = wv;
    const int ks0 = kz * (N_ / KSPLIT);

    const ush* Qpl = qktb + (size_t)bh * 131072;
    const ush* Kpl = qktb + (size_t)(16 + bh) * 131072;
    const ush* Vpl = vfm  + (size_t)bh * 98304;

    short8v qf[2][2];
    #pragma unroll
    for (int qi = 0; qi < 2; ++qi) {
        const int qg = q32 * 2 + qi;
        qf[qi][0] = *(const short8v*)(Qpl + ((size_t)qg * 2 + 0) * 512 + lane * 8);
        qf[qi][1] = *(const short8v*)(Qpl + ((size_t)qg * 2 + 1) * 512 + lane * 8);
    }

    f32x4 acc[2][3];
    #pragma unroll
    for (int qi = 0; qi < 2; ++qi)
        #pragma unroll
        for (int db = 0; db < 3; ++db) { f32x4 z = {0.f,0.f,0.f,0.f}; acc[qi][db] = z; }
    float m_i[2] = {0.f, 0.f};
    float l_l[2] = {0.f, 0.f};

    const int NT = (N_ / KSPLIT) / 64;   // 8 tiles of 64 keys
    for (int mt = 0; mt < NT; ++mt) {
        const int m0 = ks0 + mt * 64;

        short8v ka[4][2];
        #pragma unroll
        for (int kb = 0; kb < 4; ++kb) {
            const size_t kg = (m0 >> 4) + kb;
            ka[kb][0] = *(const short8v*)(Kpl + (kg * 2 + 0) * 512 + lane * 8);
            ka[kb][1] = *(const short8v*)(Kpl + (kg * 2 + 1) * 512 + lane * 8);
        }
        const int kt = m0 >> 6;
        short8v vf[2][3];
        #pragma unroll
        for (int hh = 0; hh < 2; ++hh)
            #pragma unroll
            for (int db = 0; db < 3; ++db)
                vf[hh][db] = *(const short8v*)(Vpl + (size_t)((kt * 2 + hh) * 3 + db) * 512 + lane * 8);

        f32x4 sf[2][4];
        __builtin_amdgcn_s_setprio(1);
        #pragma unroll
        for (int qi = 0; qi < 2; ++qi)
            #pragma unroll
            for (int kb = 0; kb < 4; ++kb) {
                f32x4 z = {0.f, 0.f, 0.f, 0.f};
                z = __builtin_amdgcn_mfma_f32_16x16x32_bf16(ka[kb][0], qf[qi][0], z, 0, 0, 0);
                z = __builtin_amdgcn_mfma_f32_16x16x32_bf16(ka[kb][1], qf[qi][1], z, 0, 0, 0);
                sf[qi][kb] = z;
            }
        __builtin_amdgcn_s_setprio(0);

        #pragma unroll
        for (int qi = 0; qi < 2; ++qi) {
            float psum = 0.f;
            #pragma unroll
            for (int kb = 0; kb < 4; ++kb) {
                float e0 = __expf(sf[qi][kb][0] - m_i[qi]);
                float e1 = __expf(sf[qi][kb][1] - m_i[qi]);
                float e2 = __expf(sf[qi][kb][2] - m_i[qi]);
                float e3 = __expf(sf[qi][kb][3] - m_i[qi]);
                psum += (e0 + e1) + (e2 + e3);
                u32 r0, r1;
                asm("v_cvt_pk_bf16_f32 %0, %1, %2" : "=v"(r0) : "v"(e0), "v"(e1));
                asm("v_cvt_pk_bf16_f32 %0, %1, %2" : "=v"(r1) : "v"(e2), "v"(e3));
                const int un = (4 * kb + grp) ^ (c7 << 1);
                uint2 pk2; pk2.x = r0; pk2.y = r1;
                *(uint2*)&Pl[wv][qi][col][un << 2] = pk2;
            }
            l_l[qi] += psum;
        }

        __builtin_amdgcn_s_setprio(1);
        #pragma unroll
        for (int qi = 0; qi < 2; ++qi)
            #pragma unroll
            for (int hh = 0; hh < 2; ++hh) {
                const int ur = (8 * hh + 2 * grp) ^ (c7 << 1);
                short8v pf = *(const short8v*)&Pl[wv][qi][col][ur << 2];
                #pragma unroll
                for (int db = 0; db < 3; ++db)
                    acc[qi][db] = __builtin_amdgcn_mfma_f32_16x16x32_bf16(vf[hh][db], pf, acc[qi][db], 0, 0, 0);
            }
        __builtin_amdgcn_s_setprio(0);

        #pragma unroll
        for (int qi = 0; qi < 2; ++qi) {
            float pmax = -1e30f;
            #pragma unroll
            for (int kb = 0; kb < 4; ++kb)
                #pragma unroll
                for (int r = 0; r < 4; ++r) pmax = fmaxf(pmax, sf[qi][kb][r]);
            pmax = fmaxf(pmax, __shfl_xor(pmax, 16, 64));
            pmax = fmaxf(pmax, __shfl_xor(pmax, 32, 64));
            if (!__all(pmax - m_i[qi] <= 8.0f)) {
                float mnew = fmaxf(m_i[qi], pmax);
                float sc = __expf(m_i[qi] - mnew);
                l_l[qi] *= sc;
                #pragma unroll
                for (int db = 0; db < 3; ++db) {
                    acc[qi][db][0] *= sc; acc[qi][db][1] *= sc;
                    acc[qi][db][2] *= sc; acc[qi][db][3] *= sc;
                }
                m_i[qi] = mnew;
            }
        }
    }

    const int ntile = q32 >> 1, qh = q32 & 1;
    const size_t pb = (size_t)(kz * 16 + bh) * 32 + ntile;
    #pragma unroll
    for (int qi = 0; qi < 2; ++qi) {
        float l = l_l[qi];
        l += __shfl_xor(l, 16, 64);
        l += __shfl_xor(l, 32, 64);
        const int q = qh * 32 + qi * 16 + col;
        #pragma unroll
        for (int db = 0; db < 3; ++db)
            #pragma unroll
            for (int r = 0; r < 4; ++r) {
                int d = db * 16 + grp * 4 + r;
                pacc[pb * 3072 + d * 64 + q] = f2bf(acc[qi][db][r]);
            }
        if (grp == 0) {
            pml[pb * 128 + q]      = m_i[qi];
            pml[pb * 128 + 64 + q] = l;
        }
    }
}

// ---------------------------------------------------------------------------
// fused: split-K reduce (blocks 0..511) + graph attention (blocks 512..4607)
// ---------------------------------------------------------------------------
__global__ __launch_bounds__(256) void reduce_graph_kernel(
    const ush* __restrict__ pacc, const float* __restrict__ pml,
    ush* __restrict__ ao,
    const ush* __restrict__ tq, const ush* __restrict__ tv,
    const int* __restrict__ idx, ush* __restrict__ gbuf)
{
    __shared__ float centerf[384];
    __shared__ ush nbr_l[16][384];
    __shared__ float sd[16];
    __shared__ int nbr_i[16];
    const int tid = threadIdx.x;

    if (blockIdx.x < 512) {
        // ============ split-K reduce ============
        const int nt = blockIdx.x & 31, bh = blockIdx.x >> 5;
        const int b = bh >> 3, h = bh & 7;
        const int q = tid & 63, dg = tid >> 6;

        size_t pb[KSPLIT];
        float m[KSPLIT], l[KSPLIT];
        #pragma unroll
        for (int kz = 0; kz < KSPLIT; ++kz) {
            pb[kz] = (size_t)(kz * 16 + bh) * 32 + nt;
            m[kz] = pml[pb[kz] * 128 + q];
            l[kz] = pml[pb[kz] * 128 + 64 + q];
        }
        float ms = -1e30f;
        #pragma unroll
        for (int kz = 0; kz < KSPLIT; ++kz) ms = fmaxf(ms, m[kz]);
        float w[KSPLIT], ls = 0.f;
        #pragma unroll
        for (int kz = 0; kz < KSPLIT; ++kz) { w[kz] = __expf(m[kz] - ms); ls += l[kz] * w[kz]; }
        const float inv = 1.f / ls;

        const size_t hb = ((size_t)(b * C_ + h * 16)) * 3 * N_;
        #pragma unroll
        for (int j = 0; j < 12; ++j) {
            int d = dg * 12 + j;
            float o = 0.f;
            #pragma unroll
            for (int kz = 0; kz < KSPLIT; ++kz)
                o += bf2f(pacc[pb[kz] * 3072 + d * 64 + q]) * w[kz];
            ao[hb + (size_t)d * N_ + nt * 64 + q] = f2bf(o * inv);
        }
    } else {
        // ============ graph attention ============
        const int j = blockIdx.x - 512;
        const int b = j >> 11, n = j & 2047;
        const ush* qrow = tq + (size_t)(b * N_ + n) * 384;
        for (int e = tid; e < 384; e += 256) centerf[e] = bf2f(qrow[e]);
        if (tid < 16) nbr_i[tid] = idx[(size_t)(b * N_ + n) * 16 + tid];
        __syncthreads();

        const int lane = tid & 63, wv = tid >> 6;
        for (int kk = 0; kk < 4; ++kk) {
            int k = wv * 4 + kk;
            const u32* vrow = (const u32*)(tv + ((size_t)b * N_ + nbr_i[k]) * 384);
            float p = 0.f;
            #pragma unroll
            for (int jj = 0; jj < 3; ++jj) {
                int e2 = lane + jj * 64;
                u32 v2 = vrow[e2];
                ((u32*)nbr_l[k])[e2] = v2;
                p += centerf[e2 * 2]     * bf2f((ush)(v2 & 0xffff))
                   + centerf[e2 * 2 + 1] * bf2f((ush)(v2 >> 16));
            }
            #pragma unroll
            for (int off = 32; off; off >>= 1) p += __shfl_down(p, off, 64);
            if (lane == 0) sd[k] = p * 0.05103103630798288f;
        }
        __syncthreads();

        float mx = -1e30f;
        #pragma unroll
        for (int k = 0; k < 16; ++k) mx = fmaxf(mx, sd[k]);
        float a[16]; float ssum = 0.f;
        #pragma unroll
        for (int k = 0; k < 16; ++k) { a[k] = __expf(sd[k] - mx); ssum += a[k]; }
        float inv = 1.f / ssum;

        for (int e = tid; e < 384; e += 256) {
            float accv = 0.f;
            #pragma unroll
            for (int k = 0; k < 16; ++k)
                accv += a[k] * bf2f(nbr_l[k][e]);
            accv *= inv;
            float ce = centerf[e];
            int t = e >> 7, c = e & 127;
            size_t gb = ((size_t)(b * N_ + n) * 3 + t) * 256;
            gbuf[gb + c]       = f2bf(accv - ce);
            gbuf[gb + 128 + c] = f2bf(ce);
        }
    }
}

// ---------------------------------------------------------------------------
// vn_leaky: bf16 x,d in -> bf16 out
// ---------------------------------------------------------------------------
__global__ __launch_bounds__(256) void leaky_kernel(const ush* __restrict__ x,
                                                    const ush* __restrict__ d,
                                                    ush* __restrict__ y)
{
    size_t p = (size_t)blockIdx.x * 256 + threadIdx.x;
    size_t bh = p / N_, n = p % N_;
    size_t base = bh * 3 * N_ + n;
    float x0 = bf2f(x[base]), x1 = bf2f(x[base + N_]), x2 = bf2f(x[base + 2 * N_]);
    float d0 = bf2f(d[base]), d1 = bf2f(d[base + N_]), d2 = bf2f(d[base + 2 * N_]);
    float dot = x0 * d0 + x1 * d1 + x2 * d2;
    float dsq = d0 * d0 + d1 * d1 + d2 * d2;
    float f = dot / (dsq + EPS_);
    bool pos = dot >= 0.f;
    float y0 = pos ? x0 : x0 - f * d0;
    float y1 = pos ? x1 : x1 - f * d1;
    float y2 = pos ? x2 : x2 - f * d2;
    y[base]          = f2bf(NS_ * x0 + (1.f - NS_) * y0);
    y[base + N_]     = f2bf(NS_ * x1 + (1.f - NS_) * y1);
    y[base + 2 * N_] = f2bf(NS_ * x2 + (1.f - NS_) * y2);
}

// ---------------------------------------------------------------------------
extern "C" void kernel_launch(void* const* d_in, const int* in_sizes, int n_in,
                              void* d_out, int out_size, void* d_ws, size_t ws_size,
                              hipStream_t stream)
{
    const float* q_in = (const float*)d_in[0];
    const float* v_in = (const float*)d_in[1];
    const int*   idx_s = (const int*)d_in[4];
    const int*   idx_c = (const int*)d_in[5];
    const float* g1 = (const float*)d_in[6];
    const float* b1 = (const float*)d_in[7];
    const float* g2 = (const float*)d_in[8];
    const float* b2 = (const float*)d_in[9];
    const float* gq = (const float*)d_in[10];
    const float* bq = (const float*)d_in[11];
    const float* gv = (const float*)d_in[12];
    const float* bv = (const float*)d_in[13];
    float* out = (float*)d_out;
    float* ws  = (float*)d_ws;

    const size_t S1 = (size_t)B_ * C_ * 3 * N_; // 1572864 elems
    ush*   gbuf_b= (ush*)(ws);         // 0 (6.3MB; live reduce_graph -> wm2)
    ush*   nx_b  = (ush*)(ws + 2*S1);  // 2 (half)
    ush*   nv_b  = (ush*)(ws + 3*S1);  // 3 (half)
    ush*   vfm   = (ush*)(ws + 4*S1);  // 4: 3MB
    ush*   qktb  = (ush*)(ws + 5*S1) + S1;  // 5.5-6.84: 8.4MB
    ush*   ao_b  = (ush*)(ws + 7*S1);  // 7 (half)
    float* qa    = ws + 12*S1;         // 12
    float* qb    = ws + 13*S1;         // 13
    ush*   t1_b  = (ush*)(ws + 14*S1); // 14 (half)
    ush*   t2_b  = (ush*)(ws + 15*S1); // 15 (half)
    u32*   wsp   = (u32*)(ws + 16*S1); // 16+
    // split-K attention partials (attn->reduce window only; KSPLIT=4: 12.6MB)
    ush*   pacc  = (ush*)(ws + 8*S1);  // 8-9
    float* pml   = (float*)(ws + 2*S1);// 2 (attn after qkv consumed nx_b)
    // phase C aliases (all bf16):
    ush*   hd_b  = (ush*)(ws + 1*S1);  // 1-2 as ush (12.6MB; nv_b/pml dead)
    ush*   h1_b  = (ush*)(ws + 14*S1); // 14-15 (t1/t2 dead)
    ush*   h1_b2 = (ush*)(ws + 8*S1);  // 8-9 (pacc dead)

    // weight planes: 9 split-converted + 4 fused (Wfa/Wfb per phase)
    const int wn[9]   = {16384,16384,16384, 16384,16384,16384, 65536,262144,65536};
    const int wsrc[9] = {14,15,16, 20,21,22, 26,27,28};
    u32* wd[9];
    {
        int off = 0;
        for (int i = 0; i < 9; ++i) { wd[i] = wsp + off; off += wn[i]; }
    }
    u32 *Wq_s = wd[0], *Wk_s = wd[1], *Wv_s = wd[2];
    u32 *Wq_c = wd[3], *Wk_c = wd[4], *Wv_c = wd[5];
    u32 *W1 = wd[6], *Dact = wd[7], *W2 = wd[8];
    u32* Wfa_s = wsp + 491520;
    u32* Wfb_s = Wfa_s + 16384;
    u32* Wfa_c = Wfb_s + 32768;
    u32* Wfb_c = Wfa_c + 16384;

    // zero qktb once per launch (d=48..63 pad slots must be 0)
    hipMemsetAsync(qktb, 0, (size_t)32 * 131072 * sizeof(ush), stream);

    {
        SetupArgs a{};
        for (int i = 0; i < 9; ++i) {
            a.src[i] = (const float*)d_in[wsrc[i]];
            a.dst[i] = wd[i];
            a.n[i]   = wn[i];
            a.scale[i] = 1.f;
        }
        a.scale[0] = 0.14433756729740643f;  // Wq_s: fold 1/sqrt(48)
        a.scale[3] = 0.14433756729740643f;  // Wq_c
        a.Wm[0] = (const float*)d_in[19]; a.Wo[0] = (const float*)d_in[17]; a.We[0] = (const float*)d_in[18];
        a.Wm[1] = (const float*)d_in[25]; a.Wo[1] = (const float*)d_in[23]; a.We[1] = (const float*)d_in[24];
        a.Wfa[0] = Wfa_s; a.Wfb[0] = Wfb_s;
        a.Wfa[1] = Wfa_c; a.Wfb[1] = Wfb_c;
        setup_kernel<<<dim3(9216 + 384), 256, 0, stream>>>(a);
    }

    dim3 gwm(96, 2, B_);
    dim3 gg512(96, 8, B_);

    // ---- Phase A: self attention block ----
    {
        LNArgs la{};
        la.x[0] = q_in; la.g[0] = g1; la.bt[0] = b1; la.ysp[0] = nx_b;
        ln_kernel<<<dim3(64, B_, 1), 256, 0, stream>>>(la);
    }
    {
        QKVArgs A{Wq_s, Wk_s, Wv_s, nx_b, nx_b, nx_b};
        qkv_tr_kernel<<<dim3(1152 + 1536), 256, 0, stream>>>(A, vfm, qktb, nx_b, t1_b, nullptr, nullptr);
    }
    attn_mfma_kernel<<<dim3(1024), 256, 0, stream>>>(vfm, qktb, pacc, pml);
    reduce_graph_kernel<<<dim3(512 + 4096), 256, 0, stream>>>(pacc, pml, ao_b, t1_b, t1_b, idx_s, gbuf_b);
    wm2_kernel<<<gwm, 256, 0, stream>>>(Wfa_s, Wfb_s, ao_b, gbuf_b, q_in, qa);

    // ---- Phase B: cross attention block ----
    {
        LNArgs la{};
        la.x[0] = qa;   la.g[0] = gq; la.bt[0] = bq; la.ysp[0] = nx_b;
        la.x[1] = v_in; la.g[1] = gv; la.bt[1] = bv; la.ysp[1] = nv_b;
        ln_kernel<<<dim3(64, B_, 2), 256, 0, stream>>>(la);
    }
    {
        QKVArgs A{Wq_c, Wk_c, Wv_c, nx_b, nv_b, nv_b};
        qkv_tr_kernel<<<dim3(1152 + 3072), 256, 0, stream>>>(A, vfm, qktb, nx_b, t1_b, nv_b, t2_b);
    }
    attn_mfma_kernel<<<dim3(1024), 256, 0, stream>>>(vfm, qktb, pacc, pml);
    reduce_graph_kernel<<<dim3(512 + 4096), 256, 0, stream>>>(pacc, pml, ao_b, t1_b, t2_b, idx_c, gbuf_b);
    wm2_kernel<<<gwm, 256, 0, stream>>>(Wfa_c, Wfb_c, ao_b, gbuf_b, qa, qb);

    // ---- Phase C: vector MLP (all-bf16 intermediates) ----
    {
        LNArgs la{};
        la.x[0] = qb; la.g[0] = g2; la.bt[0] = b2; la.ysp[0] = nx_b;
        ln_kernel<<<dim3(64, B_, 1), 256, 0, stream>>>(la);
    }
    gemm_kernel2<0,3,true><<<gg512, 256, 0, stream>>>(W1, 128, nx_b, nullptr, nullptr, h1_b, 512, 0, 128);
    gemm_kernel2<0,3,true><<<gg512, 256, 0, stream>>>(Dact, 512, h1_b, nullptr, nullptr, hd_b, 512, 0, 512);
    leaky_kernel<<<dim3((B_ * HID_ * N_) / 256), 256, 0, stream>>>(h1_b, hd_b, h1_b2);
    gemm_kernel2<0,0,true><<<dim3(96, 2, B_), 256, 0, stream>>>(W2, 512, h1_b2, qb, out, nullptr, 128, 0, 512);
}

// Round 18
// 219.826 us; speedup vs baseline: 1.4752x; 1.0529x over previous
//
#include <hip/hip_runtime.h>
#include <math.h>

#define B_    2
#define C_    128
#define N_    2048
#define HID_  512
#define HEADS_ 8
#define EPS_  1e-6f
#define NS_   0.2f
#define KSPLIT 4

typedef __attribute__((ext_vector_type(8))) short short8v;  // 8 bf16
typedef __attribute__((ext_vector_type(4))) float f32x4;
typedef unsigned short ush;
typedef unsigned int u32;

__device__ inline ush f2bf(float f) {
    unsigned u = __float_as_uint(f);
    u += 0x7FFF + ((u >> 16) & 1);          // round-to-nearest-even
    return (ush)(u >> 16);
}
__device__ inline float bf2f(ush u) { return __uint_as_float((u32)u << 16); }

// pack float -> (hi bf16 << 16) | lo bf16
__device__ inline u32 splitpack(float x) {
    ush hi = f2bf(x);
    float hf = __uint_as_float((u32)hi << 16);
    ush lo = f2bf(x - hf);
    return ((u32)hi << 16) | (u32)lo;
}

__device__ inline void unpack_hi(const u32* buf, short8v& h0, short8v& h1) {
    ush h[16];
    #pragma unroll
    for (int j = 0; j < 16; ++j) h[j] = (ush)(buf[j] >> 16);
    h0 = *(short8v*)&h[0]; h1 = *(short8v*)&h[8];
}

// ---------------------------------------------------------------------------
// vec_layernorm, z-indexed multi-input, single global read pass (registers)
// ---------------------------------------------------------------------------
struct LNArgs {
    const float* x[2]; const float* g[2]; const float* bt[2]; ush* ysp[2];
};
__global__ __launch_bounds__(256) void ln_kernel(LNArgs a)
{
    __shared__ float red1[8][32];
    __shared__ float red2[8][32];
    const int s = blockIdx.z;
    const float* x = a.x[s];
    const float* gma = a.g[s];
    const float* bta = a.bt[s];
    ush* ysp = a.ysp[s];

    const int b  = blockIdx.y;
    const int n0 = blockIdx.x * 32;
    const int nn = threadIdx.x & 31;
    const int cg = threadIdx.x >> 5;

    float xr0[16], xr1[16], xr2[16], nrr[16];
    float s1 = 0.f, s2 = 0.f;
    #pragma unroll
    for (int it = 0; it < 16; ++it) {
        int c = it * 8 + cg;
        size_t base = ((size_t)(b * C_ + c) * 3) * N_ + n0 + nn;
        float x0 = x[base], x1 = x[base + N_], x2 = x[base + 2 * N_];
        float nr = sqrtf(x0 * x0 + x1 * x1 + x2 * x2 + EPS_);
        xr0[it] = x0; xr1[it] = x1; xr2[it] = x2; nrr[it] = nr;
        s1 += nr; s2 += nr * nr;
    }
    red1[cg][nn] = s1; red2[cg][nn] = s2;
    __syncthreads();
    float S1 = 0.f, S2 = 0.f;
    #pragma unroll
    for (int g = 0; g < 8; ++g) { S1 += red1[g][nn]; S2 += red2[g][nn]; }
    float mu   = S1 * (1.f / 128.f);
    float var  = S2 * (1.f / 128.f) - mu * mu;
    float rstd = rsqrtf(var + EPS_);

    #pragma unroll
    for (int it = 0; it < 16; ++it) {
        int c = it * 8 + cg;
        float nr = nrr[it];
        float ln = (nr - mu) * rstd * gma[c] + bta[c];
        float sc = ln / (nr + EPS_);
        size_t base = ((size_t)(b * C_ + c) * 3) * N_ + n0 + nn;
        ysp[base]          = f2bf(xr0[it] * sc);
        ysp[base + N_]     = f2bf(xr1[it] * sc);
        ysp[base + 2 * N_] = f2bf(xr2[it] * sc);
    }
}

// ---------------------------------------------------------------------------
// fused setup: 9 weight split-conversions (blocks 0..9215) + output-mix
// weight products Wfa/Wfb (blocks 9216..9599) + qktb zeroing (9600..10623)
// ---------------------------------------------------------------------------
struct SetupArgs {
    const float* src[9]; u32* dst[9]; int n[9]; float scale[9];
    const float* Wm[2]; const float* Wo[2]; const float* We[2];
    u32* Wfa[2]; u32* Wfb[2];
    uint4* qkz;
};
__global__ __launch_bounds__(256) void setup_kernel(SetupArgs a)
{
    const int bx = blockIdx.x;
    if (bx < 9216) {
        const int w = bx / 1024;
        const int i = (bx % 1024) * 256 + threadIdx.x;
        if (i < a.n[w]) a.dst[w][i] = splitpack(a.src[w][i] * a.scale[w]);
    } else if (bx < 9600) {
        const int tg = (bx - 9216) * 256 + threadIdx.x;   // 0..98303
        const int p = tg / 49152;
        const int rem = tg % 49152;
        if (rem < 16384) {
            const int o = rem >> 7, k = rem & 127;
            const float* Wm = a.Wm[p];
            const float* Wo = a.Wo[p];
            float acc = 0.f;
            #pragma unroll 4
            for (int c = 0; c < 128; ++c)
                acc += Wm[o * 256 + c] * Wo[c * 128 + k];
            a.Wfa[p][o * 128 + k] = splitpack(acc);
        } else {
            const int r2 = rem - 16384;
            const int o = r2 >> 8, k = r2 & 255;
            const float* Wm = a.Wm[p];
            const float* We = a.We[p];
            float acc = 0.f;
            #pragma unroll 4
            for (int c = 0; c < 128; ++c)
                acc += Wm[o * 256 + 128 + c] * We[c * 256 + k];
            a.Wfb[p][o * 256 + k] = splitpack(acc);
        }
    } else {
        // zero qktb (524288 uint4 = 8.4MB); 1024 blocks x 512 uint4
        const size_t i0 = ((size_t)(bx - 9600) * 256 + threadIdx.x) * 2;
        uint4 z = {0, 0, 0, 0};
        a.qkz[i0]     = z;
        a.qkz[i0 + 1] = z;
    }
}

// ---------------------------------------------------------------------------
// bf16 MFMA GEMM core (hi-only). XBF: X input is bf16 ush (else split u32).
// XMODE 0: X[(b*K + c)*M + m]   XMODE 1: X[((b*N+n)*3+t)*K + c], m = t*N+n
// OMODE 0: fp32(+Z)  3: bf16 Ybf  4: qkv fragment-major
// ---------------------------------------------------------------------------
template <int XMODE, int OMODE, bool XBF>
__device__ __forceinline__ void gemm_tile(
    const u32* __restrict__ Wsp, int wstride,
    const void* __restrict__ Xv, int K,
    const float* __restrict__ Z, float* __restrict__ Y,
    ush* __restrict__ Ybf, ush* __restrict__ Ytr,
    int b, int m0, int o0loc, int oglob, int Ostr,
    ush (*Wh)[64], ush (*Xh)[64])
{
    const int M = 3 * N_;
    const int tid = threadIdx.x;
    const int lane = tid & 63, wv = tid >> 6;
    const int col = lane & 15, grp = lane >> 4;
    const int wo = wv >> 1, wm = wv & 1;

    f32x4 acc[2][2];
    #pragma unroll
    for (int i = 0; i < 2; ++i)
        #pragma unroll
        for (int j = 0; j < 2; ++j) { f32x4 z = {0.f,0.f,0.f,0.f}; acc[i][j] = z; }

    for (int kk = 0; kk < K; kk += 64) {
        {
            const int o = tid >> 2, kg = tid & 3;
            const u32* src = Wsp + (size_t)(o0loc + o) * wstride + kk + kg * 16;
            u32 buf[16];
            #pragma unroll
            for (int j = 0; j < 4; ++j) *(uint4*)&buf[j * 4] = *(const uint4*)(src + j * 4);
            const int s0 = ((kg * 2)     ^ (o & 7)) << 3;
            const int s1 = ((kg * 2 + 1) ^ (o & 7)) << 3;
            short8v h0, h1; unpack_hi(buf, h0, h1);
            *(short8v*)&Wh[o][s0] = h0; *(short8v*)&Wh[o][s1] = h1;
        }
        if (XMODE == 0) {
            const int m = lane, kq = wv;
            const int s0 = ((kq * 2)     ^ (m & 7)) << 3;
            const int s1 = ((kq * 2 + 1) ^ (m & 7)) << 3;
            if (XBF) {
                const ush* src = (const ush*)Xv + ((size_t)b * K + kk + kq * 16) * M + m0 + m;
                ush h[16];
                #pragma unroll
                for (int j = 0; j < 16; ++j) h[j] = src[(size_t)j * M];
                *(short8v*)&Xh[m][s0] = *(short8v*)&h[0];
                *(short8v*)&Xh[m][s1] = *(short8v*)&h[8];
            } else {
                const u32* src = (const u32*)Xv + ((size_t)b * K + kk + kq * 16) * M + m0 + m;
                u32 buf[16];
                #pragma unroll
                for (int j = 0; j < 16; ++j) buf[j] = src[(size_t)j * M];
                short8v h0, h1; unpack_hi(buf, h0, h1);
                *(short8v*)&Xh[m][s0] = h0; *(short8v*)&Xh[m][s1] = h1;
            }
        } else {
            const int m = tid >> 2, kg = tid & 3;
            const int mg = m0 + m;
            const int n = mg & (N_ - 1), t = mg >> 11;
            const int s0 = ((kg * 2)     ^ (m & 7)) << 3;
            const int s1 = ((kg * 2 + 1) ^ (m & 7)) << 3;
            const ush* src = (const ush*)Xv + ((size_t)(b * N_ + n) * 3 + t) * K + kk + kg * 16;
            ush h[16];
            *(uint4*)&h[0] = *(const uint4*)(src);
            *(uint4*)&h[8] = *(const uint4*)(src + 8);
            *(short8v*)&Xh[m][s0] = *(short8v*)&h[0];
            *(short8v*)&Xh[m][s1] = *(short8v*)&h[8];
        }
        __syncthreads();
        #pragma unroll
        for (int kc = 0; kc < 2; ++kc) {
            const int sk = ((kc * 4 + grp) ^ (col & 7)) << 3;
            short8v ah0 = *(const short8v*)&Wh[wo * 32 + col][sk];
            short8v ah1 = *(const short8v*)&Wh[wo * 32 + 16 + col][sk];
            short8v xh0 = *(const short8v*)&Xh[wm * 32 + col][sk];
            short8v xh1 = *(const short8v*)&Xh[wm * 32 + 16 + col][sk];
            acc[0][0] = __builtin_amdgcn_mfma_f32_16x16x32_bf16(ah0, xh0, acc[0][0], 0, 0, 0);
            acc[0][1] = __builtin_amdgcn_mfma_f32_16x16x32_bf16(ah0, xh1, acc[0][1], 0, 0, 0);
            acc[1][0] = __builtin_amdgcn_mfma_f32_16x16x32_bf16(ah1, xh0, acc[1][0], 0, 0, 0);
            acc[1][1] = __builtin_amdgcn_mfma_f32_16x16x32_bf16(ah1, xh1, acc[1][1], 0, 0, 0);
        }
        __syncthreads();
    }
    #pragma unroll
    for (int of = 0; of < 2; ++of) {
        #pragma unroll
        for (int r = 0; r < 4; ++r) {
            const int o = oglob + wo * 32 + of * 16 + grp * 4 + r;
            #pragma unroll
            for (int mf = 0; mf < 2; ++mf) {
                const int mloc = m0 + wm * 32 + mf * 16 + col;
                const size_t idx = ((size_t)b * Ostr + o) * M + mloc;
                float v = acc[of][mf][r];
                if (OMODE == 0) {
                    if (Z) v += Z[idx];
                    Y[idx] = v;
                }
                if (OMODE == 3) Ybf[idx] = f2bf(v);
                if (OMODE == 4) {
                    ush bv = f2bf(v);
                    const int t = mloc >> 11, n = mloc & (N_ - 1);
                    const int h = (o >> 4) & 7, cl = o & 15;
                    const int d = cl * 3 + t;
                    if (o >= 256) {
                        const int kt = n >> 6, hh = (n >> 5) & 1, db = d >> 4;
                        const size_t idx2 = ((size_t)(b * 8 + h) * 192
                                           + (kt * 2 + hh) * 3 + db) * 512
                                          + (((n >> 3) & 3) * 16 + (d & 15)) * 8 + (n & 7);
                        Ybf[idx2] = bv;
                    } else {
                        const int isK = (o >> 7) & 1;
                        const int qg = n >> 4, half = d >> 5;
                        const size_t idx2 = ((size_t)(isK * 16 + b * 8 + h) * 256
                                           + qg * 2 + half) * 512
                                          + (((d >> 3) & 3) * 16 + (n & 15)) * 8 + (d & 7);
                        Ytr[idx2] = bv;
                    }
                }
            }
        }
    }
}

template <int XMODE, int OMODE, bool XBF>
__global__ __launch_bounds__(256) void gemm_kernel2(
    const u32* __restrict__ Wsp, int wstride,
    const void* __restrict__ Xv,
    const float* __restrict__ Z,
    float* __restrict__ Y, ush* __restrict__ Ybf,
    int Ostr, int obase, int K)
{
    __shared__ __align__(16) ush Wh[64][64];
    __shared__ __align__(16) ush Xh[64][64];
    gemm_tile<XMODE, OMODE, XBF>(Wsp, wstride, Xv, K, Z, Y, Ybf, nullptr,
                            blockIdx.z, blockIdx.x * 64,
                            blockIdx.y * 64, obase + blockIdx.y * 64, Ostr,
                            Wh, Xh);
}

// ---------------------------------------------------------------------------
// fused output mix: Y = Wfa*ao (K=128, XMODE0) + Wfb*gbuf (K=256, XMODE1) + Z
// ---------------------------------------------------------------------------
__global__ __launch_bounds__(256) void wm2_kernel(
    const u32* __restrict__ Wfa, const u32* __restrict__ Wfb,
    const ush* __restrict__ ao, const ush* __restrict__ gb,
    const float* __restrict__ Z, float* __restrict__ Y)
{
    __shared__ __align__(16) ush Wh[64][64];
    __shared__ __align__(16) ush Xh[64][64];
    const int M = 3 * N_;
    const int b = blockIdx.z;
    const int m0 = blockIdx.x * 64;
    const int o0 = blockIdx.y * 64;
    const int tid = threadIdx.x;
    const int lane = tid & 63, wv = tid >> 6;
    const int col = lane & 15, grp = lane >> 4;
    const int wo = wv >> 1, wm = wv & 1;

    f32x4 acc[2][2];
    #pragma unroll
    for (int i = 0; i < 2; ++i)
        #pragma unroll
        for (int j = 0; j < 2; ++j) { f32x4 z = {0.f,0.f,0.f,0.f}; acc[i][j] = z; }

    for (int kk = 0; kk < 128; kk += 64) {
        {
            const int o = tid >> 2, kg = tid & 3;
            const u32* src = Wfa + (size_t)(o0 + o) * 128 + kk + kg * 16;
            u32 buf[16];
            #pragma unroll
            for (int j = 0; j < 4; ++j) *(uint4*)&buf[j * 4] = *(const uint4*)(src + j * 4);
            const int s0 = ((kg * 2)     ^ (o & 7)) << 3;
            const int s1 = ((kg * 2 + 1) ^ (o & 7)) << 3;
            short8v h0, h1; unpack_hi(buf, h0, h1);
            *(short8v*)&Wh[o][s0] = h0; *(short8v*)&Wh[o][s1] = h1;
        }
        {
            const int m = lane, kq = wv;
            const int s0 = ((kq * 2)     ^ (m & 7)) << 3;
            const int s1 = ((kq * 2 + 1) ^ (m & 7)) << 3;
            const ush* src = ao + ((size_t)b * 128 + kk + kq * 16) * M + m0 + m;
            ush h[16];
            #pragma unroll
            for (int j = 0; j < 16; ++j) h[j] = src[(size_t)j * M];
            *(short8v*)&Xh[m][s0] = *(short8v*)&h[0];
            *(short8v*)&Xh[m][s1] = *(short8v*)&h[8];
        }
        __syncthreads();
        #pragma unroll
        for (int kc = 0; kc < 2; ++kc) {
            const int sk = ((kc * 4 + grp) ^ (col & 7)) << 3;
            short8v ah0 = *(const short8v*)&Wh[wo * 32 + col][sk];
            short8v ah1 = *(const short8v*)&Wh[wo * 32 + 16 + col][sk];
            short8v xh0 = *(const short8v*)&Xh[wm * 32 + col][sk];
            short8v xh1 = *(const short8v*)&Xh[wm * 32 + 16 + col][sk];
            acc[0][0] = __builtin_amdgcn_mfma_f32_16x16x32_bf16(ah0, xh0, acc[0][0], 0, 0, 0);
            acc[0][1] = __builtin_amdgcn_mfma_f32_16x16x32_bf16(ah0, xh1, acc[0][1], 0, 0, 0);
            acc[1][0] = __builtin_amdgcn_mfma_f32_16x16x32_bf16(ah1, xh0, acc[1][0], 0, 0, 0);
            acc[1][1] = __builtin_amdgcn_mfma_f32_16x16x32_bf16(ah1, xh1, acc[1][1], 0, 0, 0);
        }
        __syncthreads();
    }

    for (int kk = 0; kk < 256; kk += 64) {
        {
            const int o = tid >> 2, kg = tid & 3;
            const u32* src = Wfb + (size_t)(o0 + o) * 256 + kk + kg * 16;
            u32 buf[16];
            #pragma unroll
            for (int j = 0; j < 4; ++j) *(uint4*)&buf[j * 4] = *(const uint4*)(src + j * 4);
            const int s0 = ((kg * 2)     ^ (o & 7)) << 3;
            const int s1 = ((kg * 2 + 1) ^ (o & 7)) << 3;
            short8v h0, h1; unpack_hi(buf, h0, h1);
            *(short8v*)&Wh[o][s0] = h0; *(short8v*)&Wh[o][s1] = h1;
        }
        {
            const int m = tid >> 2, kg = tid & 3;
            const int mg = m0 + m;
            const int n = mg & (N_ - 1), t = mg >> 11;
            const int s0 = ((kg * 2)     ^ (m & 7)) << 3;
            const int s1 = ((kg * 2 + 1) ^ (m & 7)) << 3;
            const ush* src = gb + ((size_t)(b * N_ + n) * 3 + t) * 256 + kk + kg * 16;
            ush h[16];
            *(uint4*)&h[0] = *(const uint4*)(src);
            *(uint4*)&h[8] = *(const uint4*)(src + 8);
            *(short8v*)&Xh[m][s0] = *(short8v*)&h[0];
            *(short8v*)&Xh[m][s1] = *(short8v*)&h[8];
        }
        __syncthreads();
        #pragma unroll
        for (int kc = 0; kc < 2; ++kc) {
            const int sk = ((kc * 4 + grp) ^ (col & 7)) << 3;
            short8v ah0 = *(const short8v*)&Wh[wo * 32 + col][sk];
            short8v ah1 = *(const short8v*)&Wh[wo * 32 + 16 + col][sk];
            short8v xh0 = *(const short8v*)&Xh[wm * 32 + col][sk];
            short8v xh1 = *(const short8v*)&Xh[wm * 32 + 16 + col][sk];
            acc[0][0] = __builtin_amdgcn_mfma_f32_16x16x32_bf16(ah0, xh0, acc[0][0], 0, 0, 0);
            acc[0][1] = __builtin_amdgcn_mfma_f32_16x16x32_bf16(ah0, xh1, acc[0][1], 0, 0, 0);
            acc[1][0] = __builtin_amdgcn_mfma_f32_16x16x32_bf16(ah1, xh0, acc[1][0], 0, 0, 0);
            acc[1][1] = __builtin_amdgcn_mfma_f32_16x16x32_bf16(ah1, xh1, acc[1][1], 0, 0, 0);
        }
        __syncthreads();
    }

    #pragma unroll
    for (int of = 0; of < 2; ++of) {
        #pragma unroll
        for (int r = 0; r < 4; ++r) {
            const int o = o0 + wo * 32 + of * 16 + grp * 4 + r;
            #pragma unroll
            for (int mf = 0; mf < 2; ++mf) {
                const int mloc = m0 + wm * 32 + mf * 16 + col;
                const size_t idx = ((size_t)b * 128 + o) * M + mloc;
                Y[idx] = acc[of][mf][r] + Z[idx];
            }
        }
    }
}

struct QKVArgs {
    const u32* W0; const u32* W1; const u32* W2;
    const ush* X0; const ush* X1; const ush* X2;
};

// fused: qkv projections (blocks 0..1151) + bf16 transpose(s) (blocks 1152..)
__global__ __launch_bounds__(256) void qkv_tr_kernel(QKVArgs A,
        ush* __restrict__ vfm, ush* __restrict__ qktb,
        const ush* __restrict__ ts0, ush* __restrict__ td0,
        const ush* __restrict__ ts1, ush* __restrict__ td1)
{
    __shared__ __align__(16) ush Wh[64][64];
    __shared__ __align__(16) ush Xh[64][64];
    __shared__ ush ttile[32][34];
    const int bx = blockIdx.x;
    if (bx < 1152) {
        const int z = bx / 576, rem = bx % 576;
        const int y = rem / 96, x = rem % 96;
        const int wi = y >> 1;
        const u32* W = wi == 0 ? A.W0 : (wi == 1 ? A.W1 : A.W2);
        const ush* X = wi == 0 ? A.X0 : (wi == 1 ? A.X1 : A.X2);
        gemm_tile<0, 4, true>(W, 128, X, 128, nullptr, nullptr, vfm, qktb,
                        z, x * 64, (y & 1) * 64, y * 64, 384,
                        Wh, Xh);
    } else {
        int i = bx - 1152;
        const int which = i / 1536; i %= 1536;
        const ush* src = which ? ts1 : ts0;
        ush* dst = which ? td1 : td0;
        const int x = i & 63, y = (i >> 6) & 3, z = i >> 8;
        const int b = z / 3, t = z % 3;
        const int n0 = x * 32, c0 = y * 32;
        const int tx = threadIdx.x & 31, ty = threadIdx.x >> 5;
        #pragma unroll
        for (int p = 0; p < 4; ++p) {
            int c = c0 + ty + p * 8;
            ttile[ty + p * 8][tx] = src[((size_t)(b * C_ + c) * 3 + t) * N_ + n0 + tx];
        }
        __syncthreads();
        #pragma unroll
        for (int p = 0; p < 4; ++p) {
            int n = n0 + ty + p * 8;
            dst[((size_t)(b * N_ + n) * 3 + t) * C_ + c0 + tx] = ttile[tx][ty + p * 8];
        }
    }
}

// ---------------------------------------------------------------------------
// barrier-free split-K flash attention, XCD-chunked 1D grid (1024 blocks).
// KSPLIT=4: each wave owns kz = its wave index, 32 queries x 512 keys.
// ---------------------------------------------------------------------------
__global__ __launch_bounds__(256) void attn_mfma_kernel(
    const ush* __restrict__ vfm, const ush* __restrict__ qktb,
    ush* __restrict__ pacc, float* __restrict__ pml)
{
    __shared__ __align__(16) ush Pl[4][2][16][64];   // 16 KB

    const int flat = blockIdx.x;
    const int xcd  = flat & 7;
    const int slot = flat >> 3;          // 0..127
    const int bh   = xcd * 2 + (slot >> 6);   // 0..15
    const int q32  = slot & 63;

    const int tid = threadIdx.x;
    const int lane = tid & 63, wv = tid >> 6;
    const int col = lane & 15, grp = lane >> 4;
    const int c7  = col & 7;
    const int kz  = wv;
    const int ks0 = kz * (N_ / KSPLIT);

    const ush* Qpl = qktb + (size_t)bh * 131072;
    const ush* Kpl = qktb + (size_t)(16 + bh) * 131072;
    const ush* Vpl = vfm  + (size_t)bh * 98304;

    short8v qf[2][2];
    #pragma unroll
    for (int qi = 0; qi < 2; ++qi) {
        const int qg = q32 * 2 + qi;
        qf[qi][0] = *(const short8v*)(Qpl + ((size_t)qg * 2 + 0) * 512 + lane * 8);
        qf[qi][1] = *(const short8v*)(Qpl + ((size_t)qg * 2 + 1) * 512 + lane * 8);
    }

    f32x4 acc[2][3];
    #pragma unroll
    for (int qi = 0; qi < 2; ++qi)
        #pragma unroll
        for (int db = 0; db < 3; ++db) { f32x4 z = {0.f,0.f,0.f,0.f}; acc[qi][db] = z; }
    float m_i[2] = {0.f, 0.f};
    float l_l[2] = {0.f, 0.f};

    const int NT = (N_ / KSPLIT) / 64;   // 8 tiles of 64 keys
    for (int mt = 0; mt < NT; ++mt) {
        const int m0 = ks0 + mt * 64;

        short8v ka[4][2];
        #pragma unroll
        for (int kb = 0; kb < 4; ++kb) {
            const size_t kg = (m0 >> 4) + kb;
            ka[kb][0] = *(const short8v*)(Kpl + (kg * 2 + 0) * 512 + lane * 8);
            ka[kb][1] = *(const short8v*)(Kpl + (kg * 2 + 1) * 512 + lane * 8);
        }
        const int kt = m0 >> 6;
        short8v vf[2][3];
        #pragma unroll
        for (int hh = 0; hh < 2; ++hh)
            #pragma unroll
            for (int db = 0; db < 3; ++db)
                vf[hh][db] = *(const short8v*)(Vpl + (size_t)((kt * 2 + hh) * 3 + db) * 512 + lane * 8);

        f32x4 sf[2][4];
        __builtin_amdgcn_s_setprio(1);
        #pragma unroll
        for (int qi = 0; qi < 2; ++qi)
            #pragma unroll
            for (int kb = 0; kb < 4; ++kb) {
                f32x4 z = {0.f, 0.f, 0.f, 0.f};
                z = __builtin_amdgcn_mfma_f32_16x16x32_bf16(ka[kb][0], qf[qi][0], z, 0, 0, 0);
                z = __builtin_amdgcn_mfma_f32_16x16x32_bf16(ka[kb][1], qf[qi][1], z, 0, 0, 0);
                sf[qi][kb] = z;
            }
        __builtin_amdgcn_s_setprio(0);

        #pragma unroll
        for (int qi = 0; qi < 2; ++qi) {
            float psum = 0.f;
            #pragma unroll
            for (int kb = 0; kb < 4; ++kb) {
                float e0 = __expf(sf[qi][kb][0] - m_i[qi]);
                float e1 = __expf(sf[qi][kb][1] - m_i[qi]);
                float e2 = __expf(sf[qi][kb][2] - m_i[qi]);
                float e3 = __expf(sf[qi][kb][3] - m_i[qi]);
                psum += (e0 + e1) + (e2 + e3);
                u32 r0, r1;
                asm("v_cvt_pk_bf16_f32 %0, %1, %2" : "=v"(r0) : "v"(e0), "v"(e1));
                asm("v_cvt_pk_bf16_f32 %0, %1, %2" : "=v"(r1) : "v"(e2), "v"(e3));
                const int un = (4 * kb + grp) ^ (c7 << 1);
                uint2 pk2; pk2.x = r0; pk2.y = r1;
                *(uint2*)&Pl[wv][qi][col][un << 2] = pk2;
            }
            l_l[qi] += psum;
        }

        __builtin_amdgcn_s_setprio(1);
        #pragma unroll
        for (int qi = 0; qi < 2; ++qi)
            #pragma unroll
            for (int hh = 0; hh < 2; ++hh) {
                const int ur = (8 * hh + 2 * grp) ^ (c7 << 1);
                short8v pf = *(const short8v*)&Pl[wv][qi][col][ur << 2];
                #pragma unroll
                for (int db = 0; db < 3; ++db)
                    acc[qi][db] = __builtin_amdgcn_mfma_f32_16x16x32_bf16(vf[hh][db], pf, acc[qi][db], 0, 0, 0);
            }
        __builtin_amdgcn_s_setprio(0);

        #pragma unroll
        for (int qi = 0; qi < 2; ++qi) {
            float pmax = -1e30f;
            #pragma unroll
            for (int kb = 0; kb < 4; ++kb)
                #pragma unroll
                for (int r = 0; r < 4; ++r) pmax = fmaxf(pmax, sf[qi][kb][r]);
            pmax = fmaxf(pmax, __shfl_xor(pmax, 16, 64));
            pmax = fmaxf(pmax, __shfl_xor(pmax, 32, 64));
            if (!__all(pmax - m_i[qi] <= 8.0f)) {
                float mnew = fmaxf(m_i[qi], pmax);
                float sc = __expf(m_i[qi] - mnew);
                l_l[qi] *= sc;
                #pragma unroll
                for (int db = 0; db < 3; ++db) {
                    acc[qi][db][0] *= sc; acc[qi][db][1] *= sc;
                    acc[qi][db][2] *= sc; acc[qi][db][3] *= sc;
                }
                m_i[qi] = mnew;
            }
        }
    }

    const int ntile = q32 >> 1, qh = q32 & 1;
    const size_t pb = (size_t)(kz * 16 + bh) * 32 + ntile;
    #pragma unroll
    for (int qi = 0; qi < 2; ++qi) {
        float l = l_l[qi];
        l += __shfl_xor(l, 16, 64);
        l += __shfl_xor(l, 32, 64);
        const int q = qh * 32 + qi * 16 + col;
        #pragma unroll
        for (int db = 0; db < 3; ++db)
            #pragma unroll
            for (int r = 0; r < 4; ++r) {
                int d = db * 16 + grp * 4 + r;
                pacc[pb * 3072 + d * 64 + q] = f2bf(acc[qi][db][r]);
            }
        if (grp == 0) {
            pml[pb * 128 + q]      = m_i[qi];
            pml[pb * 128 + 64 + q] = l;
        }
    }
}

// ---------------------------------------------------------------------------
// fused: split-K reduce (blocks 0..511) + graph attention (blocks 512..4607)
// ---------------------------------------------------------------------------
__global__ __launch_bounds__(256) void reduce_graph_kernel(
    const ush* __restrict__ pacc, const float* __restrict__ pml,
    ush* __restrict__ ao,
    const ush* __restrict__ tq, const ush* __restrict__ tv,
    const int* __restrict__ idx, ush* __restrict__ gbuf)
{
    __shared__ float centerf[384];
    __shared__ ush nbr_l[16][384];
    __shared__ float sd[16];
    __shared__ int nbr_i[16];
    const int tid = threadIdx.x;

    if (blockIdx.x < 512) {
        // ============ split-K reduce ============
        const int nt = blockIdx.x & 31, bh = blockIdx.x >> 5;
        const int b = bh >> 3, h = bh & 7;
        const int q = tid & 63, dg = tid >> 6;

        size_t pb[KSPLIT];
        float m[KSPLIT], l[KSPLIT];
        #pragma unroll
        for (int kz = 0; kz < KSPLIT; ++kz) {
            pb[kz] = (size_t)(kz * 16 + bh) * 32 + nt;
            m[kz] = pml[pb[kz] * 128 + q];
            l[kz] = pml[pb[kz] * 128 + 64 + q];
        }
        float ms = -1e30f;
        #pragma unroll
        for (int kz = 0; kz < KSPLIT; ++kz) ms = fmaxf(ms, m[kz]);
        float w[KSPLIT], ls = 0.f;
        #pragma unroll
        for (int kz = 0; kz < KSPLIT; ++kz) { w[kz] = __expf(m[kz] - ms); ls += l[kz] * w[kz]; }
        const float inv = 1.f / ls;

        const size_t hb = ((size_t)(b * C_ + h * 16)) * 3 * N_;
        #pragma unroll
        for (int j = 0; j < 12; ++j) {
            int d = dg * 12 + j;
            float o = 0.f;
            #pragma unroll
            for (int kz = 0; kz < KSPLIT; ++kz)
                o += bf2f(pacc[pb[kz] * 3072 + d * 64 + q]) * w[kz];
            ao[hb + (size_t)d * N_ + nt * 64 + q] = f2bf(o * inv);
        }
    } else {
        // ============ graph attention ============
        const int j = blockIdx.x - 512;
        const int b = j >> 11, n = j & 2047;
        const ush* qrow = tq + (size_t)(b * N_ + n) * 384;
        for (int e = tid; e < 384; e += 256) centerf[e] = bf2f(qrow[e]);
        if (tid < 16) nbr_i[tid] = idx[(size_t)(b * N_ + n) * 16 + tid];
        __syncthreads();

        const int lane = tid & 63, wv = tid >> 6;
        for (int kk = 0; kk < 4; ++kk) {
            int k = wv * 4 + kk;
            const u32* vrow = (const u32*)(tv + ((size_t)b * N_ + nbr_i[k]) * 384);
            float p = 0.f;
            #pragma unroll
            for (int jj = 0; jj < 3; ++jj) {
                int e2 = lane + jj * 64;
                u32 v2 = vrow[e2];
                ((u32*)nbr_l[k])[e2] = v2;
                p += centerf[e2 * 2]     * bf2f((ush)(v2 & 0xffff))
                   + centerf[e2 * 2 + 1] * bf2f((ush)(v2 >> 16));
            }
            #pragma unroll
            for (int off = 32; off; off >>= 1) p += __shfl_down(p, off, 64);
            if (lane == 0) sd[k] = p * 0.05103103630798288f;
        }
        __syncthreads();

        float mx = -1e30f;
        #pragma unroll
        for (int k = 0; k < 16; ++k) mx = fmaxf(mx, sd[k]);
        float a[16]; float ssum = 0.f;
        #pragma unroll
        for (int k = 0; k < 16; ++k) { a[k] = __expf(sd[k] - mx); ssum += a[k]; }
        float inv = 1.f / ssum;

        for (int e = tid; e < 384; e += 256) {
            float accv = 0.f;
            #pragma unroll
            for (int k = 0; k < 16; ++k)
                accv += a[k] * bf2f(nbr_l[k][e]);
            accv *= inv;
            float ce = centerf[e];
            int t = e >> 7, c = e & 127;
            size_t gb = ((size_t)(b * N_ + n) * 3 + t) * 256;
            gbuf[gb + c]       = f2bf(accv - ce);
            gbuf[gb + 128 + c] = f2bf(ce);
        }
    }
}

// ---------------------------------------------------------------------------
// vn_leaky: bf16 x,d in -> bf16 out
// ---------------------------------------------------------------------------
__global__ __launch_bounds__(256) void leaky_kernel(const ush* __restrict__ x,
                                                    const ush* __restrict__ d,
                                                    ush* __restrict__ y)
{
    size_t p = (size_t)blockIdx.x * 256 + threadIdx.x;
    size_t bh = p / N_, n = p % N_;
    size_t base = bh * 3 * N_ + n;
    float x0 = bf2f(x[base]), x1 = bf2f(x[base + N_]), x2 = bf2f(x[base + 2 * N_]);
    float d0 = bf2f(d[base]), d1 = bf2f(d[base + N_]), d2 = bf2f(d[base + 2 * N_]);
    float dot = x0 * d0 + x1 * d1 + x2 * d2;
    float dsq = d0 * d0 + d1 * d1 + d2 * d2;
    float f = dot / (dsq + EPS_);
    bool pos = dot >= 0.f;
    float y0 = pos ? x0 : x0 - f * d0;
    float y1 = pos ? x1 : x1 - f * d1;
    float y2 = pos ? x2 : x2 - f * d2;
    y[base]          = f2bf(NS_ * x0 + (1.f - NS_) * y0);
    y[base + N_]     = f2bf(NS_ * x1 + (1.f - NS_) * y1);
    y[base + 2 * N_] = f2bf(NS_ * x2 + (1.f - NS_) * y2);
}

// ---------------------------------------------------------------------------
extern "C" void kernel_launch(void* const* d_in, const int* in_sizes, int n_in,
                              void* d_out, int out_size, void* d_ws, size_t ws_size,
                              hipStream_t stream)
{
    const float* q_in = (const float*)d_in[0];
    const float* v_in = (const float*)d_in[1];
    const int*   idx_s = (const int*)d_in[4];
    const int*   idx_c = (const int*)d_in[5];
    const float* g1 = (const float*)d_in[6];
    const float* b1 = (const float*)d_in[7];
    const float* g2 = (const float*)d_in[8];
    const float* b2 = (const float*)d_in[9];
    const float* gq = (const float*)d_in[10];
    const float* bq = (const float*)d_in[11];
    const float* gv = (const float*)d_in[12];
    const float* bv = (const float*)d_in[13];
    float* out = (float*)d_out;
    float* ws  = (float*)d_ws;

    const size_t S1 = (size_t)B_ * C_ * 3 * N_; // 1572864 elems
    ush*   gbuf_b= (ush*)(ws);         // 0 (6.3MB; live reduce_graph -> wm2)
    ush*   nx_b  = (ush*)(ws + 2*S1);  // 2 (half)
    ush*   nv_b  = (ush*)(ws + 3*S1);  // 3 (half)
    ush*   vfm   = (ush*)(ws + 4*S1);  // 4: 3MB
    ush*   qktb  = (ush*)(ws + 5*S1) + S1;  // 5.5-6.84: 8.4MB
    ush*   ao_b  = (ush*)(ws + 7*S1);  // 7 (half)
    float* qa    = ws + 12*S1;         // 12
    float* qb    = ws + 13*S1;         // 13
    ush*   t1_b  = (ush*)(ws + 14*S1); // 14 (half)
    ush*   t2_b  = (ush*)(ws + 15*S1); // 15 (half)
    u32*   wsp   = (u32*)(ws + 16*S1); // 16+
    // split-K attention partials (attn->reduce window only; KSPLIT=4: 12.6MB)
    ush*   pacc  = (ush*)(ws + 8*S1);  // 8-9
    float* pml   = (float*)(ws + 2*S1);// 2 (attn after qkv consumed nx_b)
    // phase C aliases (all bf16):
    ush*   hd_b  = (ush*)(ws + 1*S1);  // 1-2 as ush (12.6MB; nv_b/pml dead)
    ush*   h1_b  = (ush*)(ws + 14*S1); // 14-15 (t1/t2 dead)
    ush*   h1_b2 = (ush*)(ws + 8*S1);  // 8-9 (pacc dead)

    // weight planes: 9 split-converted + 4 fused (Wfa/Wfb per phase)
    const int wn[9]   = {16384,16384,16384, 16384,16384,16384, 65536,262144,65536};
    const int wsrc[9] = {14,15,16, 20,21,22, 26,27,28};
    u32* wd[9];
    {
        int off = 0;
        for (int i = 0; i < 9; ++i) { wd[i] = wsp + off; off += wn[i]; }
    }
    u32 *Wq_s = wd[0], *Wk_s = wd[1], *Wv_s = wd[2];
    u32 *Wq_c = wd[3], *Wk_c = wd[4], *Wv_c = wd[5];
    u32 *W1 = wd[6], *Dact = wd[7], *W2 = wd[8];
    u32* Wfa_s = wsp + 491520;
    u32* Wfb_s = Wfa_s + 16384;
    u32* Wfa_c = Wfb_s + 32768;
    u32* Wfb_c = Wfa_c + 16384;

    {
        SetupArgs a{};
        for (int i = 0; i < 9; ++i) {
            a.src[i] = (const float*)d_in[wsrc[i]];
            a.dst[i] = wd[i];
            a.n[i]   = wn[i];
            a.scale[i] = 1.f;
        }
        a.scale[0] = 0.14433756729740643f;  // Wq_s: fold 1/sqrt(48)
        a.scale[3] = 0.14433756729740643f;  // Wq_c
        a.Wm[0] = (const float*)d_in[19]; a.Wo[0] = (const float*)d_in[17]; a.We[0] = (const float*)d_in[18];
        a.Wm[1] = (const float*)d_in[25]; a.Wo[1] = (const float*)d_in[23]; a.We[1] = (const float*)d_in[24];
        a.Wfa[0] = Wfa_s; a.Wfb[0] = Wfb_s;
        a.Wfa[1] = Wfa_c; a.Wfb[1] = Wfb_c;
        a.qkz = (uint4*)qktb;
        setup_kernel<<<dim3(9216 + 384 + 1024), 256, 0, stream>>>(a);
    }

    dim3 gwm(96, 2, B_);
    dim3 gg512(96, 8, B_);

    // ---- Phase A: self attention block ----
    {
        LNArgs la{};
        la.x[0] = q_in; la.g[0] = g1; la.bt[0] = b1; la.ysp[0] = nx_b;
        ln_kernel<<<dim3(64, B_, 1), 256, 0, stream>>>(la);
    }
    {
        QKVArgs A{Wq_s, Wk_s, Wv_s, nx_b, nx_b, nx_b};
        qkv_tr_kernel<<<dim3(1152 + 1536), 256, 0, stream>>>(A, vfm, qktb, nx_b, t1_b, nullptr, nullptr);
    }
    attn_mfma_kernel<<<dim3(1024), 256, 0, stream>>>(vfm, qktb, pacc, pml);
    reduce_graph_kernel<<<dim3(512 + 4096), 256, 0, stream>>>(pacc, pml, ao_b, t1_b, t1_b, idx_s, gbuf_b);
    wm2_kernel<<<gwm, 256, 0, stream>>>(Wfa_s, Wfb_s, ao_b, gbuf_b, q_in, qa);

    // ---- Phase B: cross attention block ----
    {
        LNArgs la{};
        la.x[0] = qa;   la.g[0] = gq; la.bt[0] = bq; la.ysp[0] = nx_b;
        la.x[1] = v_in; la.g[1] = gv; la.bt[1] = bv; la.ysp[1] = nv_b;
        ln_kernel<<<dim3(64, B_, 2), 256, 0, stream>>>(la);
    }
    {
        QKVArgs A{Wq_c, Wk_c, Wv_c, nx_b, nv_b, nv_b};
        qkv_tr_kernel<<<dim3(1152 + 3072), 256, 0, stream>>>(A, vfm, qktb, nx_b, t1_b, nv_b, t2_b);
    }
    attn_mfma_kernel<<<dim3(1024), 256, 0, stream>>>(vfm, qktb, pacc, pml);
    reduce_graph_kernel<<<dim3(512 + 4096), 256, 0, stream>>>(pacc, pml, ao_b, t1_b, t2_b, idx_c, gbuf_b);
    wm2_kernel<<<gwm, 256, 0, stream>>>(Wfa_c, Wfb_c, ao_b, gbuf_b, qa, qb);

    // ---- Phase C: vector MLP (all-bf16 intermediates) ----
    {
        LNArgs la{};
        la.x[0] = qb; la.g[0] = g2; la.bt[0] = b2; la.ysp[0] = nx_b;
        ln_kernel<<<dim3(64, B_, 1), 256, 0, stream>>>(la);
    }
    gemm_kernel2<0,3,true><<<gg512, 256, 0, stream>>>(W1, 128, nx_b, nullptr, nullptr, h1_b, 512, 0, 128);
    gemm_kernel2<0,3,true><<<gg512, 256, 0, stream>>>(Dact, 512, h1_b, nullptr, nullptr, hd_b, 512, 0, 512);
    leaky_kernel<<<dim3((B_ * HID_ * N_) / 256), 256, 0, stream>>>(h1_b, hd_b, h1_b2);
    gemm_kernel2<0,0,true><<<dim3(96, 2, B_), 256, 0, stream>>>(W2, 512, h1_b2, qb, out, nullptr, 128, 0, 512);
}